// Round 3
// baseline (1062.200 us; speedup 1.0000x reference)
//
#include <hip/hip_runtime.h>

typedef _Float16 half8 __attribute__((ext_vector_type(8)));
typedef _Float16 half4 __attribute__((ext_vector_type(4)));
typedef float floatx4 __attribute__((ext_vector_type(4)));

#define B_    64
#define N_    512
#define DIN_  256
#define DH_   512
#define DOUT_ 256
#define H_    4
#define BN_   (B_ * N_)   // 32768

// raw waitcnt immediates (gfx9: vmcnt[3:0]|[15:14], exp[6:4], lgkm[11:8])
#define WAIT_VM4_LGKM0() __builtin_amdgcn_s_waitcnt(0x0074)  // vm<=4, lgkm<=0
#define WAIT_VM0_LGKM0() __builtin_amdgcn_s_waitcnt(0x0070)  // vm<=0, lgkm<=0
#define WAIT_VM4()       __builtin_amdgcn_s_waitcnt(0x0F74)  // vm<=4 only
#define WAIT_VM0()       __builtin_amdgcn_s_waitcnt(0x0F70)  // vm<=0 only
#define MEMBAR()         __asm__ __volatile__("" ::: "memory")
#define BAR()            do { MEMBAR(); __builtin_amdgcn_s_barrier(); MEMBAR(); } while (0)

__device__ static inline void async_copy16(const _Float16* g, _Float16* l) {
    __builtin_amdgcn_global_load_lds(
        (const __attribute__((address_space(1))) void*)g,
        (__attribute__((address_space(3))) void*)l, 16, 0, 0);
}

// ---------------------------------------------------------------------------
// OLD GEMM (kept for small preprocessing shapes): C[M,N]=A[M,K]*B[N,K]^T(+bias)
// 128x128 tile, BK=32, 4 waves, triple-buffered, 1 barrier/iter.
// ---------------------------------------------------------------------------
template <bool OUT_F16>
__global__ __launch_bounds__(256)
void gemm_f16(const _Float16* __restrict__ A, long long aS1, long long aS2, int lda, long long aSeg,
              const _Float16* __restrict__ B, long long bS1, long long bS2, int ldb, long long bSeg,
              void* __restrict__ Cv, long long cS1, long long cS2, int ldc,
              int K, const float* __restrict__ bias, int biasMode,
              long long biasS1, long long biasS2, int zShift)
{
    __shared__ __align__(16) _Float16 As[3][128 * 32];
    __shared__ __align__(16) _Float16 Bs[3][128 * 32];

    const int tid  = threadIdx.x;
    const int wave = tid >> 6;
    const int lane = tid & 63;
    const int quad = lane >> 4;
    const int r16  = lane & 15;

    const int z  = blockIdx.z;
    const int z1 = z >> zShift;
    const int z2 = z & ((1 << zShift) - 1);

    const int gx = gridDim.x, gy = gridDim.y;
    const int T = gx * gy;
    int lin = blockIdx.y * gx + blockIdx.x;
    int id2 = (T & 7) ? lin : ((lin & 7) * (T >> 3) + (lin >> 3));
    const int m0 = (id2 / gx) * 128;
    const int n0 = (id2 % gx) * 128;

    const int srow = lane >> 2;
    const int scol = (((lane & 3) ^ ((lane >> 3) & 3))) * 8;

    const _Float16* gaRow = A + z1 * aS1 + z2 * aS2
                              + (long long)(m0 + wave * 32 + srow) * lda + scol;
    const _Float16* gbRow = B + z1 * bS1 + z2 * bS2
                              + (long long)(n0 + wave * 32 + srow) * ldb + scol;

    const int wm = (wave >> 1) * 64;
    const int wn = (wave & 1) * 64;
    const int gl = (quad ^ ((r16 >> 1) & 3)) * 8;

    floatx4 acc[4][4];
#pragma unroll
    for (int i = 0; i < 4; i++)
#pragma unroll
        for (int j = 0; j < 4; j++) acc[i][j] = (floatx4){0.f, 0.f, 0.f, 0.f};

    auto stage = [&](int p, int k0) {
        const _Float16* a = gaRow + (long long)(k0 >> 9) * aSeg + (k0 & 511);
        const _Float16* b = gbRow + (long long)(k0 >> 9) * bSeg + (k0 & 511);
        _Float16* la = &As[p][wave * 1024];
        _Float16* lb = &Bs[p][wave * 1024];
        async_copy16(a,                    la);
        async_copy16(a + (size_t)16 * lda, la + 512);
        async_copy16(b,                    lb);
        async_copy16(b + (size_t)16 * ldb, lb + 512);
    };

    auto compute = [&](int p) {
        half8 af[4], bf[4];
#pragma unroll
        for (int i = 0; i < 4; i++)
            af[i] = *(const half8*)&As[p][(wm + i * 16 + r16) * 32 + gl];
#pragma unroll
        for (int j = 0; j < 4; j++)
            bf[j] = *(const half8*)&Bs[p][(wn + j * 16 + r16) * 32 + gl];
#pragma unroll
        for (int i = 0; i < 4; i++)
#pragma unroll
            for (int j = 0; j < 4; j++)
                acc[i][j] = __builtin_amdgcn_mfma_f32_16x16x32_f16(
                    bf[j], af[i], acc[i][j], 0, 0, 0);
    };

    const int niter = K >> 5;
    stage(0, 0);
    stage(1, 32);
    int pNext = 2;
    int pCur  = 0;
    for (int it = 0; it < niter - 1; ++it) {
        MEMBAR(); WAIT_VM4_LGKM0();
        __builtin_amdgcn_s_barrier();
        MEMBAR();
        if (it + 2 < niter) stage(pNext, (it + 2) << 5);
        compute(pCur);
        MEMBAR();
        pNext = (pNext == 2) ? 0 : pNext + 1;
        pCur  = (pCur  == 2) ? 0 : pCur  + 1;
    }
    MEMBAR(); WAIT_VM0_LGKM0();
    __builtin_amdgcn_s_barrier(); MEMBAR();
    compute(pCur);

    const float* bz = bias + z1 * biasS1 + z2 * biasS2;
    float*    Cf = (float*)Cv    + z1 * cS1 + z2 * cS2;
    _Float16* Ch = (_Float16*)Cv + z1 * cS1 + z2 * cS2;
#pragma unroll
    for (int i = 0; i < 4; i++) {
        const int row = m0 + wm + i * 16 + r16;
#pragma unroll
        for (int j = 0; j < 4; j++) {
            const int col = n0 + wn + j * 16 + quad * 4;
            float v0 = acc[i][j][0], v1 = acc[i][j][1],
                  v2 = acc[i][j][2], v3 = acc[i][j][3];
            if (biasMode == 1) {
                v0 += bz[col]; v1 += bz[col + 1];
                v2 += bz[col + 2]; v3 += bz[col + 3];
            } else if (biasMode == 2) {
                const float bv = bz[row];
                v0 += bv; v1 += bv; v2 += bv; v3 += bv;
            }
            const size_t idx = (size_t)row * ldc + col;
            if (OUT_F16) {
                half4 hv = {(_Float16)v0, (_Float16)v1, (_Float16)v2, (_Float16)v3};
                *(half4*)&Ch[idx] = hv;
            } else {
                float4 fv = {v0, v1, v2, v3};
                *(float4*)&Cf[idx] = fv;
            }
        }
    }
}

// ---------------------------------------------------------------------------
// 256x256 tile, 8 waves (2x4), BK=64, 8-phase interleave, counted vmcnt,
// XOR-swizzled LDS via pre-swizzled global source, setprio around MFMA.
// STATIC buffer map: even K-tiles -> buf0 (read p0-p3), odd -> buf1 (p4-p7).
//
// This round: B col-half-0 fragments are kept in registers across the
// K-tile (bf0s loaded at p0/p4, reused at p3/p7) -> 24 instead of 28
// ds_read_b128 per wave per K-tile; p3/p7 are pure-MFMA phases.
//
// Schedule per iteration (tiles tt=2it, tt+1; snake (0,0)(0,1)(1,1)(1,0)):
//  p0: rd A0,B0(tt)@b0    stage A1(tt+1)->b1
//  p1: rd B1(tt)@b0       stage B0(tt+1)->b1
//  p2: rd A1(tt)@b0       stage A0(tt+2)->b0
//  p3: (regs only)        stage B1(tt+2)->b0   W0: vmcnt(4) (last iter: 0)
//  p4: rd A0,B0(tt+1)@b1  stage A1(tt+2)->b0
//  p5: rd B1(tt+1)@b1     stage B0(tt+2)->b0
//  p6: rd A1(tt+1)@b1     stage A0(tt+3)->b1
//  p7: (regs only)        stage B1(tt+3)->b1   W1: vmcnt(4)
// RAW: W0's <=4 outstanding = p2+p3 stages -> tile tt+1 landed for p4-p7;
// W1's <=4 = p6+p7 stages -> tile tt+2 landed for next p0-p3.
// WAR: every stage issues >=2 barriers after the last read of its slot.
// ---------------------------------------------------------------------------
template <bool OUT_F16>
__global__ __launch_bounds__(512, 2)
void gemm256(const _Float16* __restrict__ A, long long aS1, long long aS2, int lda, long long aSeg,
             const _Float16* __restrict__ B, long long bS1, long long bS2, int ldb, long long bSeg,
             void* __restrict__ Cv, long long cS1, long long cS2, int ldc,
             int K, const float* __restrict__ bias, int biasMode,
             long long biasS1, long long biasS2, int zShift)
{
    extern __shared__ __align__(16) _Float16 lds[];
    _Float16* AsB = lds;                 // [2][256*64]
    _Float16* BsB = lds + 2 * 256 * 64;  // [2][256*64]

    const int tid  = threadIdx.x;
    const int wave = tid >> 6;        // 0..7
    const int lane = tid & 63;
    const int quad = lane >> 4;
    const int r16  = lane & 15;
    const int wr   = wave >> 2;       // 0..1  (row half of wave grid)
    const int wc   = wave & 3;        // 0..3  (col quarter)

    const int z  = blockIdx.z;
    const int z1 = z >> zShift;
    const int z2 = z & ((1 << zShift) - 1);

    const int gx = gridDim.x, gy = gridDim.y;
    const int T = gx * gy;
    int lin = blockIdx.y * gx + blockIdx.x;
    int id2 = (T & 7) ? lin : ((lin & 7) * (T >> 3) + (lin >> 3));
    const int m0 = (id2 / gx) * 256;
    const int n0 = (id2 % gx) * 256;

    // staging: thread t, load l, half h of tile tt2:
    //   LDS granule gi = l*512 + t  (row_lds = l*64 + (t>>3), g_store = t&7)
    //   fetch global col granule (t&7)^((t>>3)&7)  [pre-swizzled source]
    const int sr  = tid >> 3;                       // 0..63
    const int swz = ((tid & 7) ^ (sr & 7)) * 8;     // swizzled k-offset (elems)
    const _Float16* gaA = A + z1 * aS1 + z2 * aS2 + (long long)(m0 + sr) * lda + swz;
    const _Float16* gbB = B + z1 * bS1 + z2 * bS2 + (long long)(n0 + sr) * ldb + swz;

    // read-side constants: row&7 == r16&7 for all fragment rows
    const int arow = wr * 64 + r16;   // + rh*128 + i*16
    const int brow = wc * 32 + r16;   // + ch*128 + j*16
    const int rsw  = r16 & 7;
    const int gxk0 = (quad ^ rsw) * 8;        // ks=0 granule (swizzled), elems
    const int gxk1 = ((4 + quad) ^ rsw) * 8;  // ks=1

    floatx4 acc[8][4];
#pragma unroll
    for (int i = 0; i < 8; i++)
#pragma unroll
        for (int j = 0; j < 4; j++) acc[i][j] = (floatx4){0.f, 0.f, 0.f, 0.f};

    half8 af[4][2], bf0s[2][2], bf1s[2][2];

    auto stageA = [&](int buf, int h, int tt2) {
        const _Float16* s = gaA + (long long)(h * 128) * lda
                          + (long long)(tt2 >> 3) * aSeg + ((tt2 & 7) << 6);
        _Float16* d = AsB + buf * 16384 + h * 8192 + wave * 512;
        async_copy16(s, d);
        async_copy16(s + (long long)64 * lda, d + 4096);
    };
    auto stageB = [&](int buf, int h, int tt2) {
        const _Float16* s = gbB + (long long)(h * 128) * ldb
                          + (long long)(tt2 >> 3) * bSeg + ((tt2 & 7) << 6);
        _Float16* d = BsB + buf * 16384 + h * 8192 + wave * 512;
        async_copy16(s, d);
        async_copy16(s + (long long)64 * ldb, d + 4096);
    };

#define LOAD_AF(RH, BUF) do { \
    const _Float16* ab_ = AsB + (BUF) * 16384 + ((RH) * 128 + arow) * 64; \
    _Pragma("unroll") \
    for (int i5 = 0; i5 < 4; i5++) { \
        af[i5][0] = *(const half8*)(ab_ + i5 * 1024 + gxk0); \
        af[i5][1] = *(const half8*)(ab_ + i5 * 1024 + gxk1); \
    } \
} while (0)

#define LOAD_BF(DST, CH, BUF) do { \
    const _Float16* bb_ = BsB + (BUF) * 16384 + ((CH) * 128 + brow) * 64; \
    _Pragma("unroll") \
    for (int j5 = 0; j5 < 2; j5++) { \
        DST[j5][0] = *(const half8*)(bb_ + j5 * 1024 + gxk0); \
        DST[j5][1] = *(const half8*)(bb_ + j5 * 1024 + gxk1); \
    } \
} while (0)

#define MFMA16(RH, CH, BFS) do { \
    _Pragma("unroll") \
    for (int i6 = 0; i6 < 4; i6++) { \
        _Pragma("unroll") \
        for (int j6 = 0; j6 < 2; j6++) { \
            floatx4 c_ = acc[(RH) * 4 + i6][(CH) * 2 + j6]; \
            c_ = __builtin_amdgcn_mfma_f32_16x16x32_f16(BFS[j6][0], af[i6][0], c_, 0, 0, 0); \
            c_ = __builtin_amdgcn_mfma_f32_16x16x32_f16(BFS[j6][1], af[i6][1], c_, 0, 0, 0); \
            acc[(RH) * 4 + i6][(CH) * 2 + j6] = c_; \
        } \
    } \
} while (0)

    const int nit = K >> 7;   // iterations of 2 K-tiles (K % 128 == 0)

    // prologue: tile0 -> buf0 (all 4 halves), tile1 -> buf1 (A0, B1)
    stageA(0, 0, 0);
    stageB(0, 1, 0);
    stageA(0, 1, 0);
    stageB(0, 0, 0);
    stageA(1, 0, 1);
    stageB(1, 1, 1);
    WAIT_VM4();
    BAR();

    for (int it = 0; it < nit; ++it) {
        const int tt = it * 2;
        const bool full = (it < nit - 1);

        // ---- p0: (0,0) of tile tt  [buf0]
        LOAD_AF(0, 0); LOAD_BF(bf0s, 0, 0);
        stageA(1, 1, tt + 1);
        BAR();
        __builtin_amdgcn_s_setprio(1); MFMA16(0, 0, bf0s); __builtin_amdgcn_s_setprio(0);
        BAR();
        // ---- p1: (0,1)
        LOAD_BF(bf1s, 1, 0);
        stageB(1, 0, tt + 1);
        BAR();
        __builtin_amdgcn_s_setprio(1); MFMA16(0, 1, bf1s); __builtin_amdgcn_s_setprio(0);
        BAR();
        // ---- p2: (1,1)
        LOAD_AF(1, 0);
        if (full) stageA(0, 0, tt + 2);
        BAR();
        __builtin_amdgcn_s_setprio(1); MFMA16(1, 1, bf1s); __builtin_amdgcn_s_setprio(0);
        BAR();
        // ---- p3: (1,0)  regs-only  + W0
        if (full) stageB(0, 1, tt + 2);
        BAR();
        __builtin_amdgcn_s_setprio(1); MFMA16(1, 0, bf0s); __builtin_amdgcn_s_setprio(0);
        if (full) WAIT_VM4(); else WAIT_VM0();
        BAR();
        // ---- p4: (0,0) of tile tt+1  [buf1]
        LOAD_AF(0, 1); LOAD_BF(bf0s, 0, 1);
        if (full) stageA(0, 1, tt + 2);
        BAR();
        __builtin_amdgcn_s_setprio(1); MFMA16(0, 0, bf0s); __builtin_amdgcn_s_setprio(0);
        BAR();
        // ---- p5: (0,1)
        LOAD_BF(bf1s, 1, 1);
        if (full) stageB(0, 0, tt + 2);
        BAR();
        __builtin_amdgcn_s_setprio(1); MFMA16(0, 1, bf1s); __builtin_amdgcn_s_setprio(0);
        BAR();
        // ---- p6: (1,1)
        LOAD_AF(1, 1);
        if (full) stageA(1, 0, tt + 3);
        BAR();
        __builtin_amdgcn_s_setprio(1); MFMA16(1, 1, bf1s); __builtin_amdgcn_s_setprio(0);
        BAR();
        // ---- p7: (1,0)  regs-only  + W1
        if (full) stageB(1, 1, tt + 3);
        BAR();
        __builtin_amdgcn_s_setprio(1); MFMA16(1, 0, bf0s); __builtin_amdgcn_s_setprio(0);
        if (full) WAIT_VM4();
        BAR();
    }

#undef LOAD_AF
#undef LOAD_BF
#undef MFMA16

    // epilogue (swapped layout): row from r16, 4 consecutive cols per lane.
    //   row(f) = (f>>2)*128 + wr*64 + (f&3)*16 + r16
    //   col(j) = (j>>1)*128 + wc*32 + (j&1)*16 + quad*4
    const float* bz = bias + z1 * biasS1 + z2 * biasS2;
    float*    Cf = (float*)Cv    + z1 * cS1 + z2 * cS2;
    _Float16* Ch = (_Float16*)Cv + z1 * cS1 + z2 * cS2;
#pragma unroll
    for (int f = 0; f < 8; f++) {
        const int row = m0 + (f >> 2) * 128 + wr * 64 + (f & 3) * 16 + r16;
#pragma unroll
        for (int j = 0; j < 4; j++) {
            const int col = n0 + (j >> 1) * 128 + wc * 32 + (j & 1) * 16 + quad * 4;
            float v0 = acc[f][j][0], v1 = acc[f][j][1],
                  v2 = acc[f][j][2], v3 = acc[f][j][3];
            if (biasMode == 1) {
                v0 += bz[col]; v1 += bz[col + 1];
                v2 += bz[col + 2]; v3 += bz[col + 3];
            } else if (biasMode == 2) {
                const float bv = bz[row];
                v0 += bv; v1 += bv; v2 += bv; v3 += bv;
            }
            const size_t idx = (size_t)row * ldc + col;
            if (OUT_F16) {
                half4 hv = {(_Float16)v0, (_Float16)v1, (_Float16)v2, (_Float16)v3};
                *(half4*)&Ch[idx] = hv;
            } else {
                float4 fv = {v0, v1, v2, v3};
                *(float4*)&Cf[idx] = fv;
            }
        }
    }
}

// ---------------------------------------------------------------------------
// in-place fp16 softmax over rows of 512, scaled by 0.25 (head mean).
// ---------------------------------------------------------------------------
__global__ __launch_bounds__(256)
void softmax_f16(_Float16* __restrict__ S)
{
    const int row  = blockIdx.x * 4 + (threadIdx.x >> 6);
    const int lane = threadIdx.x & 63;
    _Float16* s = S + (size_t)row * 512 + lane * 8;
    half8 h = *(const half8*)s;
    float v[8];
    float mx = -1e30f;
#pragma unroll
    for (int j = 0; j < 8; j++) { v[j] = (float)h[j]; mx = fmaxf(mx, v[j]); }
#pragma unroll
    for (int off = 32; off; off >>= 1) mx = fmaxf(mx, __shfl_xor(mx, off));
    float sum = 0.f;
#pragma unroll
    for (int j = 0; j < 8; j++) { v[j] = __expf(v[j] - mx); sum += v[j]; }
#pragma unroll
    for (int off = 32; off; off >>= 1) sum += __shfl_xor(sum, off);
    const float inv = 0.25f / sum;
#pragma unroll
    for (int j = 0; j < 8; j++) h[j] = (_Float16)(v[j] * inv);
    *(half8*)s = h;
}

__global__ __launch_bounds__(256)
void cvt_f32_f16(const float* __restrict__ in, _Float16* __restrict__ out)
{
    const size_t i = ((size_t)blockIdx.x * blockDim.x + threadIdx.x) * 4;
    const float4 f = *(const float4*)(in + i);
    out[i + 0] = (_Float16)f.x;
    out[i + 1] = (_Float16)f.y;
    out[i + 2] = (_Float16)f.z;
    out[i + 3] = (_Float16)f.w;
}

// in [G][R][C] -> out [G][C][R], fp32 -> fp16
__global__ __launch_bounds__(256)
void transpose_cvt(const float* __restrict__ in, _Float16* __restrict__ out,
                   int R, int C)
{
    __shared__ float tile[32][33];
    const int g  = blockIdx.z;
    const int c0 = blockIdx.x * 32;
    const int r0 = blockIdx.y * 32;
    const float* inp  = in  + (size_t)g * R * C;
    _Float16*    outp = out + (size_t)g * R * C;
#pragma unroll
    for (int i = threadIdx.y; i < 32; i += 8)
        tile[i][threadIdx.x] = inp[(size_t)(r0 + i) * C + c0 + threadIdx.x];
    __syncthreads();
#pragma unroll
    for (int i = threadIdx.y; i < 32; i += 8)
        outp[(size_t)(c0 + i) * R + r0 + threadIdx.x] = (_Float16)tile[threadIdx.x][i];
}

// w[h][d] = sum_e Wk[h][d][e] * bq[h][e]
__global__ __launch_bounds__(256)
void wk_bq(const float* __restrict__ kq_w, const float* __restrict__ kq_b,
           float* __restrict__ w, int dinShift)
{
    const int t = blockIdx.x * 256 + threadIdx.x;
    const int h = t >> dinShift;
    const int d = t & ((1 << dinShift) - 1);
    const float* wk = kq_w + ((size_t)(h << dinShift) + d) * (2 * DH_);
    const float* bq = kq_b + (size_t)h * 2 * DH_ + DH_;
    float s = 0.f;
    for (int e = 0; e < DH_; e++) s += wk[e] * bq[e];
    w[t] = s;
}

// be1p[h][o] = sum_d e_b1[h][d] * projwT[o][d]
__global__ __launch_bounds__(256)
void fold_bias(const _Float16* __restrict__ projwT, const float* __restrict__ e_b1,
               float* __restrict__ be1p)
{
    const int t = blockIdx.x * 256 + threadIdx.x;   // t < H*DOUT
    const int h = t >> 8;
    const int o = t & 255;
    const _Float16* pw = projwT + (size_t)o * DH_;
    const float*    eb = e_b1 + (size_t)h * DH_;
    float s = 0.f;
    for (int d = 0; d < DH_; d++) s += (float)pw[d] * eb[d];
    be1p[t] = s;
}

// V[b][h][n] = x[b*N+n, :] . w[h, :]   — one wave per row, 4 heads at once
__global__ __launch_bounds__(256)
void compute_v(const _Float16* __restrict__ x, const float* __restrict__ w,
               float* __restrict__ V, int Kin)
{
    const int row  = blockIdx.x * 4 + (threadIdx.x >> 6);
    const int lane = threadIdx.x & 63;
    const int b = row >> 9, n = row & 511;
    const _Float16* xr = x + (size_t)row * Kin;
    float s0 = 0.f, s1 = 0.f, s2 = 0.f, s3 = 0.f;
    const int iters = Kin >> 6;
    for (int j = 0; j < iters; j++) {
        const int idx = lane + j * 64;
        const float xv = (float)xr[idx];
        s0 += xv * w[idx];
        s1 += xv * w[Kin + idx];
        s2 += xv * w[2 * Kin + idx];
        s3 += xv * w[3 * Kin + idx];
    }
#pragma unroll
    for (int off = 32; off; off >>= 1) {
        s0 += __shfl_xor(s0, off); s1 += __shfl_xor(s1, off);
        s2 += __shfl_xor(s2, off); s3 += __shfl_xor(s3, off);
    }
    if (lane == 0) {
        float* vb = V + ((size_t)b * H_) * N_ + n;
        vb[0] = s0; vb[N_] = s1; vb[2 * N_] = s2; vb[3 * N_] = s3;
    }
}

// ---------------------------------------------------------------------------
extern "C" void kernel_launch(void* const* d_in, const int* in_sizes, int n_in,
                              void* d_out, int out_size, void* d_ws, size_t ws_size,
                              hipStream_t stream)
{
    (void)in_sizes; (void)n_in; (void)out_size;

    static bool attr_set = false;
    if (!attr_set) {
        hipFuncSetAttribute((const void*)gemm256<true>,
                            hipFuncAttributeMaxDynamicSharedMemorySize, 131072);
        hipFuncSetAttribute((const void*)gemm256<false>,
                            hipFuncAttributeMaxDynamicSharedMemorySize, 131072);
        attr_set = true;
    }

    const float* x      = (const float*)d_in[0];
    const float* e_w0   = (const float*)d_in[1];
    const float* e_b0   = (const float*)d_in[2];
    const float* kq_w0  = (const float*)d_in[3];
    const float* kq_b0  = (const float*)d_in[4];
    const float* e_w1   = (const float*)d_in[5];
    const float* e_b1   = (const float*)d_in[6];
    const float* kq_w1  = (const float*)d_in[7];
    const float* kq_b1  = (const float*)d_in[8];
    const float* proj_w = (const float*)d_in[9];
    const float* proj_b = (const float*)d_in[10];
    float* out = (float*)d_out;

    char* ws = (char*)d_ws;
    size_t off = 0;
    auto alloc = [&](size_t bytes) -> char* {
        char* p = ws + off;
        off += (bytes + 255) & ~(size_t)255;
        return p;
    };

    // persistent (~62 MB)
    _Float16* x16    = (_Float16*)alloc((size_t)BN_ * DIN_ * 2);
    _Float16* h1_16  = (_Float16*)alloc((size_t)BN_ * DH_ * 2);
    _Float16* kq0_16 = (_Float16*)alloc((size_t)H_ * DIN_ * 2 * DH_ * 2);
    _Float16* kq1_16 = (_Float16*)alloc((size_t)H_ * DH_ * 2 * DH_ * 2);
    _Float16* ew1_16 = (_Float16*)alloc((size_t)H_ * DH_ * DH_ * 2);
    _Float16* ewT0   = (_Float16*)alloc((size_t)H_ * DH_ * DIN_ * 2);
    _Float16* projwT = (_Float16*)alloc((size_t)DOUT_ * DH_ * 2);
    _Float16* Mt0    = (_Float16*)alloc((size_t)H_ * DIN_ * DIN_ * 2);
    _Float16* Mt1    = (_Float16*)alloc((size_t)H_ * DH_ * DH_ * 2);
    _Float16* We1pT  = (_Float16*)alloc((size_t)H_ * DOUT_ * DH_ * 2);
    float*    be1p   = (float*)alloc((size_t)H_ * DOUT_ * 4);
    float*    w0     = (float*)alloc((size_t)H_ * DIN_ * 4);
    float*    w1     = (float*)alloc((size_t)H_ * DH_ * 4);
    float*    Vb     = (float*)alloc((size_t)B_ * H_ * N_ * 4);

    const size_t persist = off;
    const size_t SLACK    = 1u << 20;
    const size_t SC_FULL  = (size_t)B_ * H_ * N_ * N_ * 2;    // 128 MiB
    const size_t EMB_FULL = (size_t)B_ * H_ * DH_ * N_ * 2;   // 128 MiB
    auto tcBytes = [](int ch) { return (size_t)ch * N_ * H_ * DH_ * 2; };
    auto chunkBytes = [&](int ch) {
        return tcBytes(ch)
             + (size_t)ch * H_ * N_ * N_ * 2
             + (size_t)ch * H_ * DH_ * N_ * 2;
    };

    // mode 2: full-batch prologue + deferred full-batch PV
    // mode 1: chunked prologue (CH=32) + deferred full-batch PV
    // mode 0: fully chunked (legacy, verified)
    int mode, CH;
    if (ws_size >= persist + tcBytes(64) + SC_FULL + EMB_FULL + SLACK)      { mode = 2; CH = 64; }
    else if (ws_size >= persist + tcBytes(32) + SC_FULL + EMB_FULL + SLACK) { mode = 1; CH = 32; }
    else {
        mode = 0; CH = 8;
        if (ws_size >= persist + chunkBytes(32) + SLACK) CH = 32;
        else if (ws_size >= persist + chunkBytes(16) + SLACK) CH = 16;
    }
    const int NCH = B_ / CH;

    _Float16 *Tc, *Sc, *embc;
    if (mode >= 1) {
        Tc   = (_Float16*)alloc(tcBytes(CH));
        Sc   = (_Float16*)alloc(SC_FULL);
        embc = (_Float16*)alloc(EMB_FULL);
    } else {
        Tc   = (_Float16*)alloc(tcBytes(CH));
        Sc   = (_Float16*)alloc((size_t)CH * H_ * N_ * N_ * 2);
        embc = (_Float16*)alloc((size_t)CH * H_ * DH_ * N_ * 2);
    }

    auto gemm = [&](bool outF16,
                    const _Float16* A, long long aS1, long long aS2, int lda, long long aSeg,
                    const _Float16* Bp, long long bS1, long long bS2, int ldb, long long bSeg,
                    void* C, long long cS1, long long cS2, int ldc,
                    int M, int Nn, int K, int batches, int zShift,
                    const float* bias, int biasMode, long long biasS1, long long biasS2) {
        const bool big = (M % 256 == 0) && (Nn % 256 == 0) && (K % 128 == 0)
                       && ((long long)(M >> 8) * (Nn >> 8) * batches >= 32);
        if (big) {
            dim3 grid(Nn / 256, M / 256, batches), block(512);
            if (outF16)
                gemm256<true><<<grid, block, 131072, stream>>>(A, aS1, aS2, lda, aSeg,
                    Bp, bS1, bS2, ldb, bSeg, C, cS1, cS2, ldc, K, bias, biasMode, biasS1, biasS2, zShift);
            else
                gemm256<false><<<grid, block, 131072, stream>>>(A, aS1, aS2, lda, aSeg,
                    Bp, bS1, bS2, ldb, bSeg, C, cS1, cS2, ldc, K, bias, biasMode, biasS1, biasS2, zShift);
        } else {
            dim3 grid(Nn / 128, M / 128, batches), block(256);
            if (outF16)
                gemm_f16<true><<<grid, block, 0, stream>>>(A, aS1, aS2, lda, aSeg,
                    Bp, bS1, bS2, ldb, bSeg, C, cS1, cS2, ldc, K, bias, biasMode, biasS1, biasS2, zShift);
            else
                gemm_f16<false><<<grid, block, 0, stream>>>(A, aS1, aS2, lda, aSeg,
                    Bp, bS1, bS2, ldb, bSeg, C, cS1, cS2, ldc, K, bias, biasMode, biasS1, biasS2, zShift);
        }
    };

    // --- preprocessing -----------------------------------------------------
    cvt_f32_f16<<<BN_ * DIN_ / 1024, 256, 0, stream>>>(x, x16);
    cvt_f32_f16<<<H_ * DIN_ * 2 * DH_ / 1024, 256, 0, stream>>>(kq_w0, kq0_16);
    cvt_f32_f16<<<H_ * DH_ * 2 * DH_ / 1024, 256, 0, stream>>>(kq_w1, kq1_16);
    cvt_f32_f16<<<H_ * DH_ * DH_ / 1024, 256, 0, stream>>>(e_w1, ew1_16);
    transpose_cvt<<<dim3(DH_ / 32, DIN_ / 32, H_), dim3(32, 8), 0, stream>>>(e_w0, ewT0, DIN_, DH_);
    transpose_cvt<<<dim3(DOUT_ / 32, DH_ / 32, 1), dim3(32, 8), 0, stream>>>(proj_w, projwT, DH_, DOUT_);

    // Mt_h = Wk_h * Wq_h^T  (so T = x * Mt^T = x * (Wq Wk^T))
    gemm(true, kq0_16, 0, (long long)DIN_ * 2 * DH_, 2 * DH_, 512,
         kq0_16 + DH_, 0, (long long)DIN_ * 2 * DH_, 2 * DH_, 512,
         Mt0, 0, (long long)DIN_ * DIN_, DIN_,
         DIN_, DIN_, DH_, H_, 2, nullptr, 0, 0, 0);
    gemm(true, kq1_16, 0, (long long)DH_ * 2 * DH_, 2 * DH_, 512,
         kq1_16 + DH_, 0, (long long)DH_ * 2 * DH_, 2 * DH_, 512,
         Mt1, 0, (long long)DH_ * DH_, DH_,
         DH_, DH_, DH_, H_, 2, nullptr, 0, 0, 0);
    // We1pT[h][o][d] = sum_d' projwT[o][d'] * e_w1[h][d][d']
    gemm(true, projwT, 0, 0, DH_, 512,
         ew1_16, 0, (long long)DH_ * DH_, DH_, 512,
         We1pT, 0, (long long)DOUT_ * DH_, DH_,
         DOUT_, DH_, DH_, H_, 2, nullptr, 0, 0, 0);
    fold_bias<<<H_ * DOUT_ / 256, 256, 0, stream>>>(projwT, e_b1, be1p);
    wk_bq<<<H_ * DIN_ / 256, 256, 0, stream>>>(kq_w0, kq_b0, w0, 8);
    wk_bq<<<H_ * DH_ / 256, 256, 0, stream>>>(kq_w1, kq_b1, w1, 9);

    const long long SB = (long long)N_ * N_;

    // --- two attention blocks ---------------------------------------------
    for (int blk = 0; blk < 2; blk++) {
        const _Float16* xin = blk ? h1_16 : x16;
        const int       Kin = blk ? DH_ : DIN_;
        const int       E   = blk ? DOUT_ : DH_;   // emb cols per head
        const _Float16* Mt  = blk ? Mt1 : Mt0;
        const float*    wv  = blk ? w1 : w0;

        compute_v<<<BN_ / 4, 256, 0, stream>>>(xin, wv, Vb, Kin);

        for (int c = 0; c < NCH; c++) {
            const _Float16* xc = xin + (size_t)c * CH * N_ * Kin;
            _Float16* Scp  = Sc   + (mode >= 1 ? (size_t)c * CH * H_ * SB : 0);
            _Float16* embp = embc + (mode >= 1 ? (size_t)c * CH * H_ * E * N_ : 0);

            // T[q, h*Kin+d'] = sum_d x[q,d] * Mt[h*Kin+d', d]
            gemm(true, xc, 0, 0, Kin, 512,
                 Mt, 0, 0, Kin, 512,
                 Tc, 0, 0, H_ * Kin,
                 CH * N_, H_ * Kin, Kin, 1, 0, nullptr, 0, 0, 0);
            // S[b][h][q][k] = T[b,h] * x_b^T + V[b][h][k]
            gemm(true, Tc, (long long)N_ * H_ * Kin, Kin, H_ * Kin, 512,
                 xc, (long long)N_ * Kin, 0, Kin, 512,
                 Scp, (long long)H_ * SB, SB, N_,
                 N_, N_, Kin, CH * H_, 2,
                 Vb + (size_t)c * CH * H_ * N_, 1, (long long)H_ * N_, N_);
            // P = softmax(S) * 0.25, in place fp16
            softmax_f16<<<CH * H_ * N_ / 4, 256, 0, stream>>>(Scp);

            if (blk == 0) {
                // embT[b][h*DH+e][n] = ewT0 @ x_b^T + e_b0
                gemm(true, ewT0, 0, 0, Kin, 512,
                     xc, (long long)N_ * Kin, 0, Kin, 512,
                     embp, (long long)H_ * DH_ * N_, 0, N_,
                     H_ * DH_, N_, Kin, CH, 0, e_b0, 2, 0, 0);
                if (mode == 0) {
                    // h1[b][q][e] = sum_{h,n} P * embT   (segmented K = H*N)
                    gemm(true, Scp, (long long)H_ * SB, 0, N_, SB,
                         embp, (long long)H_ * DH_ * N_, 0, N_, (long long)DH_ * N_,
                         h1_16 + (size_t)c * CH * N_ * DH_, (long long)N_ * DH_, 0, DH_,
                         N_, DH_, H_ * N_, CH, 0, nullptr, 0, 0, 0);
                }
            } else {
                // embWT[b][h*DOUT+o][n] = We1pT @ h1_b^T + be1p
                gemm(true, We1pT, 0, 0, DH_, 512,
                     xc, (long long)N_ * DH_, 0, DH_, 512,
                     embp, (long long)H_ * DOUT_ * N_, 0, N_,
                     H_ * DOUT_, N_, DH_, CH, 0, be1p, 2, 0, 0);
                if (mode == 0) {
                    // out[b][q][o] = sum_{h,n} P * embWT + proj_b  (fp32)
                    gemm(false, Scp, (long long)H_ * SB, 0, N_, SB,
                         embp, (long long)H_ * DOUT_ * N_, 0, N_, (long long)DOUT_ * N_,
                         out + (size_t)c * CH * N_ * DOUT_, (long long)N_ * DOUT_, 0, DOUT_,
                         N_, DOUT_, H_ * N_, CH, 0, proj_b, 1, 0, 0);
                }
            }
        }

        if (mode >= 1) {
            if (blk == 0) {
                // deferred full-batch PV: grid 2x2x64 = 256 wgs (1/CU)
                gemm(true, Sc, (long long)H_ * SB, 0, N_, SB,
                     embc, (long long)H_ * DH_ * N_, 0, N_, (long long)DH_ * N_,
                     h1_16, (long long)N_ * DH_, 0, DH_,
                     N_, DH_, H_ * N_, B_, 0, nullptr, 0, 0, 0);
            } else {
                // deferred full-batch PV: grid 1x2x64 = 128 wgs
                gemm(false, Sc, (long long)H_ * SB, 0, N_, SB,
                     embc, (long long)H_ * DOUT_ * N_, 0, N_, (long long)DOUT_ * N_,
                     out, (long long)N_ * DOUT_, 0, DOUT_,
                     N_, DOUT_, H_ * N_, B_, 0, proj_b, 1, 0, 0);
            }
        }
    }
}

// Round 4
// 1016.330 us; speedup vs baseline: 1.0451x; 1.0451x over previous
//
#include <hip/hip_runtime.h>

typedef _Float16 half8 __attribute__((ext_vector_type(8)));
typedef _Float16 half4 __attribute__((ext_vector_type(4)));
typedef float floatx4 __attribute__((ext_vector_type(4)));

#define B_    64
#define N_    512
#define DIN_  256
#define DH_   512
#define DOUT_ 256
#define H_    4
#define BN_   (B_ * N_)   // 32768

// raw waitcnt immediates (gfx9: vmcnt[3:0]|[15:14], exp[6:4], lgkm[11:8])
#define WAIT_VM4_LGKM0() __builtin_amdgcn_s_waitcnt(0x0074)  // vm<=4, lgkm<=0
#define WAIT_VM0_LGKM0() __builtin_amdgcn_s_waitcnt(0x0070)  // vm<=0, lgkm<=0
#define WAIT_VM4()       __builtin_amdgcn_s_waitcnt(0x0F74)  // vm<=4 only
#define WAIT_VM0()       __builtin_amdgcn_s_waitcnt(0x0F70)  // vm<=0 only
#define MEMBAR()         __asm__ __volatile__("" ::: "memory")
#define BAR()            do { MEMBAR(); __builtin_amdgcn_s_barrier(); MEMBAR(); } while (0)

__device__ static inline void async_copy16(const _Float16* g, _Float16* l) {
    __builtin_amdgcn_global_load_lds(
        (const __attribute__((address_space(1))) void*)g,
        (__attribute__((address_space(3))) void*)l, 16, 0, 0);
}

// ---------------------------------------------------------------------------
// OLD GEMM (small preprocessing shapes only): C[M,N]=A[M,K]*B[N,K]^T(+bias)
// 128x128 tile, BK=32, 4 waves, triple-buffered. K-segments fixed at 512.
// ---------------------------------------------------------------------------
template <bool OUT_F16>
__global__ __launch_bounds__(256)
void gemm_f16(const _Float16* __restrict__ A, long long aS1, long long aS2, int lda, long long aSeg,
              const _Float16* __restrict__ B, long long bS1, long long bS2, int ldb, long long bSeg,
              void* __restrict__ Cv, long long cS1, long long cS2, int ldc,
              int K, const float* __restrict__ bias, int biasMode,
              long long biasS1, long long biasS2, int zShift)
{
    __shared__ __align__(16) _Float16 As[3][128 * 32];
    __shared__ __align__(16) _Float16 Bs[3][128 * 32];

    const int tid  = threadIdx.x;
    const int wave = tid >> 6;
    const int lane = tid & 63;
    const int quad = lane >> 4;
    const int r16  = lane & 15;

    const int z  = blockIdx.z;
    const int z1 = z >> zShift;
    const int z2 = z & ((1 << zShift) - 1);

    const int gx = gridDim.x, gy = gridDim.y;
    const int T = gx * gy;
    int lin = blockIdx.y * gx + blockIdx.x;
    int id2 = (T & 7) ? lin : ((lin & 7) * (T >> 3) + (lin >> 3));
    const int m0 = (id2 / gx) * 128;
    const int n0 = (id2 % gx) * 128;

    const int srow = lane >> 2;
    const int scol = (((lane & 3) ^ ((lane >> 3) & 3))) * 8;

    const _Float16* gaRow = A + z1 * aS1 + z2 * aS2
                              + (long long)(m0 + wave * 32 + srow) * lda + scol;
    const _Float16* gbRow = B + z1 * bS1 + z2 * bS2
                              + (long long)(n0 + wave * 32 + srow) * ldb + scol;

    const int wm = (wave >> 1) * 64;
    const int wn = (wave & 1) * 64;
    const int gl = (quad ^ ((r16 >> 1) & 3)) * 8;

    floatx4 acc[4][4];
#pragma unroll
    for (int i = 0; i < 4; i++)
#pragma unroll
        for (int j = 0; j < 4; j++) acc[i][j] = (floatx4){0.f, 0.f, 0.f, 0.f};

    auto stage = [&](int p, int k0) {
        const _Float16* a = gaRow + (long long)(k0 >> 9) * aSeg + (k0 & 511);
        const _Float16* b = gbRow + (long long)(k0 >> 9) * bSeg + (k0 & 511);
        _Float16* la = &As[p][wave * 1024];
        _Float16* lb = &Bs[p][wave * 1024];
        async_copy16(a,                    la);
        async_copy16(a + (size_t)16 * lda, la + 512);
        async_copy16(b,                    lb);
        async_copy16(b + (size_t)16 * ldb, lb + 512);
    };

    auto compute = [&](int p) {
        half8 af[4], bf[4];
#pragma unroll
        for (int i = 0; i < 4; i++)
            af[i] = *(const half8*)&As[p][(wm + i * 16 + r16) * 32 + gl];
#pragma unroll
        for (int j = 0; j < 4; j++)
            bf[j] = *(const half8*)&Bs[p][(wn + j * 16 + r16) * 32 + gl];
#pragma unroll
        for (int i = 0; i < 4; i++)
#pragma unroll
            for (int j = 0; j < 4; j++)
                acc[i][j] = __builtin_amdgcn_mfma_f32_16x16x32_f16(
                    bf[j], af[i], acc[i][j], 0, 0, 0);
    };

    const int niter = K >> 5;
    stage(0, 0);
    stage(1, 32);
    int pNext = 2;
    int pCur  = 0;
    for (int it = 0; it < niter - 1; ++it) {
        MEMBAR(); WAIT_VM4_LGKM0();
        __builtin_amdgcn_s_barrier();
        MEMBAR();
        if (it + 2 < niter) stage(pNext, (it + 2) << 5);
        compute(pCur);
        MEMBAR();
        pNext = (pNext == 2) ? 0 : pNext + 1;
        pCur  = (pCur  == 2) ? 0 : pCur  + 1;
    }
    MEMBAR(); WAIT_VM0_LGKM0();
    __builtin_amdgcn_s_barrier(); MEMBAR();
    compute(pCur);

    const float* bz = bias + z1 * biasS1 + z2 * biasS2;
    float*    Cf = (float*)Cv    + z1 * cS1 + z2 * cS2;
    _Float16* Ch = (_Float16*)Cv + z1 * cS1 + z2 * cS2;
#pragma unroll
    for (int i = 0; i < 4; i++) {
        const int row = m0 + wm + i * 16 + r16;
#pragma unroll
        for (int j = 0; j < 4; j++) {
            const int col = n0 + wn + j * 16 + quad * 4;
            float v0 = acc[i][j][0], v1 = acc[i][j][1],
                  v2 = acc[i][j][2], v3 = acc[i][j][3];
            if (biasMode == 1) {
                v0 += bz[col]; v1 += bz[col + 1];
                v2 += bz[col + 2]; v3 += bz[col + 3];
            } else if (biasMode == 2) {
                const float bv = bz[row];
                v0 += bv; v1 += bv; v2 += bv; v3 += bv;
            }
            const size_t idx = (size_t)row * ldc + col;
            if (OUT_F16) {
                half4 hv = {(_Float16)v0, (_Float16)v1, (_Float16)v2, (_Float16)v3};
                *(half4*)&Ch[idx] = hv;
            } else {
                float4 fv = {v0, v1, v2, v3};
                *(float4*)&Cf[idx] = fv;
            }
        }
    }
}

// ---------------------------------------------------------------------------
// 256x256 tile, 8 waves (2x4), BK=64, 8-phase interleave, counted vmcnt,
// XOR-swizzled LDS via pre-swizzled global source, setprio around MFMA.
// STATIC buffer map: even K-tiles -> buf0 (read p0-p3), odd -> buf1 (p4-p7).
// B col-half-0 fragments kept in regs across the K-tile (p3/p7 reg-only).
//
// Generalized K segmentation: segment size = 1<<aSh elements (aSh>=7), i.e.
// K-tile tt2 maps to (tt2 >> (aSh-6))*aSeg + ((tt2 & mask)<<6). aSh=9 gives
// the original 512-elem segments; aSh=8 gives 256 (for [h][q][d] operands).
// ---------------------------------------------------------------------------
template <bool OUT_F16>
__global__ __launch_bounds__(512, 2)
void gemm256(const _Float16* __restrict__ A, long long aS1, long long aS2, int lda, long long aSeg, int aSh,
             const _Float16* __restrict__ B, long long bS1, long long bS2, int ldb, long long bSeg, int bSh,
             void* __restrict__ Cv, long long cS1, long long cS2, int ldc,
             int K, const float* __restrict__ bias, int biasMode,
             long long biasS1, long long biasS2, int zShift)
{
    extern __shared__ __align__(16) _Float16 lds[];
    _Float16* AsB = lds;                 // [2][256*64]
    _Float16* BsB = lds + 2 * 256 * 64;  // [2][256*64]

    const int tid  = threadIdx.x;
    const int wave = tid >> 6;        // 0..7
    const int lane = tid & 63;
    const int quad = lane >> 4;
    const int r16  = lane & 15;
    const int wr   = wave >> 2;       // 0..1
    const int wc   = wave & 3;        // 0..3

    const int z  = blockIdx.z;
    const int z1 = z >> zShift;
    const int z2 = z & ((1 << zShift) - 1);

    const int aTSh = aSh - 6, aTMk = (1 << aTSh) - 1;
    const int bTSh = bSh - 6, bTMk = (1 << bTSh) - 1;

    const int gx = gridDim.x, gy = gridDim.y;
    const int T = gx * gy;
    int lin = blockIdx.y * gx + blockIdx.x;
    int id2 = (T & 7) ? lin : ((lin & 7) * (T >> 3) + (lin >> 3));
    const int m0 = (id2 / gx) * 256;
    const int n0 = (id2 % gx) * 256;

    const int sr  = tid >> 3;                       // 0..63
    const int swz = ((tid & 7) ^ (sr & 7)) * 8;     // swizzled k-offset (elems)
    const _Float16* gaA = A + z1 * aS1 + z2 * aS2 + (long long)(m0 + sr) * lda + swz;
    const _Float16* gbB = B + z1 * bS1 + z2 * bS2 + (long long)(n0 + sr) * ldb + swz;

    const int arow = wr * 64 + r16;
    const int brow = wc * 32 + r16;
    const int rsw  = r16 & 7;
    const int gxk0 = (quad ^ rsw) * 8;
    const int gxk1 = ((4 + quad) ^ rsw) * 8;

    floatx4 acc[8][4];
#pragma unroll
    for (int i = 0; i < 8; i++)
#pragma unroll
        for (int j = 0; j < 4; j++) acc[i][j] = (floatx4){0.f, 0.f, 0.f, 0.f};

    half8 af[4][2], bf0s[2][2], bf1s[2][2];

    auto stageA = [&](int buf, int h, int tt2) {
        const _Float16* s = gaA + (long long)(h * 128) * lda
                          + (long long)(tt2 >> aTSh) * aSeg + ((tt2 & aTMk) << 6);
        _Float16* d = AsB + buf * 16384 + h * 8192 + wave * 512;
        async_copy16(s, d);
        async_copy16(s + (long long)64 * lda, d + 4096);
    };
    auto stageB = [&](int buf, int h, int tt2) {
        const _Float16* s = gbB + (long long)(h * 128) * ldb
                          + (long long)(tt2 >> bTSh) * bSeg + ((tt2 & bTMk) << 6);
        _Float16* d = BsB + buf * 16384 + h * 8192 + wave * 512;
        async_copy16(s, d);
        async_copy16(s + (long long)64 * ldb, d + 4096);
    };

#define LOAD_AF(RH, BUF) do { \
    const _Float16* ab_ = AsB + (BUF) * 16384 + ((RH) * 128 + arow) * 64; \
    _Pragma("unroll") \
    for (int i5 = 0; i5 < 4; i5++) { \
        af[i5][0] = *(const half8*)(ab_ + i5 * 1024 + gxk0); \
        af[i5][1] = *(const half8*)(ab_ + i5 * 1024 + gxk1); \
    } \
} while (0)

#define LOAD_BF(DST, CH, BUF) do { \
    const _Float16* bb_ = BsB + (BUF) * 16384 + ((CH) * 128 + brow) * 64; \
    _Pragma("unroll") \
    for (int j5 = 0; j5 < 2; j5++) { \
        DST[j5][0] = *(const half8*)(bb_ + j5 * 1024 + gxk0); \
        DST[j5][1] = *(const half8*)(bb_ + j5 * 1024 + gxk1); \
    } \
} while (0)

#define MFMA16(RH, CH, BFS) do { \
    _Pragma("unroll") \
    for (int i6 = 0; i6 < 4; i6++) { \
        _Pragma("unroll") \
        for (int j6 = 0; j6 < 2; j6++) { \
            floatx4 c_ = acc[(RH) * 4 + i6][(CH) * 2 + j6]; \
            c_ = __builtin_amdgcn_mfma_f32_16x16x32_f16(BFS[j6][0], af[i6][0], c_, 0, 0, 0); \
            c_ = __builtin_amdgcn_mfma_f32_16x16x32_f16(BFS[j6][1], af[i6][1], c_, 0, 0, 0); \
            acc[(RH) * 4 + i6][(CH) * 2 + j6] = c_; \
        } \
    } \
} while (0)

    const int nit = K >> 7;   // iterations of 2 K-tiles (K % 128 == 0)

    // prologue: tile0 -> buf0 (all 4 halves), tile1 -> buf1 (A0, B1)
    stageA(0, 0, 0);
    stageB(0, 1, 0);
    stageA(0, 1, 0);
    stageB(0, 0, 0);
    stageA(1, 0, 1);
    stageB(1, 1, 1);
    WAIT_VM4();
    BAR();

    for (int it = 0; it < nit; ++it) {
        const int tt = it * 2;
        const bool full = (it < nit - 1);

        // ---- p0: (0,0) of tile tt  [buf0]
        LOAD_AF(0, 0); LOAD_BF(bf0s, 0, 0);
        stageA(1, 1, tt + 1);
        BAR();
        __builtin_amdgcn_s_setprio(1); MFMA16(0, 0, bf0s); __builtin_amdgcn_s_setprio(0);
        BAR();
        // ---- p1: (0,1)
        LOAD_BF(bf1s, 1, 0);
        stageB(1, 0, tt + 1);
        BAR();
        __builtin_amdgcn_s_setprio(1); MFMA16(0, 1, bf1s); __builtin_amdgcn_s_setprio(0);
        BAR();
        // ---- p2: (1,1)
        LOAD_AF(1, 0);
        if (full) stageA(0, 0, tt + 2);
        BAR();
        __builtin_amdgcn_s_setprio(1); MFMA16(1, 1, bf1s); __builtin_amdgcn_s_setprio(0);
        BAR();
        // ---- p3: (1,0)  regs-only  + W0
        if (full) stageB(0, 1, tt + 2);
        BAR();
        __builtin_amdgcn_s_setprio(1); MFMA16(1, 0, bf0s); __builtin_amdgcn_s_setprio(0);
        if (full) WAIT_VM4(); else WAIT_VM0();
        BAR();
        // ---- p4: (0,0) of tile tt+1  [buf1]
        LOAD_AF(0, 1); LOAD_BF(bf0s, 0, 1);
        if (full) stageA(0, 1, tt + 2);
        BAR();
        __builtin_amdgcn_s_setprio(1); MFMA16(0, 0, bf0s); __builtin_amdgcn_s_setprio(0);
        BAR();
        // ---- p5: (0,1)
        LOAD_BF(bf1s, 1, 1);
        if (full) stageB(0, 0, tt + 2);
        BAR();
        __builtin_amdgcn_s_setprio(1); MFMA16(0, 1, bf1s); __builtin_amdgcn_s_setprio(0);
        BAR();
        // ---- p6: (1,1)
        LOAD_AF(1, 1);
        if (full) stageA(1, 0, tt + 3);
        BAR();
        __builtin_amdgcn_s_setprio(1); MFMA16(1, 1, bf1s); __builtin_amdgcn_s_setprio(0);
        BAR();
        // ---- p7: (1,0)  regs-only  + W1
        if (full) stageB(1, 1, tt + 3);
        BAR();
        __builtin_amdgcn_s_setprio(1); MFMA16(1, 0, bf0s); __builtin_amdgcn_s_setprio(0);
        if (full) WAIT_VM4();
        BAR();
    }

#undef LOAD_AF
#undef LOAD_BF
#undef MFMA16

    // epilogue (swapped layout)
    const float* bz = bias + z1 * biasS1 + z2 * biasS2;
    float*    Cf = (float*)Cv    + z1 * cS1 + z2 * cS2;
    _Float16* Ch = (_Float16*)Cv + z1 * cS1 + z2 * cS2;
#pragma unroll
    for (int f = 0; f < 8; f++) {
        const int row = m0 + (f >> 2) * 128 + wr * 64 + (f & 3) * 16 + r16;
#pragma unroll
        for (int j = 0; j < 4; j++) {
            const int col = n0 + (j >> 1) * 128 + wc * 32 + (j & 1) * 16 + quad * 4;
            float v0 = acc[f][j][0], v1 = acc[f][j][1],
                  v2 = acc[f][j][2], v3 = acc[f][j][3];
            if (biasMode == 1) {
                v0 += bz[col]; v1 += bz[col + 1];
                v2 += bz[col + 2]; v3 += bz[col + 3];
            } else if (biasMode == 2) {
                const float bv = bz[row];
                v0 += bv; v1 += bv; v2 += bv; v3 += bv;
            }
            const size_t idx = (size_t)row * ldc + col;
            if (OUT_F16) {
                half4 hv = {(_Float16)v0, (_Float16)v1, (_Float16)v2, (_Float16)v3};
                *(half4*)&Ch[idx] = hv;
            } else {
                float4 fv = {v0, v1, v2, v3};
                *(float4*)&Cf[idx] = fv;
            }
        }
    }
}

// ---------------------------------------------------------------------------
// in-place fp16 softmax over rows of 512, scaled by 0.25 (head mean).
// ---------------------------------------------------------------------------
__global__ __launch_bounds__(256)
void softmax_f16(_Float16* __restrict__ S)
{
    const int row  = blockIdx.x * 4 + (threadIdx.x >> 6);
    const int lane = threadIdx.x & 63;
    _Float16* s = S + (size_t)row * 512 + lane * 8;
    half8 h = *(const half8*)s;
    float v[8];
    float mx = -1e30f;
#pragma unroll
    for (int j = 0; j < 8; j++) { v[j] = (float)h[j]; mx = fmaxf(mx, v[j]); }
#pragma unroll
    for (int off = 32; off; off >>= 1) mx = fmaxf(mx, __shfl_xor(mx, off));
    float sum = 0.f;
#pragma unroll
    for (int j = 0; j < 8; j++) { v[j] = __expf(v[j] - mx); sum += v[j]; }
#pragma unroll
    for (int off = 32; off; off >>= 1) sum += __shfl_xor(sum, off);
    const float inv = 0.25f / sum;
#pragma unroll
    for (int j = 0; j < 8; j++) h[j] = (_Float16)(v[j] * inv);
    *(half8*)s = h;
}

__global__ __launch_bounds__(256)
void cvt_f32_f16(const float* __restrict__ in, _Float16* __restrict__ out)
{
    const size_t i = ((size_t)blockIdx.x * blockDim.x + threadIdx.x) * 4;
    const float4 f = *(const float4*)(in + i);
    out[i + 0] = (_Float16)f.x;
    out[i + 1] = (_Float16)f.y;
    out[i + 2] = (_Float16)f.z;
    out[i + 3] = (_Float16)f.w;
}

// in [G][R][C] -> out [G][C][R], fp32 -> fp16
__global__ __launch_bounds__(256)
void transpose_cvt(const float* __restrict__ in, _Float16* __restrict__ out,
                   int R, int C)
{
    __shared__ float tile[32][33];
    const int g  = blockIdx.z;
    const int c0 = blockIdx.x * 32;
    const int r0 = blockIdx.y * 32;
    const float* inp  = in  + (size_t)g * R * C;
    _Float16*    outp = out + (size_t)g * R * C;
#pragma unroll
    for (int i = threadIdx.y; i < 32; i += 8)
        tile[i][threadIdx.x] = inp[(size_t)(r0 + i) * C + c0 + threadIdx.x];
    __syncthreads();
#pragma unroll
    for (int i = threadIdx.y; i < 32; i += 8)
        outp[(size_t)(c0 + i) * R + r0 + threadIdx.x] = (_Float16)tile[threadIdx.x][i];
}

// w[h][d] = sum_e Wk[h][d][e] * bq[h][e]
__global__ __launch_bounds__(256)
void wk_bq(const float* __restrict__ kq_w, const float* __restrict__ kq_b,
           float* __restrict__ w, int dinShift)
{
    const int t = blockIdx.x * 256 + threadIdx.x;
    const int h = t >> dinShift;
    const int d = t & ((1 << dinShift) - 1);
    const float* wk = kq_w + ((size_t)(h << dinShift) + d) * (2 * DH_);
    const float* bq = kq_b + (size_t)h * 2 * DH_ + DH_;
    float s = 0.f;
    for (int e = 0; e < DH_; e++) s += wk[e] * bq[e];
    w[t] = s;
}

// be1p[h][o] = sum_d e_b1[h][d] * projwT[o][d]
__global__ __launch_bounds__(256)
void fold_bias(const _Float16* __restrict__ projwT, const float* __restrict__ e_b1,
               float* __restrict__ be1p)
{
    const int t = blockIdx.x * 256 + threadIdx.x;   // t < H*DOUT
    const int h = t >> 8;
    const int o = t & 255;
    const _Float16* pw = projwT + (size_t)o * DH_;
    const float*    eb = e_b1 + (size_t)h * DH_;
    float s = 0.f;
    for (int d = 0; d < DH_; d++) s += (float)pw[d] * eb[d];
    be1p[t] = s;
}

// sb0[e] = 0.25 * sum_h e_b0[h][e]   (e < DH_)
__global__ __launch_bounds__(256)
void sum_b0(const float* __restrict__ eb, float* __restrict__ sb)
{
    const int e = blockIdx.x * 256 + threadIdx.x;
    sb[e] = 0.25f * (eb[e] + eb[DH_ + e] + eb[2 * DH_ + e] + eb[3 * DH_ + e]);
}

// V[b][h][n] = x[b*N+n, :] . w[h, :]   — one wave per row, 4 heads at once
__global__ __launch_bounds__(256)
void compute_v(const _Float16* __restrict__ x, const float* __restrict__ w,
               float* __restrict__ V, int Kin)
{
    const int row  = blockIdx.x * 4 + (threadIdx.x >> 6);
    const int lane = threadIdx.x & 63;
    const int b = row >> 9, n = row & 511;
    const _Float16* xr = x + (size_t)row * Kin;
    float s0 = 0.f, s1 = 0.f, s2 = 0.f, s3 = 0.f;
    const int iters = Kin >> 6;
    for (int j = 0; j < iters; j++) {
        const int idx = lane + j * 64;
        const float xv = (float)xr[idx];
        s0 += xv * w[idx];
        s1 += xv * w[Kin + idx];
        s2 += xv * w[2 * Kin + idx];
        s3 += xv * w[3 * Kin + idx];
    }
#pragma unroll
    for (int off = 32; off; off >>= 1) {
        s0 += __shfl_xor(s0, off); s1 += __shfl_xor(s1, off);
        s2 += __shfl_xor(s2, off); s3 += __shfl_xor(s3, off);
    }
    if (lane == 0) {
        float* vb = V + ((size_t)b * H_) * N_ + n;
        vb[0] = s0; vb[N_] = s1; vb[2 * N_] = s2; vb[3 * N_] = s3;
    }
}

// ---------------------------------------------------------------------------
extern "C" void kernel_launch(void* const* d_in, const int* in_sizes, int n_in,
                              void* d_out, int out_size, void* d_ws, size_t ws_size,
                              hipStream_t stream)
{
    (void)in_sizes; (void)n_in; (void)out_size;

    static bool attr_set = false;
    if (!attr_set) {
        hipFuncSetAttribute((const void*)gemm256<true>,
                            hipFuncAttributeMaxDynamicSharedMemorySize, 131072);
        hipFuncSetAttribute((const void*)gemm256<false>,
                            hipFuncAttributeMaxDynamicSharedMemorySize, 131072);
        attr_set = true;
    }

    const float* x      = (const float*)d_in[0];
    const float* e_w0   = (const float*)d_in[1];
    const float* e_b0   = (const float*)d_in[2];
    const float* kq_w0  = (const float*)d_in[3];
    const float* kq_b0  = (const float*)d_in[4];
    const float* e_w1   = (const float*)d_in[5];
    const float* e_b1   = (const float*)d_in[6];
    const float* kq_w1  = (const float*)d_in[7];
    const float* kq_b1  = (const float*)d_in[8];
    const float* proj_w = (const float*)d_in[9];
    const float* proj_b = (const float*)d_in[10];
    float* out = (float*)d_out;

    char* ws = (char*)d_ws;
    size_t off = 0;
    auto alloc = [&](size_t bytes) -> char* {
        char* p = ws + off;
        off += (bytes + 255) & ~(size_t)255;
        return p;
    };

    // --- persistent (~73 MB incl. xT) --------------------------------------
    _Float16* x16    = (_Float16*)alloc((size_t)BN_ * DIN_ * 2);
    _Float16* h1_16  = (_Float16*)alloc((size_t)BN_ * DH_ * 2);
    _Float16* ewT0   = (_Float16*)alloc((size_t)H_ * DH_ * DIN_ * 2);
    _Float16* projwT = (_Float16*)alloc((size_t)DOUT_ * DH_ * 2);
    _Float16* Mt0    = (_Float16*)alloc((size_t)H_ * DIN_ * DIN_ * 2);
    _Float16* Mt1    = (_Float16*)alloc((size_t)H_ * DH_ * DH_ * 2);
    _Float16* We1pT  = (_Float16*)alloc((size_t)H_ * DOUT_ * DH_ * 2);
    float*    be1p   = (float*)alloc((size_t)H_ * DOUT_ * 4);
    float*    w0     = (float*)alloc((size_t)H_ * DIN_ * 4);
    float*    w1     = (float*)alloc((size_t)H_ * DH_ * 4);
    float*    sb0    = (float*)alloc((size_t)DH_ * 4);
    float*    Vb     = (float*)alloc((size_t)B_ * H_ * N_ * 4);
    _Float16* xT     = (_Float16*)alloc((size_t)BN_ * DIN_ * 2);   // [b][d][n]

    const size_t persistAll = off;
    const long long SB = (long long)N_ * N_;
    const size_t SC_FULL  = (size_t)B_ * H_ * N_ * N_ * 2;       // 134.2 MB
    const size_t SC_CHUNK = SC_FULL / 2;                          // 67.1 MB
    const size_t A2_SZ    = (size_t)BN_ * H_ * DIN_ * 2;          // 67.1 MB
    const size_t SLACK    = 1u << 20;

    // tier A: full-batch blk0 + deferred full-batch blk1 PV  (~276 MB)
    // tier B: CH=32 chunks, G-path blk0, chunked emb/PV blk1  (~217 MB)
    const bool tierA = ws_size >= persistAll + SC_FULL + A2_SZ + SLACK;

    _Float16* Sc = (_Float16*)alloc(tierA ? SC_FULL : SC_CHUNK);
    _Float16* A2 = (_Float16*)alloc(A2_SZ);

    // transient cvt buffers live inside A2 (dead before A2's first GEMM use)
    _Float16* kq0_16 = A2;                                        // 2.1 MB
    _Float16* kq1_16 = kq0_16 + (size_t)H_ * DIN_ * 2 * DH_;      // 4.2 MB
    _Float16* ew1_16 = kq1_16 + (size_t)H_ * DH_ * 2 * DH_;       // 2.1 MB

    auto gemm = [&](bool outF16,
                    const _Float16* A, long long aS1, long long aS2, int lda, long long aSeg,
                    const _Float16* Bp, long long bS1, long long bS2, int ldb, long long bSeg,
                    void* C, long long cS1, long long cS2, int ldc,
                    int M, int Nn, int K, int batches, int zShift,
                    const float* bias, int biasMode, long long biasS1, long long biasS2,
                    int aSh, int bSh) {
        const bool big = ((M % 256 == 0) && (Nn % 256 == 0) && (K % 128 == 0)
                       && ((long long)(M >> 8) * (Nn >> 8) * batches >= 32))
                       || aSh != 9 || bSh != 9;
        if (big) {
            dim3 grid(Nn / 256, M / 256, batches), block(512);
            if (outF16)
                gemm256<true><<<grid, block, 131072, stream>>>(A, aS1, aS2, lda, aSeg, aSh,
                    Bp, bS1, bS2, ldb, bSeg, bSh, C, cS1, cS2, ldc, K, bias, biasMode, biasS1, biasS2, zShift);
            else
                gemm256<false><<<grid, block, 131072, stream>>>(A, aS1, aS2, lda, aSeg, aSh,
                    Bp, bS1, bS2, ldb, bSeg, bSh, C, cS1, cS2, ldc, K, bias, biasMode, biasS1, biasS2, zShift);
        } else {
            dim3 grid(Nn / 128, M / 128, batches), block(256);
            if (outF16)
                gemm_f16<true><<<grid, block, 0, stream>>>(A, aS1, aS2, lda, aSeg,
                    Bp, bS1, bS2, ldb, bSeg, C, cS1, cS2, ldc, K, bias, biasMode, biasS1, biasS2, zShift);
            else
                gemm_f16<false><<<grid, block, 0, stream>>>(A, aS1, aS2, lda, aSeg,
                    Bp, bS1, bS2, ldb, bSeg, C, cS1, cS2, ldc, K, bias, biasMode, biasS1, biasS2, zShift);
        }
    };

    // --- preprocessing -----------------------------------------------------
    cvt_f32_f16<<<BN_ * DIN_ / 1024, 256, 0, stream>>>(x, x16);
    cvt_f32_f16<<<H_ * DIN_ * 2 * DH_ / 1024, 256, 0, stream>>>(kq_w0, kq0_16);
    cvt_f32_f16<<<H_ * DH_ * 2 * DH_ / 1024, 256, 0, stream>>>(kq_w1, kq1_16);
    cvt_f32_f16<<<H_ * DH_ * DH_ / 1024, 256, 0, stream>>>(e_w1, ew1_16);
    transpose_cvt<<<dim3(DH_ / 32, DIN_ / 32, H_), dim3(32, 8), 0, stream>>>(e_w0, ewT0, DIN_, DH_);
    transpose_cvt<<<dim3(DOUT_ / 32, DH_ / 32, 1), dim3(32, 8), 0, stream>>>(proj_w, projwT, DH_, DOUT_);
    transpose_cvt<<<dim3(DIN_ / 32, N_ / 32, B_), dim3(32, 8), 0, stream>>>(x, xT, N_, DIN_);
    sum_b0<<<DH_ / 256, 256, 0, stream>>>(e_b0, sb0);

    // Mt_h = Wk_h * Wq_h^T  (so T = x * Mt^T = x * (Wq Wk^T))
    gemm(true, kq0_16, 0, (long long)DIN_ * 2 * DH_, 2 * DH_, 512,
         kq0_16 + DH_, 0, (long long)DIN_ * 2 * DH_, 2 * DH_, 512,
         Mt0, 0, (long long)DIN_ * DIN_, DIN_,
         DIN_, DIN_, DH_, H_, 2, nullptr, 0, 0, 0, 9, 9);
    gemm(true, kq1_16, 0, (long long)DH_ * 2 * DH_, 2 * DH_, 512,
         kq1_16 + DH_, 0, (long long)DH_ * 2 * DH_, 2 * DH_, 512,
         Mt1, 0, (long long)DH_ * DH_, DH_,
         DH_, DH_, DH_, H_, 2, nullptr, 0, 0, 0, 9, 9);
    // We1pT[h][o][d] = sum_d' projwT[o][d'] * e_w1[h][d][d']
    gemm(true, projwT, 0, 0, DH_, 512,
         ew1_16, 0, (long long)DH_ * DH_, DH_, 512,
         We1pT, 0, (long long)DOUT_ * DH_, DH_,
         DOUT_, DH_, DH_, H_, 2, nullptr, 0, 0, 0, 9, 9);
    fold_bias<<<H_ * DOUT_ / 256, 256, 0, stream>>>(projwT, e_b1, be1p);
    wk_bq<<<H_ * DIN_ / 256, 256, 0, stream>>>(kq_w0, kq_b0, w0, 8);
    wk_bq<<<H_ * DH_ / 256, 256, 0, stream>>>(kq_w1, kq_b1, w1, 9);

    // --- block 0: G-path (h1 = sum_h (P_h x) W_h + 0.25 sum_h b_h) ---------
    {
        const int CH0  = tierA ? B_ : 32;
        const int NCH0 = B_ / CH0;
        compute_v<<<BN_ / 4, 256, 0, stream>>>(x16, w0, Vb, DIN_);
        for (int c = 0; c < NCH0; c++) {
            const _Float16* xc  = x16 + (size_t)c * CH0 * N_ * DIN_;
            const _Float16* xTc = xT  + (size_t)c * CH0 * DIN_ * N_;
            // T0 -> A2 (overwrites dead cvt scratch)
            gemm(true, xc, 0, 0, DIN_, 512,
                 Mt0, 0, 0, DIN_, 512,
                 A2, 0, 0, H_ * DIN_,
                 CH0 * N_, H_ * DIN_, DIN_, 1, 0, nullptr, 0, 0, 0, 9, 9);
            // S = T x^T + V
            gemm(true, A2, (long long)N_ * H_ * DIN_, DIN_, H_ * DIN_, 512,
                 xc, (long long)N_ * DIN_, 0, DIN_, 512,
                 Sc, (long long)H_ * SB, SB, N_,
                 N_, N_, DIN_, CH0 * H_, 2,
                 Vb + (size_t)c * CH0 * H_ * N_, 1, (long long)H_ * N_, N_, 9, 9);
            softmax_f16<<<CH0 * H_ * N_ / 4, 256, 0, stream>>>(Sc);
            // G[b][h][q][d] = P[b,h] . x_b  -> A2 (Tc0 dead)
            gemm(true, Sc, (long long)H_ * SB, SB, N_, 512,
                 xTc, (long long)DIN_ * N_, 0, N_, 512,
                 A2, (long long)H_ * N_ * DIN_, (long long)N_ * DIN_, DIN_,
                 N_, DIN_, N_, CH0 * H_, 2, nullptr, 0, 0, 0, 9, 9);
            // h1[b][q][e] = sum_{h,d} G . ewT0 + sb0   (K = H*DIN, 256-seg)
            gemm(true, A2, (long long)H_ * N_ * DIN_, 0, DIN_, (long long)N_ * DIN_,
                 ewT0, 0, 0, DIN_, (long long)DH_ * DIN_,
                 h1_16 + (size_t)c * CH0 * N_ * DH_, (long long)N_ * DH_, 0, DH_,
                 N_, DH_, H_ * DIN_, CH0, 0, sb0, 1, 0, 0, 8, 8);
        }
    }

    // --- block 1 -----------------------------------------------------------
    {
        compute_v<<<BN_ / 4, 256, 0, stream>>>(h1_16, w1, Vb, DH_);
        for (int c = 0; c < 2; c++) {
            const _Float16* hc = h1_16 + (size_t)c * 32 * N_ * DH_;
            _Float16* Scp = tierA ? Sc + (size_t)c * 32 * H_ * SB : Sc;
            // T1 -> A2
            gemm(true, hc, 0, 0, DH_, 512,
                 Mt1, 0, 0, DH_, 512,
                 A2, 0, 0, H_ * DH_,
                 32 * N_, H_ * DH_, DH_, 1, 0, nullptr, 0, 0, 0, 9, 9);
            // S1
            gemm(true, A2, (long long)N_ * H_ * DH_, DH_, H_ * DH_, 512,
                 hc, (long long)N_ * DH_, 0, DH_, 512,
                 Scp, (long long)H_ * SB, SB, N_,
                 N_, N_, DH_, 32 * H_, 2,
                 Vb + (size_t)c * 32 * H_ * N_, 1, (long long)H_ * N_, N_, 9, 9);
            softmax_f16<<<32 * H_ * N_ / 4, 256, 0, stream>>>(Scp);
            if (!tierA) {
                // embW chunk -> A2 (Tc1 dead)
                gemm(true, We1pT, 0, 0, DH_, 512,
                     hc, (long long)N_ * DH_, 0, DH_, 512,
                     A2, (long long)H_ * DOUT_ * N_, 0, N_,
                     H_ * DOUT_, N_, DH_, 32, 0, be1p, 2, 0, 0, 9, 9);
                // PV chunk (fp32 out)
                gemm(false, Scp, (long long)H_ * SB, 0, N_, SB,
                     A2, (long long)H_ * DOUT_ * N_, 0, N_, (long long)DOUT_ * N_,
                     out + (size_t)c * 32 * N_ * DOUT_, (long long)N_ * DOUT_, 0, DOUT_,
                     N_, DOUT_, H_ * N_, 32, 0, proj_b, 1, 0, 0, 9, 9);
            }
        }
        if (tierA) {
            // embW full -> A2 (Tc1 dead after last S1)
            gemm(true, We1pT, 0, 0, DH_, 512,
                 h1_16, (long long)N_ * DH_, 0, DH_, 512,
                 A2, (long long)H_ * DOUT_ * N_, 0, N_,
                 H_ * DOUT_, N_, DH_, B_, 0, be1p, 2, 0, 0, 9, 9);
            // deferred full-batch PV (128 wgs)
            gemm(false, Sc, (long long)H_ * SB, 0, N_, SB,
                 A2, (long long)H_ * DOUT_ * N_, 0, N_, (long long)DOUT_ * N_,
                 out, (long long)N_ * DOUT_, 0, DOUT_,
                 N_, DOUT_, H_ * N_, B_, 0, proj_b, 1, 0, 0, 9, 9);
        }
    }
}

// Round 5
// 989.009 us; speedup vs baseline: 1.0740x; 1.0276x over previous
//
#include <hip/hip_runtime.h>

typedef _Float16 half8 __attribute__((ext_vector_type(8)));
typedef _Float16 half4 __attribute__((ext_vector_type(4)));
typedef float floatx4 __attribute__((ext_vector_type(4)));

#define B_    64
#define N_    512
#define DIN_  256
#define DH_   512
#define DOUT_ 256
#define H_    4
#define BN_   (B_ * N_)   // 32768

// raw waitcnt immediates (gfx9: vmcnt[3:0]|[15:14], exp[6:4], lgkm[11:8])
#define WAIT_VM4_LGKM0() __builtin_amdgcn_s_waitcnt(0x0074)  // vm<=4, lgkm<=0
#define WAIT_VM0_LGKM0() __builtin_amdgcn_s_waitcnt(0x0070)  // vm<=0, lgkm<=0
#define WAIT_VM4()       __builtin_amdgcn_s_waitcnt(0x0F74)  // vm<=4 only
#define WAIT_VM0()       __builtin_amdgcn_s_waitcnt(0x0F70)  // vm<=0 only
#define MEMBAR()         __asm__ __volatile__("" ::: "memory")
#define BAR()            do { MEMBAR(); __builtin_amdgcn_s_barrier(); MEMBAR(); } while (0)

__device__ static inline void async_copy16(const _Float16* g, _Float16* l) {
    __builtin_amdgcn_global_load_lds(
        (const __attribute__((address_space(1))) void*)g,
        (__attribute__((address_space(3))) void*)l, 16, 0, 0);
}

// ---------------------------------------------------------------------------
// 128x128-tile GEMM (BK=32, 4 waves, triple-buffered): used for small
// preprocessing shapes AND for main shapes whose 256^2 grid would be
// starved (<192 wgs) — 4x more workgroups fill the chip. 512-elem K-segs.
// ---------------------------------------------------------------------------
template <bool OUT_F16>
__global__ __launch_bounds__(256)
void gemm_f16(const _Float16* __restrict__ A, long long aS1, long long aS2, int lda, long long aSeg,
              const _Float16* __restrict__ B, long long bS1, long long bS2, int ldb, long long bSeg,
              void* __restrict__ Cv, long long cS1, long long cS2, int ldc,
              int K, const float* __restrict__ bias, int biasMode,
              long long biasS1, long long biasS2, int zShift)
{
    __shared__ __align__(16) _Float16 As[3][128 * 32];
    __shared__ __align__(16) _Float16 Bs[3][128 * 32];

    const int tid  = threadIdx.x;
    const int wave = tid >> 6;
    const int lane = tid & 63;
    const int quad = lane >> 4;
    const int r16  = lane & 15;

    const int z  = blockIdx.z;
    const int z1 = z >> zShift;
    const int z2 = z & ((1 << zShift) - 1);

    const int gx = gridDim.x, gy = gridDim.y;
    const int T = gx * gy;
    int lin = blockIdx.y * gx + blockIdx.x;
    int id2 = (T & 7) ? lin : ((lin & 7) * (T >> 3) + (lin >> 3));
    const int m0 = (id2 / gx) * 128;
    const int n0 = (id2 % gx) * 128;

    const int srow = lane >> 2;
    const int scol = (((lane & 3) ^ ((lane >> 3) & 3))) * 8;

    const _Float16* gaRow = A + z1 * aS1 + z2 * aS2
                              + (long long)(m0 + wave * 32 + srow) * lda + scol;
    const _Float16* gbRow = B + z1 * bS1 + z2 * bS2
                              + (long long)(n0 + wave * 32 + srow) * ldb + scol;

    const int wm = (wave >> 1) * 64;
    const int wn = (wave & 1) * 64;
    const int gl = (quad ^ ((r16 >> 1) & 3)) * 8;

    floatx4 acc[4][4];
#pragma unroll
    for (int i = 0; i < 4; i++)
#pragma unroll
        for (int j = 0; j < 4; j++) acc[i][j] = (floatx4){0.f, 0.f, 0.f, 0.f};

    auto stage = [&](int p, int k0) {
        const _Float16* a = gaRow + (long long)(k0 >> 9) * aSeg + (k0 & 511);
        const _Float16* b = gbRow + (long long)(k0 >> 9) * bSeg + (k0 & 511);
        _Float16* la = &As[p][wave * 1024];
        _Float16* lb = &Bs[p][wave * 1024];
        async_copy16(a,                    la);
        async_copy16(a + (size_t)16 * lda, la + 512);
        async_copy16(b,                    lb);
        async_copy16(b + (size_t)16 * ldb, lb + 512);
    };

    auto compute = [&](int p) {
        half8 af[4], bf[4];
#pragma unroll
        for (int i = 0; i < 4; i++)
            af[i] = *(const half8*)&As[p][(wm + i * 16 + r16) * 32 + gl];
#pragma unroll
        for (int j = 0; j < 4; j++)
            bf[j] = *(const half8*)&Bs[p][(wn + j * 16 + r16) * 32 + gl];
#pragma unroll
        for (int i = 0; i < 4; i++)
#pragma unroll
            for (int j = 0; j < 4; j++)
                acc[i][j] = __builtin_amdgcn_mfma_f32_16x16x32_f16(
                    bf[j], af[i], acc[i][j], 0, 0, 0);
    };

    const int niter = K >> 5;
    stage(0, 0);
    stage(1, 32);
    int pNext = 2;
    int pCur  = 0;
    for (int it = 0; it < niter - 1; ++it) {
        MEMBAR(); WAIT_VM4_LGKM0();
        __builtin_amdgcn_s_barrier();
        MEMBAR();
        if (it + 2 < niter) stage(pNext, (it + 2) << 5);
        compute(pCur);
        MEMBAR();
        pNext = (pNext == 2) ? 0 : pNext + 1;
        pCur  = (pCur  == 2) ? 0 : pCur  + 1;
    }
    MEMBAR(); WAIT_VM0_LGKM0();
    __builtin_amdgcn_s_barrier(); MEMBAR();
    compute(pCur);

    const float* bz = bias + z1 * biasS1 + z2 * biasS2;
    float*    Cf = (float*)Cv    + z1 * cS1 + z2 * cS2;
    _Float16* Ch = (_Float16*)Cv + z1 * cS1 + z2 * cS2;
#pragma unroll
    for (int i = 0; i < 4; i++) {
        const int row = m0 + wm + i * 16 + r16;
#pragma unroll
        for (int j = 0; j < 4; j++) {
            const int col = n0 + wn + j * 16 + quad * 4;
            float v0 = acc[i][j][0], v1 = acc[i][j][1],
                  v2 = acc[i][j][2], v3 = acc[i][j][3];
            if (biasMode == 1) {
                v0 += bz[col]; v1 += bz[col + 1];
                v2 += bz[col + 2]; v3 += bz[col + 3];
            } else if (biasMode == 2) {
                const float bv = bz[row];
                v0 += bv; v1 += bv; v2 += bv; v3 += bv;
            }
            const size_t idx = (size_t)row * ldc + col;
            if (OUT_F16) {
                half4 hv = {(_Float16)v0, (_Float16)v1, (_Float16)v2, (_Float16)v3};
                *(half4*)&Ch[idx] = hv;
            } else {
                float4 fv = {v0, v1, v2, v3};
                *(float4*)&Cf[idx] = fv;
            }
        }
    }
}

// ---------------------------------------------------------------------------
// 256x256 tile, 8 waves (2x4), BK=64, 8-phase interleave, counted vmcnt,
// XOR-swizzled LDS via pre-swizzled global source, setprio around MFMA.
// STATIC buffer map: even K-tiles -> buf0 (read p0-p3), odd -> buf1 (p4-p7).
// B col-half-0 fragments kept in regs across the K-tile (p3/p7 reg-only).
// Generalized K segmentation: segment size = 1<<aSh elements (aSh>=7).
// ---------------------------------------------------------------------------
template <bool OUT_F16>
__global__ __launch_bounds__(512, 2)
void gemm256(const _Float16* __restrict__ A, long long aS1, long long aS2, int lda, long long aSeg, int aSh,
             const _Float16* __restrict__ B, long long bS1, long long bS2, int ldb, long long bSeg, int bSh,
             void* __restrict__ Cv, long long cS1, long long cS2, int ldc,
             int K, const float* __restrict__ bias, int biasMode,
             long long biasS1, long long biasS2, int zShift)
{
    extern __shared__ __align__(16) _Float16 lds[];
    _Float16* AsB = lds;                 // [2][256*64]
    _Float16* BsB = lds + 2 * 256 * 64;  // [2][256*64]

    const int tid  = threadIdx.x;
    const int wave = tid >> 6;        // 0..7
    const int lane = tid & 63;
    const int quad = lane >> 4;
    const int r16  = lane & 15;
    const int wr   = wave >> 2;       // 0..1
    const int wc   = wave & 3;        // 0..3

    const int z  = blockIdx.z;
    const int z1 = z >> zShift;
    const int z2 = z & ((1 << zShift) - 1);

    const int aTSh = aSh - 6, aTMk = (1 << aTSh) - 1;
    const int bTSh = bSh - 6, bTMk = (1 << bTSh) - 1;

    const int gx = gridDim.x, gy = gridDim.y;
    const int T = gx * gy;
    int lin = blockIdx.y * gx + blockIdx.x;
    int id2 = (T & 7) ? lin : ((lin & 7) * (T >> 3) + (lin >> 3));
    const int m0 = (id2 / gx) * 256;
    const int n0 = (id2 % gx) * 256;

    const int sr  = tid >> 3;                       // 0..63
    const int swz = ((tid & 7) ^ (sr & 7)) * 8;     // swizzled k-offset (elems)
    const _Float16* gaA = A + z1 * aS1 + z2 * aS2 + (long long)(m0 + sr) * lda + swz;
    const _Float16* gbB = B + z1 * bS1 + z2 * bS2 + (long long)(n0 + sr) * ldb + swz;

    const int arow = wr * 64 + r16;
    const int brow = wc * 32 + r16;
    const int rsw  = r16 & 7;
    const int gxk0 = (quad ^ rsw) * 8;
    const int gxk1 = ((4 + quad) ^ rsw) * 8;

    floatx4 acc[8][4];
#pragma unroll
    for (int i = 0; i < 8; i++)
#pragma unroll
        for (int j = 0; j < 4; j++) acc[i][j] = (floatx4){0.f, 0.f, 0.f, 0.f};

    half8 af[4][2], bf0s[2][2], bf1s[2][2];

    auto stageA = [&](int buf, int h, int tt2) {
        const _Float16* s = gaA + (long long)(h * 128) * lda
                          + (long long)(tt2 >> aTSh) * aSeg + ((tt2 & aTMk) << 6);
        _Float16* d = AsB + buf * 16384 + h * 8192 + wave * 512;
        async_copy16(s, d);
        async_copy16(s + (long long)64 * lda, d + 4096);
    };
    auto stageB = [&](int buf, int h, int tt2) {
        const _Float16* s = gbB + (long long)(h * 128) * ldb
                          + (long long)(tt2 >> bTSh) * bSeg + ((tt2 & bTMk) << 6);
        _Float16* d = BsB + buf * 16384 + h * 8192 + wave * 512;
        async_copy16(s, d);
        async_copy16(s + (long long)64 * ldb, d + 4096);
    };

#define LOAD_AF(RH, BUF) do { \
    const _Float16* ab_ = AsB + (BUF) * 16384 + ((RH) * 128 + arow) * 64; \
    _Pragma("unroll") \
    for (int i5 = 0; i5 < 4; i5++) { \
        af[i5][0] = *(const half8*)(ab_ + i5 * 1024 + gxk0); \
        af[i5][1] = *(const half8*)(ab_ + i5 * 1024 + gxk1); \
    } \
} while (0)

#define LOAD_BF(DST, CH, BUF) do { \
    const _Float16* bb_ = BsB + (BUF) * 16384 + ((CH) * 128 + brow) * 64; \
    _Pragma("unroll") \
    for (int j5 = 0; j5 < 2; j5++) { \
        DST[j5][0] = *(const half8*)(bb_ + j5 * 1024 + gxk0); \
        DST[j5][1] = *(const half8*)(bb_ + j5 * 1024 + gxk1); \
    } \
} while (0)

#define MFMA16(RH, CH, BFS) do { \
    _Pragma("unroll") \
    for (int i6 = 0; i6 < 4; i6++) { \
        _Pragma("unroll") \
        for (int j6 = 0; j6 < 2; j6++) { \
            floatx4 c_ = acc[(RH) * 4 + i6][(CH) * 2 + j6]; \
            c_ = __builtin_amdgcn_mfma_f32_16x16x32_f16(BFS[j6][0], af[i6][0], c_, 0, 0, 0); \
            c_ = __builtin_amdgcn_mfma_f32_16x16x32_f16(BFS[j6][1], af[i6][1], c_, 0, 0, 0); \
            acc[(RH) * 4 + i6][(CH) * 2 + j6] = c_; \
        } \
    } \
} while (0)

    const int nit = K >> 7;   // iterations of 2 K-tiles (K % 128 == 0)

    // prologue: tile0 -> buf0 (all 4 halves), tile1 -> buf1 (A0, B1)
    stageA(0, 0, 0);
    stageB(0, 1, 0);
    stageA(0, 1, 0);
    stageB(0, 0, 0);
    stageA(1, 0, 1);
    stageB(1, 1, 1);
    WAIT_VM4();
    BAR();

    for (int it = 0; it < nit; ++it) {
        const int tt = it * 2;
        const bool full = (it < nit - 1);

        // ---- p0: (0,0) of tile tt  [buf0]
        LOAD_AF(0, 0); LOAD_BF(bf0s, 0, 0);
        stageA(1, 1, tt + 1);
        BAR();
        __builtin_amdgcn_s_setprio(1); MFMA16(0, 0, bf0s); __builtin_amdgcn_s_setprio(0);
        BAR();
        // ---- p1: (0,1)
        LOAD_BF(bf1s, 1, 0);
        stageB(1, 0, tt + 1);
        BAR();
        __builtin_amdgcn_s_setprio(1); MFMA16(0, 1, bf1s); __builtin_amdgcn_s_setprio(0);
        BAR();
        // ---- p2: (1,1)
        LOAD_AF(1, 0);
        if (full) stageA(0, 0, tt + 2);
        BAR();
        __builtin_amdgcn_s_setprio(1); MFMA16(1, 1, bf1s); __builtin_amdgcn_s_setprio(0);
        BAR();
        // ---- p3: (1,0)  regs-only  + W0
        if (full) stageB(0, 1, tt + 2);
        BAR();
        __builtin_amdgcn_s_setprio(1); MFMA16(1, 0, bf0s); __builtin_amdgcn_s_setprio(0);
        if (full) WAIT_VM4(); else WAIT_VM0();
        BAR();
        // ---- p4: (0,0) of tile tt+1  [buf1]
        LOAD_AF(0, 1); LOAD_BF(bf0s, 0, 1);
        if (full) stageA(0, 1, tt + 2);
        BAR();
        __builtin_amdgcn_s_setprio(1); MFMA16(0, 0, bf0s); __builtin_amdgcn_s_setprio(0);
        BAR();
        // ---- p5: (0,1)
        LOAD_BF(bf1s, 1, 1);
        if (full) stageB(0, 0, tt + 2);
        BAR();
        __builtin_amdgcn_s_setprio(1); MFMA16(0, 1, bf1s); __builtin_amdgcn_s_setprio(0);
        BAR();
        // ---- p6: (1,1)
        LOAD_AF(1, 1);
        if (full) stageA(1, 0, tt + 3);
        BAR();
        __builtin_amdgcn_s_setprio(1); MFMA16(1, 1, bf1s); __builtin_amdgcn_s_setprio(0);
        BAR();
        // ---- p7: (1,0)  regs-only  + W1
        if (full) stageB(1, 1, tt + 3);
        BAR();
        __builtin_amdgcn_s_setprio(1); MFMA16(1, 0, bf0s); __builtin_amdgcn_s_setprio(0);
        if (full) WAIT_VM4();
        BAR();
    }

#undef LOAD_AF
#undef LOAD_BF
#undef MFMA16

    // epilogue (swapped layout)
    const float* bz = bias + z1 * biasS1 + z2 * biasS2;
    float*    Cf = (float*)Cv    + z1 * cS1 + z2 * cS2;
    _Float16* Ch = (_Float16*)Cv + z1 * cS1 + z2 * cS2;
#pragma unroll
    for (int f = 0; f < 8; f++) {
        const int row = m0 + (f >> 2) * 128 + wr * 64 + (f & 3) * 16 + r16;
#pragma unroll
        for (int j = 0; j < 4; j++) {
            const int col = n0 + (j >> 1) * 128 + wc * 32 + (j & 1) * 16 + quad * 4;
            float v0 = acc[f][j][0], v1 = acc[f][j][1],
                  v2 = acc[f][j][2], v3 = acc[f][j][3];
            if (biasMode == 1) {
                v0 += bz[col]; v1 += bz[col + 1];
                v2 += bz[col + 2]; v3 += bz[col + 3];
            } else if (biasMode == 2) {
                const float bv = bz[row];
                v0 += bv; v1 += bv; v2 += bv; v3 += bv;
            }
            const size_t idx = (size_t)row * ldc + col;
            if (OUT_F16) {
                half4 hv = {(_Float16)v0, (_Float16)v1, (_Float16)v2, (_Float16)v3};
                *(half4*)&Ch[idx] = hv;
            } else {
                float4 fv = {v0, v1, v2, v3};
                *(float4*)&Cf[idx] = fv;
            }
        }
    }
}

// ---------------------------------------------------------------------------
// in-place fp16 softmax over rows of 512, scaled by 0.25 (head mean).
// ---------------------------------------------------------------------------
__global__ __launch_bounds__(256)
void softmax_f16(_Float16* __restrict__ S)
{
    const int row  = blockIdx.x * 4 + (threadIdx.x >> 6);
    const int lane = threadIdx.x & 63;
    _Float16* s = S + (size_t)row * 512 + lane * 8;
    half8 h = *(const half8*)s;
    float v[8];
    float mx = -1e30f;
#pragma unroll
    for (int j = 0; j < 8; j++) { v[j] = (float)h[j]; mx = fmaxf(mx, v[j]); }
#pragma unroll
    for (int off = 32; off; off >>= 1) mx = fmaxf(mx, __shfl_xor(mx, off));
    float sum = 0.f;
#pragma unroll
    for (int j = 0; j < 8; j++) { v[j] = __expf(v[j] - mx); sum += v[j]; }
#pragma unroll
    for (int off = 32; off; off >>= 1) sum += __shfl_xor(sum, off);
    const float inv = 0.25f / sum;
#pragma unroll
    for (int j = 0; j < 8; j++) h[j] = (_Float16)(v[j] * inv);
    *(half8*)s = h;
}

__global__ __launch_bounds__(256)
void cvt_f32_f16(const float* __restrict__ in, _Float16* __restrict__ out)
{
    const size_t i = ((size_t)blockIdx.x * blockDim.x + threadIdx.x) * 4;
    const float4 f = *(const float4*)(in + i);
    out[i + 0] = (_Float16)f.x;
    out[i + 1] = (_Float16)f.y;
    out[i + 2] = (_Float16)f.z;
    out[i + 3] = (_Float16)f.w;
}

// in [G][R][C] -> out [G][C][R], fp32 -> fp16
__global__ __launch_bounds__(256)
void transpose_cvt(const float* __restrict__ in, _Float16* __restrict__ out,
                   int R, int C)
{
    __shared__ float tile[32][33];
    const int g  = blockIdx.z;
    const int c0 = blockIdx.x * 32;
    const int r0 = blockIdx.y * 32;
    const float* inp  = in  + (size_t)g * R * C;
    _Float16*    outp = out + (size_t)g * R * C;
#pragma unroll
    for (int i = threadIdx.y; i < 32; i += 8)
        tile[i][threadIdx.x] = inp[(size_t)(r0 + i) * C + c0 + threadIdx.x];
    __syncthreads();
#pragma unroll
    for (int i = threadIdx.y; i < 32; i += 8)
        outp[(size_t)(c0 + i) * R + r0 + threadIdx.x] = (_Float16)tile[threadIdx.x][i];
}

// w[h][d] = sum_e Wk[h][d][e] * bq[h][e]
__global__ __launch_bounds__(256)
void wk_bq(const float* __restrict__ kq_w, const float* __restrict__ kq_b,
           float* __restrict__ w, int dinShift)
{
    const int t = blockIdx.x * 256 + threadIdx.x;
    const int h = t >> dinShift;
    const int d = t & ((1 << dinShift) - 1);
    const float* wk = kq_w + ((size_t)(h << dinShift) + d) * (2 * DH_);
    const float* bq = kq_b + (size_t)h * 2 * DH_ + DH_;
    float s = 0.f;
    for (int e = 0; e < DH_; e++) s += wk[e] * bq[e];
    w[t] = s;
}

// be1p[h][o] = sum_d e_b1[h][d] * projwT[o][d]
__global__ __launch_bounds__(256)
void fold_bias(const _Float16* __restrict__ projwT, const float* __restrict__ e_b1,
               float* __restrict__ be1p)
{
    const int t = blockIdx.x * 256 + threadIdx.x;   // t < H*DOUT
    const int h = t >> 8;
    const int o = t & 255;
    const _Float16* pw = projwT + (size_t)o * DH_;
    const float*    eb = e_b1 + (size_t)h * DH_;
    float s = 0.f;
    for (int d = 0; d < DH_; d++) s += (float)pw[d] * eb[d];
    be1p[t] = s;
}

// sb0[e] = 0.25 * sum_h e_b0[h][e]   (e < DH_)
__global__ __launch_bounds__(256)
void sum_b0(const float* __restrict__ eb, float* __restrict__ sb)
{
    const int e = blockIdx.x * 256 + threadIdx.x;
    sb[e] = 0.25f * (eb[e] + eb[DH_ + e] + eb[2 * DH_ + e] + eb[3 * DH_ + e]);
}

// V[b][h][n] = x[b*N+n, :] . w[h, :]   — one wave per row, 4 heads at once
__global__ __launch_bounds__(256)
void compute_v(const _Float16* __restrict__ x, const float* __restrict__ w,
               float* __restrict__ V, int Kin)
{
    const int row  = blockIdx.x * 4 + (threadIdx.x >> 6);
    const int lane = threadIdx.x & 63;
    const int b = row >> 9, n = row & 511;
    const _Float16* xr = x + (size_t)row * Kin;
    float s0 = 0.f, s1 = 0.f, s2 = 0.f, s3 = 0.f;
    const int iters = Kin >> 6;
    for (int j = 0; j < iters; j++) {
        const int idx = lane + j * 64;
        const float xv = (float)xr[idx];
        s0 += xv * w[idx];
        s1 += xv * w[Kin + idx];
        s2 += xv * w[2 * Kin + idx];
        s3 += xv * w[3 * Kin + idx];
    }
#pragma unroll
    for (int off = 32; off; off >>= 1) {
        s0 += __shfl_xor(s0, off); s1 += __shfl_xor(s1, off);
        s2 += __shfl_xor(s2, off); s3 += __shfl_xor(s3, off);
    }
    if (lane == 0) {
        float* vb = V + ((size_t)b * H_) * N_ + n;
        vb[0] = s0; vb[N_] = s1; vb[2 * N_] = s2; vb[3 * N_] = s3;
    }
}

// ---------------------------------------------------------------------------
extern "C" void kernel_launch(void* const* d_in, const int* in_sizes, int n_in,
                              void* d_out, int out_size, void* d_ws, size_t ws_size,
                              hipStream_t stream)
{
    (void)in_sizes; (void)n_in; (void)out_size;

    static bool attr_set = false;
    if (!attr_set) {
        hipFuncSetAttribute((const void*)gemm256<true>,
                            hipFuncAttributeMaxDynamicSharedMemorySize, 131072);
        hipFuncSetAttribute((const void*)gemm256<false>,
                            hipFuncAttributeMaxDynamicSharedMemorySize, 131072);
        attr_set = true;
    }

    const float* x      = (const float*)d_in[0];
    const float* e_w0   = (const float*)d_in[1];
    const float* e_b0   = (const float*)d_in[2];
    const float* kq_w0  = (const float*)d_in[3];
    const float* kq_b0  = (const float*)d_in[4];
    const float* e_w1   = (const float*)d_in[5];
    const float* e_b1   = (const float*)d_in[6];
    const float* kq_w1  = (const float*)d_in[7];
    const float* kq_b1  = (const float*)d_in[8];
    const float* proj_w = (const float*)d_in[9];
    const float* proj_b = (const float*)d_in[10];
    float* out = (float*)d_out;

    char* ws = (char*)d_ws;
    size_t off = 0;
    auto alloc = [&](size_t bytes) -> char* {
        char* p = ws + off;
        off += (bytes + 255) & ~(size_t)255;
        return p;
    };

    // --- persistent (~73 MB incl. xT) --------------------------------------
    _Float16* x16    = (_Float16*)alloc((size_t)BN_ * DIN_ * 2);
    _Float16* h1_16  = (_Float16*)alloc((size_t)BN_ * DH_ * 2);
    _Float16* ewT0   = (_Float16*)alloc((size_t)H_ * DH_ * DIN_ * 2);
    _Float16* projwT = (_Float16*)alloc((size_t)DOUT_ * DH_ * 2);
    _Float16* Mt0    = (_Float16*)alloc((size_t)H_ * DIN_ * DIN_ * 2);
    _Float16* Mt1    = (_Float16*)alloc((size_t)H_ * DH_ * DH_ * 2);
    _Float16* We1pT  = (_Float16*)alloc((size_t)H_ * DOUT_ * DH_ * 2);
    float*    be1p   = (float*)alloc((size_t)H_ * DOUT_ * 4);
    float*    w0     = (float*)alloc((size_t)H_ * DIN_ * 4);
    float*    w1     = (float*)alloc((size_t)H_ * DH_ * 4);
    float*    sb0    = (float*)alloc((size_t)DH_ * 4);
    float*    Vb     = (float*)alloc((size_t)B_ * H_ * N_ * 4);
    _Float16* xT     = (_Float16*)alloc((size_t)BN_ * DIN_ * 2);   // [b][d][n]

    const size_t persistAll = off;
    const long long SB = (long long)N_ * N_;
    const size_t SC_FULL  = (size_t)B_ * H_ * N_ * N_ * 2;       // 134.2 MB
    const size_t SC_CHUNK = SC_FULL / 2;                          // 67.1 MB
    const size_t A2_SZ    = (size_t)BN_ * H_ * DIN_ * 2;          // 67.1 MB
    const size_t SLACK    = 1u << 20;

    // tier A: full-batch blk0 + deferred full-batch blk1 PV  (~276 MB)
    // tier B: CH=32 chunks (ws known to be in [232,276) on this harness)
    const bool tierA = ws_size >= persistAll + SC_FULL + A2_SZ + SLACK;

    _Float16* Sc = (_Float16*)alloc(tierA ? SC_FULL : SC_CHUNK);
    _Float16* A2 = (_Float16*)alloc(A2_SZ);

    // transient cvt buffers live inside A2 (dead before A2's first GEMM use)
    _Float16* kq0_16 = A2;                                        // 2.1 MB
    _Float16* kq1_16 = kq0_16 + (size_t)H_ * DIN_ * 2 * DH_;      // 4.2 MB
    _Float16* ew1_16 = kq1_16 + (size_t)H_ * DH_ * 2 * DH_;       // 2.1 MB

    // routing: 256^2 kernel only when its grid fills the chip (>=192 wgs);
    // otherwise 128^2 kernel (4x the workgroups) — requires 512-elem segs.
    auto gemm = [&](bool outF16,
                    const _Float16* A, long long aS1, long long aS2, int lda, long long aSeg,
                    const _Float16* Bp, long long bS1, long long bS2, int ldb, long long bSeg,
                    void* C, long long cS1, long long cS2, int ldc,
                    int M, int Nn, int K, int batches, int zShift,
                    const float* bias, int biasMode, long long biasS1, long long biasS2,
                    int aSh, int bSh) {
        const bool can256 = (M % 256 == 0) && (Nn % 256 == 0) && (K % 128 == 0);
        const bool can128 = (M % 128 == 0) && (Nn % 128 == 0) && (K % 32 == 0)
                          && (aSh == 9) && (bSh == 9);
        const long long wg256 = can256 ? (long long)(M >> 8) * (Nn >> 8) * batches : 0;
        bool use256;
        if (!can128)            use256 = true;       // segmented shapes: only gemm256
        else if (!can256)       use256 = false;
        else                    use256 = (wg256 >= 192) || (wg256 >= 32 && wg256 * 4 < 128);
        if (use256) {
            dim3 grid(Nn / 256, M / 256, batches), block(512);
            if (outF16)
                gemm256<true><<<grid, block, 131072, stream>>>(A, aS1, aS2, lda, aSeg, aSh,
                    Bp, bS1, bS2, ldb, bSeg, bSh, C, cS1, cS2, ldc, K, bias, biasMode, biasS1, biasS2, zShift);
            else
                gemm256<false><<<grid, block, 131072, stream>>>(A, aS1, aS2, lda, aSeg, aSh,
                    Bp, bS1, bS2, ldb, bSeg, bSh, C, cS1, cS2, ldc, K, bias, biasMode, biasS1, biasS2, zShift);
        } else {
            dim3 grid(Nn / 128, M / 128, batches), block(256);
            if (outF16)
                gemm_f16<true><<<grid, block, 0, stream>>>(A, aS1, aS2, lda, aSeg,
                    Bp, bS1, bS2, ldb, bSeg, C, cS1, cS2, ldc, K, bias, biasMode, biasS1, biasS2, zShift);
            else
                gemm_f16<false><<<grid, block, 0, stream>>>(A, aS1, aS2, lda, aSeg,
                    Bp, bS1, bS2, ldb, bSeg, C, cS1, cS2, ldc, K, bias, biasMode, biasS1, biasS2, zShift);
        }
    };

    // --- preprocessing -----------------------------------------------------
    cvt_f32_f16<<<BN_ * DIN_ / 1024, 256, 0, stream>>>(x, x16);
    cvt_f32_f16<<<H_ * DIN_ * 2 * DH_ / 1024, 256, 0, stream>>>(kq_w0, kq0_16);
    cvt_f32_f16<<<H_ * DH_ * 2 * DH_ / 1024, 256, 0, stream>>>(kq_w1, kq1_16);
    cvt_f32_f16<<<H_ * DH_ * DH_ / 1024, 256, 0, stream>>>(e_w1, ew1_16);
    transpose_cvt<<<dim3(DH_ / 32, DIN_ / 32, H_), dim3(32, 8), 0, stream>>>(e_w0, ewT0, DIN_, DH_);
    transpose_cvt<<<dim3(DOUT_ / 32, DH_ / 32, 1), dim3(32, 8), 0, stream>>>(proj_w, projwT, DH_, DOUT_);
    transpose_cvt<<<dim3(DIN_ / 32, N_ / 32, B_), dim3(32, 8), 0, stream>>>(x, xT, N_, DIN_);
    sum_b0<<<DH_ / 256, 256, 0, stream>>>(e_b0, sb0);

    // Mt_h = Wk_h * Wq_h^T  (so T = x * Mt^T = x * (Wq Wk^T))
    gemm(true, kq0_16, 0, (long long)DIN_ * 2 * DH_, 2 * DH_, 512,
         kq0_16 + DH_, 0, (long long)DIN_ * 2 * DH_, 2 * DH_, 512,
         Mt0, 0, (long long)DIN_ * DIN_, DIN_,
         DIN_, DIN_, DH_, H_, 2, nullptr, 0, 0, 0, 9, 9);
    gemm(true, kq1_16, 0, (long long)DH_ * 2 * DH_, 2 * DH_, 512,
         kq1_16 + DH_, 0, (long long)DH_ * 2 * DH_, 2 * DH_, 512,
         Mt1, 0, (long long)DH_ * DH_, DH_,
         DH_, DH_, DH_, H_, 2, nullptr, 0, 0, 0, 9, 9);
    // We1pT[h][o][d] = sum_d' projwT[o][d'] * e_w1[h][d][d']
    gemm(true, projwT, 0, 0, DH_, 512,
         ew1_16, 0, (long long)DH_ * DH_, DH_, 512,
         We1pT, 0, (long long)DOUT_ * DH_, DH_,
         DOUT_, DH_, DH_, H_, 2, nullptr, 0, 0, 0, 9, 9);
    fold_bias<<<H_ * DOUT_ / 256, 256, 0, stream>>>(projwT, e_b1, be1p);
    wk_bq<<<H_ * DIN_ / 256, 256, 0, stream>>>(kq_w0, kq_b0, w0, 8);
    wk_bq<<<H_ * DH_ / 256, 256, 0, stream>>>(kq_w1, kq_b1, w1, 9);

    // --- block 0: G-path (h1 = sum_h (P_h x) W_h + 0.25 sum_h b_h) ---------
    {
        const int CH0  = tierA ? B_ : 32;
        const int NCH0 = B_ / CH0;
        const size_t GCH = (size_t)CH0 * N_ * H_ * DIN_;   // elems per A2 slot
        compute_v<<<BN_ / 4, 256, 0, stream>>>(x16, w0, Vb, DIN_);
        for (int c = 0; c < NCH0; c++) {
            const _Float16* xc  = x16 + (size_t)c * CH0 * N_ * DIN_;
            const _Float16* xTc = xT  + (size_t)c * CH0 * DIN_ * N_;
            _Float16* slot = A2 + (size_t)c * GCH;
            // T0 -> slot c (chunk 0 overwrites dead cvt scratch)
            gemm(true, xc, 0, 0, DIN_, 512,
                 Mt0, 0, 0, DIN_, 512,
                 slot, 0, 0, H_ * DIN_,
                 CH0 * N_, H_ * DIN_, DIN_, 1, 0, nullptr, 0, 0, 0, 9, 9);
            // S = T x^T + V
            gemm(true, slot, (long long)N_ * H_ * DIN_, DIN_, H_ * DIN_, 512,
                 xc, (long long)N_ * DIN_, 0, DIN_, 512,
                 Sc, (long long)H_ * SB, SB, N_,
                 N_, N_, DIN_, CH0 * H_, 2,
                 Vb + (size_t)c * CH0 * H_ * N_, 1, (long long)H_ * N_, N_, 9, 9);
            softmax_f16<<<CH0 * H_ * N_ / 4, 256, 0, stream>>>(Sc);
            // G[b][h][q][d] = P[b,h] . x_b  -> slot c (T0 dead)
            gemm(true, Sc, (long long)H_ * SB, SB, N_, 512,
                 xTc, (long long)DIN_ * N_, 0, N_, 512,
                 slot, (long long)H_ * N_ * DIN_, (long long)N_ * DIN_, DIN_,
                 N_, DIN_, N_, CH0 * H_, 2, nullptr, 0, 0, 0, 9, 9);
        }
        // deferred h1 over ALL batches: grid (2,2,64) = 256 wgs
        gemm(true, A2, (long long)H_ * N_ * DIN_, 0, DIN_, (long long)N_ * DIN_,
             ewT0, 0, 0, DIN_, (long long)DH_ * DIN_,
             h1_16, (long long)N_ * DH_, 0, DH_,
             N_, DH_, H_ * DIN_, B_, 0, sb0, 1, 0, 0, 8, 8);
    }

    // --- block 1 -----------------------------------------------------------
    {
        compute_v<<<BN_ / 4, 256, 0, stream>>>(h1_16, w1, Vb, DH_);
        for (int c = 0; c < 2; c++) {
            const _Float16* hc = h1_16 + (size_t)c * 32 * N_ * DH_;
            _Float16* Scp = tierA ? Sc + (size_t)c * 32 * H_ * SB : Sc;
            // T1 -> A2 (needs the whole 67 MB arena; G dead after h1)
            gemm(true, hc, 0, 0, DH_, 512,
                 Mt1, 0, 0, DH_, 512,
                 A2, 0, 0, H_ * DH_,
                 32 * N_, H_ * DH_, DH_, 1, 0, nullptr, 0, 0, 0, 9, 9);
            // S1
            gemm(true, A2, (long long)N_ * H_ * DH_, DH_, H_ * DH_, 512,
                 hc, (long long)N_ * DH_, 0, DH_, 512,
                 Scp, (long long)H_ * SB, SB, N_,
                 N_, N_, DH_, 32 * H_, 2,
                 Vb + (size_t)c * 32 * H_ * N_, 1, (long long)H_ * N_, N_, 9, 9);
            softmax_f16<<<32 * H_ * N_ / 4, 256, 0, stream>>>(Scp);
            if (!tierA) {
                // embW chunk -> A2 (T1 dead)
                gemm(true, We1pT, 0, 0, DH_, 512,
                     hc, (long long)N_ * DH_, 0, DH_, 512,
                     A2, (long long)H_ * DOUT_ * N_, 0, N_,
                     H_ * DOUT_, N_, DH_, 32, 0, be1p, 2, 0, 0, 9, 9);
                // PV chunk (fp32 out) — routed to gemm_f16: grid (2,4,32)=256 wgs
                gemm(false, Scp, (long long)H_ * SB, 0, N_, SB,
                     A2, (long long)H_ * DOUT_ * N_, 0, N_, (long long)DOUT_ * N_,
                     out + (size_t)c * 32 * N_ * DOUT_, (long long)N_ * DOUT_, 0, DOUT_,
                     N_, DOUT_, H_ * N_, 32, 0, proj_b, 1, 0, 0, 9, 9);
            }
        }
        if (tierA) {
            // embW full -> A2 (T1 dead after last S1)
            gemm(true, We1pT, 0, 0, DH_, 512,
                 h1_16, (long long)N_ * DH_, 0, DH_, 512,
                 A2, (long long)H_ * DOUT_ * N_, 0, N_,
                 H_ * DOUT_, N_, DH_, B_, 0, be1p, 2, 0, 0, 9, 9);
            // deferred full-batch PV — routed to gemm_f16: grid (2,4,64)=512 wgs
            gemm(false, Sc, (long long)H_ * SB, 0, N_, SB,
                 A2, (long long)H_ * DOUT_ * N_, 0, N_, (long long)DOUT_ * N_,
                 out, (long long)N_ * DOUT_, 0, DOUT_,
                 N_, DOUT_, H_ * N_, B_, 0, proj_b, 1, 0, 0, 9, 9);
        }
    }
}

// Round 6
// 965.538 us; speedup vs baseline: 1.1001x; 1.0243x over previous
//
#include <hip/hip_runtime.h>

typedef _Float16 half8 __attribute__((ext_vector_type(8)));
typedef _Float16 half4 __attribute__((ext_vector_type(4)));
typedef float floatx4 __attribute__((ext_vector_type(4)));

#define B_    64
#define N_    512
#define DIN_  256
#define DH_   512
#define DOUT_ 256
#define H_    4
#define BN_   (B_ * N_)   // 32768

// raw waitcnt immediates (gfx9: vmcnt[3:0]|[15:14], exp[6:4], lgkm[11:8])
#define WAIT_VM4_LGKM0() __builtin_amdgcn_s_waitcnt(0x0074)  // vm<=4, lgkm<=0
#define WAIT_VM0_LGKM0() __builtin_amdgcn_s_waitcnt(0x0070)  // vm<=0, lgkm<=0
#define WAIT_VM4()       __builtin_amdgcn_s_waitcnt(0x0F74)  // vm<=4 only
#define WAIT_VM0()       __builtin_amdgcn_s_waitcnt(0x0F70)  // vm<=0 only
#define MEMBAR()         __asm__ __volatile__("" ::: "memory")
#define BAR()            do { MEMBAR(); __builtin_amdgcn_s_barrier(); MEMBAR(); } while (0)

__device__ static inline void async_copy16(const _Float16* g, _Float16* l) {
    __builtin_amdgcn_global_load_lds(
        (const __attribute__((address_space(1))) void*)g,
        (__attribute__((address_space(3))) void*)l, 16, 0, 0);
}

// ---------------------------------------------------------------------------
// 128x128-tile GEMM (BK=32, 4 waves, triple-buffered): used for small
// preprocessing shapes AND for main shapes whose 256^2 grid would be
// starved (<192 wgs) — 4x more workgroups fill the chip. 512-elem K-segs.
// ---------------------------------------------------------------------------
template <bool OUT_F16>
__global__ __launch_bounds__(256)
void gemm_f16(const _Float16* __restrict__ A, long long aS1, long long aS2, int lda, long long aSeg,
              const _Float16* __restrict__ B, long long bS1, long long bS2, int ldb, long long bSeg,
              void* __restrict__ Cv, long long cS1, long long cS2, int ldc,
              int K, const float* __restrict__ bias, int biasMode,
              long long biasS1, long long biasS2, int zShift)
{
    __shared__ __align__(16) _Float16 As[3][128 * 32];
    __shared__ __align__(16) _Float16 Bs[3][128 * 32];

    const int tid  = threadIdx.x;
    const int wave = tid >> 6;
    const int lane = tid & 63;
    const int quad = lane >> 4;
    const int r16  = lane & 15;

    const int z  = blockIdx.z;
    const int z1 = z >> zShift;
    const int z2 = z & ((1 << zShift) - 1);

    const int gx = gridDim.x, gy = gridDim.y;
    const int T = gx * gy;
    int lin = blockIdx.y * gx + blockIdx.x;
    int id2 = (T & 7) ? lin : ((lin & 7) * (T >> 3) + (lin >> 3));
    const int m0 = (id2 / gx) * 128;
    const int n0 = (id2 % gx) * 128;

    const int srow = lane >> 2;
    const int scol = (((lane & 3) ^ ((lane >> 3) & 3))) * 8;

    const _Float16* gaRow = A + z1 * aS1 + z2 * aS2
                              + (long long)(m0 + wave * 32 + srow) * lda + scol;
    const _Float16* gbRow = B + z1 * bS1 + z2 * bS2
                              + (long long)(n0 + wave * 32 + srow) * ldb + scol;

    const int wm = (wave >> 1) * 64;
    const int wn = (wave & 1) * 64;
    const int gl = (quad ^ ((r16 >> 1) & 3)) * 8;

    floatx4 acc[4][4];
#pragma unroll
    for (int i = 0; i < 4; i++)
#pragma unroll
        for (int j = 0; j < 4; j++) acc[i][j] = (floatx4){0.f, 0.f, 0.f, 0.f};

    auto stage = [&](int p, int k0) {
        const _Float16* a = gaRow + (long long)(k0 >> 9) * aSeg + (k0 & 511);
        const _Float16* b = gbRow + (long long)(k0 >> 9) * bSeg + (k0 & 511);
        _Float16* la = &As[p][wave * 1024];
        _Float16* lb = &Bs[p][wave * 1024];
        async_copy16(a,                    la);
        async_copy16(a + (size_t)16 * lda, la + 512);
        async_copy16(b,                    lb);
        async_copy16(b + (size_t)16 * ldb, lb + 512);
    };

    auto compute = [&](int p) {
        half8 af[4], bf[4];
#pragma unroll
        for (int i = 0; i < 4; i++)
            af[i] = *(const half8*)&As[p][(wm + i * 16 + r16) * 32 + gl];
#pragma unroll
        for (int j = 0; j < 4; j++)
            bf[j] = *(const half8*)&Bs[p][(wn + j * 16 + r16) * 32 + gl];
#pragma unroll
        for (int i = 0; i < 4; i++)
#pragma unroll
            for (int j = 0; j < 4; j++)
                acc[i][j] = __builtin_amdgcn_mfma_f32_16x16x32_f16(
                    bf[j], af[i], acc[i][j], 0, 0, 0);
    };

    const int niter = K >> 5;
    stage(0, 0);
    stage(1, 32);
    int pNext = 2;
    int pCur  = 0;
    for (int it = 0; it < niter - 1; ++it) {
        MEMBAR(); WAIT_VM4_LGKM0();
        __builtin_amdgcn_s_barrier();
        MEMBAR();
        if (it + 2 < niter) stage(pNext, (it + 2) << 5);
        compute(pCur);
        MEMBAR();
        pNext = (pNext == 2) ? 0 : pNext + 1;
        pCur  = (pCur  == 2) ? 0 : pCur  + 1;
    }
    MEMBAR(); WAIT_VM0_LGKM0();
    __builtin_amdgcn_s_barrier(); MEMBAR();
    compute(pCur);

    const float* bz = bias + z1 * biasS1 + z2 * biasS2;
    float*    Cf = (float*)Cv    + z1 * cS1 + z2 * cS2;
    _Float16* Ch = (_Float16*)Cv + z1 * cS1 + z2 * cS2;
#pragma unroll
    for (int i = 0; i < 4; i++) {
        const int row = m0 + wm + i * 16 + r16;
#pragma unroll
        for (int j = 0; j < 4; j++) {
            const int col = n0 + wn + j * 16 + quad * 4;
            float v0 = acc[i][j][0], v1 = acc[i][j][1],
                  v2 = acc[i][j][2], v3 = acc[i][j][3];
            if (biasMode == 1) {
                v0 += bz[col]; v1 += bz[col + 1];
                v2 += bz[col + 2]; v3 += bz[col + 3];
            } else if (biasMode == 2) {
                const float bv = bz[row];
                v0 += bv; v1 += bv; v2 += bv; v3 += bv;
            }
            const size_t idx = (size_t)row * ldc + col;
            if (OUT_F16) {
                half4 hv = {(_Float16)v0, (_Float16)v1, (_Float16)v2, (_Float16)v3};
                *(half4*)&Ch[idx] = hv;
            } else {
                float4 fv = {v0, v1, v2, v3};
                *(float4*)&Cf[idx] = fv;
            }
        }
    }
}

// ---------------------------------------------------------------------------
// 256x256 tile, 8 waves (2x4), BK=64, 8-phase interleave, counted vmcnt,
// XOR-swizzled LDS via pre-swizzled global source, setprio around MFMA.
// STATIC buffer map: even K-tiles -> buf0 (read p0-p3), odd -> buf1 (p4-p7).
// B col-half-0 fragments kept in regs across the K-tile (p3/p7 reg-only).
// Generalized K segmentation: segment size = 1<<aSh elements (aSh>=7).
//
// z-loop (this round): one wg processes zLoop (1 or 2) consecutive batches
// at the same (m0,n0). Tile index T in [0, zLoop*ntiles) is globally linear;
// the K-pipeline (staging, counted vmcnt, buffer map) continues seamlessly
// across the z boundary. Epilogue (VGPR->global, no barriers) + acc reset
// fire in-loop whenever (it+1) % (ntiles/2) == 0. Requires ntiles pow2,
// ntiles even (K%128==0). Halves the grid -> 1 dispatch round, 1 prologue.
// ---------------------------------------------------------------------------
template <bool OUT_F16>
__global__ __launch_bounds__(512, 2)
void gemm256(const _Float16* __restrict__ A, long long aS1, long long aS2, int lda, long long aSeg, int aSh,
             const _Float16* __restrict__ B, long long bS1, long long bS2, int ldb, long long bSeg, int bSh,
             void* __restrict__ Cv, long long cS1, long long cS2, int ldc,
             int K, const float* __restrict__ bias, int biasMode,
             long long biasS1, long long biasS2, int zShift, int zLoop)
{
    extern __shared__ __align__(16) _Float16 lds[];
    _Float16* AsB = lds;                 // [2][256*64]
    _Float16* BsB = lds + 2 * 256 * 64;  // [2][256*64]

    const int tid  = threadIdx.x;
    const int wave = tid >> 6;        // 0..7
    const int lane = tid & 63;
    const int quad = lane >> 4;
    const int r16  = lane & 15;
    const int wr   = wave >> 2;       // 0..1
    const int wc   = wave & 3;        // 0..3

    const int zBase = blockIdx.z * zLoop;
    const int zMask = (1 << zShift) - 1;

    const int aTSh = aSh - 6, aTMk = (1 << aTSh) - 1;
    const int bTSh = bSh - 6, bTMk = (1 << bTSh) - 1;

    const int ntiles = K >> 6;                    // K-tiles per z (pow2, even)
    const int ntSh   = __builtin_ctz(ntiles);
    const int ntHMsk = (ntiles >> 1) - 1;
    const int TTh    = (ntiles * zLoop) >> 1;     // main-loop iterations

    const int gx = gridDim.x, gy = gridDim.y;
    const int T_ = gx * gy;
    int lin = blockIdx.y * gx + blockIdx.x;
    int id2 = (T_ & 7) ? lin : ((lin & 7) * (T_ >> 3) + (lin >> 3));
    const int m0 = (id2 / gx) * 256;
    const int n0 = (id2 % gx) * 256;

    const int sr  = tid >> 3;                       // 0..63
    const int swz = ((tid & 7) ^ (sr & 7)) * 8;     // swizzled k-offset (elems)

    // per-z operand bases (zLoop <= 2; tz selects via ternary, no arrays)
    const int zz0 = zBase, zz1 = zBase + (zLoop - 1);
    const _Float16* gaA0 = A + (long long)(zz0 >> zShift) * aS1 + (long long)(zz0 & zMask) * aS2
                             + (long long)(m0 + sr) * lda + swz;
    const _Float16* gaA1 = A + (long long)(zz1 >> zShift) * aS1 + (long long)(zz1 & zMask) * aS2
                             + (long long)(m0 + sr) * lda + swz;
    const _Float16* gbB0 = B + (long long)(zz0 >> zShift) * bS1 + (long long)(zz0 & zMask) * bS2
                             + (long long)(n0 + sr) * ldb + swz;
    const _Float16* gbB1 = B + (long long)(zz1 >> zShift) * bS1 + (long long)(zz1 & zMask) * bS2
                             + (long long)(n0 + sr) * ldb + swz;

    const int arow = wr * 64 + r16;
    const int brow = wc * 32 + r16;
    const int rsw  = r16 & 7;
    const int gxk0 = (quad ^ rsw) * 8;
    const int gxk1 = ((4 + quad) ^ rsw) * 8;

    floatx4 acc[8][4];
#pragma unroll
    for (int i = 0; i < 8; i++)
#pragma unroll
        for (int j = 0; j < 4; j++) acc[i][j] = (floatx4){0.f, 0.f, 0.f, 0.f};

    half8 af[4][2], bf0s[2][2], bf1s[2][2];

    auto stageA = [&](int buf, int h, int T) {
        const int tz = T >> ntSh, tk = T & (ntiles - 1);
        const _Float16* s = (tz ? gaA1 : gaA0) + (long long)(h * 128) * lda
                          + (long long)(tk >> aTSh) * aSeg + ((tk & aTMk) << 6);
        _Float16* d = AsB + buf * 16384 + h * 8192 + wave * 512;
        async_copy16(s, d);
        async_copy16(s + (long long)64 * lda, d + 4096);
    };
    auto stageB = [&](int buf, int h, int T) {
        const int tz = T >> ntSh, tk = T & (ntiles - 1);
        const _Float16* s = (tz ? gbB1 : gbB0) + (long long)(h * 128) * ldb
                          + (long long)(tk >> bTSh) * bSeg + ((tk & bTMk) << 6);
        _Float16* d = BsB + buf * 16384 + h * 8192 + wave * 512;
        async_copy16(s, d);
        async_copy16(s + (long long)64 * ldb, d + 4096);
    };

    // epilogue: VGPR->global only, no LDS, no barriers.
    auto epi = [&](int zz) {
        const int z1 = zz >> zShift, z2 = zz & zMask;
        const float* bz = bias + (long long)z1 * biasS1 + (long long)z2 * biasS2;
        float*    Cf = (float*)Cv    + (long long)z1 * cS1 + (long long)z2 * cS2;
        _Float16* Ch = (_Float16*)Cv + (long long)z1 * cS1 + (long long)z2 * cS2;
#pragma unroll
        for (int f = 0; f < 8; f++) {
            const int row = m0 + (f >> 2) * 128 + wr * 64 + (f & 3) * 16 + r16;
#pragma unroll
            for (int j = 0; j < 4; j++) {
                const int col = n0 + (j >> 1) * 128 + wc * 32 + (j & 1) * 16 + quad * 4;
                float v0 = acc[f][j][0], v1 = acc[f][j][1],
                      v2 = acc[f][j][2], v3 = acc[f][j][3];
                if (biasMode == 1) {
                    v0 += bz[col]; v1 += bz[col + 1];
                    v2 += bz[col + 2]; v3 += bz[col + 3];
                } else if (biasMode == 2) {
                    const float bv = bz[row];
                    v0 += bv; v1 += bv; v2 += bv; v3 += bv;
                }
                const size_t idx = (size_t)row * ldc + col;
                if (OUT_F16) {
                    half4 hv = {(_Float16)v0, (_Float16)v1, (_Float16)v2, (_Float16)v3};
                    *(half4*)&Ch[idx] = hv;
                } else {
                    float4 fv = {v0, v1, v2, v3};
                    *(float4*)&Cf[idx] = fv;
                }
            }
        }
    };

#define LOAD_AF(RH, BUF) do { \
    const _Float16* ab_ = AsB + (BUF) * 16384 + ((RH) * 128 + arow) * 64; \
    _Pragma("unroll") \
    for (int i5 = 0; i5 < 4; i5++) { \
        af[i5][0] = *(const half8*)(ab_ + i5 * 1024 + gxk0); \
        af[i5][1] = *(const half8*)(ab_ + i5 * 1024 + gxk1); \
    } \
} while (0)

#define LOAD_BF(DST, CH, BUF) do { \
    const _Float16* bb_ = BsB + (BUF) * 16384 + ((CH) * 128 + brow) * 64; \
    _Pragma("unroll") \
    for (int j5 = 0; j5 < 2; j5++) { \
        DST[j5][0] = *(const half8*)(bb_ + j5 * 1024 + gxk0); \
        DST[j5][1] = *(const half8*)(bb_ + j5 * 1024 + gxk1); \
    } \
} while (0)

#define MFMA16(RH, CH, BFS) do { \
    _Pragma("unroll") \
    for (int i6 = 0; i6 < 4; i6++) { \
        _Pragma("unroll") \
        for (int j6 = 0; j6 < 2; j6++) { \
            floatx4 c_ = acc[(RH) * 4 + i6][(CH) * 2 + j6]; \
            c_ = __builtin_amdgcn_mfma_f32_16x16x32_f16(BFS[j6][0], af[i6][0], c_, 0, 0, 0); \
            c_ = __builtin_amdgcn_mfma_f32_16x16x32_f16(BFS[j6][1], af[i6][1], c_, 0, 0, 0); \
            acc[(RH) * 4 + i6][(CH) * 2 + j6] = c_; \
        } \
    } \
} while (0)

    // prologue: tile0 -> buf0 (all 4 halves), tile1 -> buf1 (A0, B1)
    stageA(0, 0, 0);
    stageB(0, 1, 0);
    stageA(0, 1, 0);
    stageB(0, 0, 0);
    stageA(1, 0, 1);
    stageB(1, 1, 1);
    WAIT_VM4();
    BAR();

    int zi = 0;
    for (int it = 0; it < TTh; ++it) {
        const int T = it * 2;
        const bool full = (it < TTh - 1);

        // ---- p0: (0,0) of tile T  [buf0]
        LOAD_AF(0, 0); LOAD_BF(bf0s, 0, 0);
        stageA(1, 1, T + 1);
        BAR();
        __builtin_amdgcn_s_setprio(1); MFMA16(0, 0, bf0s); __builtin_amdgcn_s_setprio(0);
        BAR();
        // ---- p1: (0,1)
        LOAD_BF(bf1s, 1, 0);
        stageB(1, 0, T + 1);
        BAR();
        __builtin_amdgcn_s_setprio(1); MFMA16(0, 1, bf1s); __builtin_amdgcn_s_setprio(0);
        BAR();
        // ---- p2: (1,1)
        LOAD_AF(1, 0);
        if (full) stageA(0, 0, T + 2);
        BAR();
        __builtin_amdgcn_s_setprio(1); MFMA16(1, 1, bf1s); __builtin_amdgcn_s_setprio(0);
        BAR();
        // ---- p3: (1,0)  regs-only  + W0
        if (full) stageB(0, 1, T + 2);
        BAR();
        __builtin_amdgcn_s_setprio(1); MFMA16(1, 0, bf0s); __builtin_amdgcn_s_setprio(0);
        if (full) WAIT_VM4(); else WAIT_VM0();
        BAR();
        // ---- p4: (0,0) of tile T+1  [buf1]
        LOAD_AF(0, 1); LOAD_BF(bf0s, 0, 1);
        if (full) stageA(0, 1, T + 2);
        BAR();
        __builtin_amdgcn_s_setprio(1); MFMA16(0, 0, bf0s); __builtin_amdgcn_s_setprio(0);
        BAR();
        // ---- p5: (0,1)
        LOAD_BF(bf1s, 1, 1);
        if (full) stageB(0, 0, T + 2);
        BAR();
        __builtin_amdgcn_s_setprio(1); MFMA16(0, 1, bf1s); __builtin_amdgcn_s_setprio(0);
        BAR();
        // ---- p6: (1,1)
        LOAD_AF(1, 1);
        if (full) stageA(1, 0, T + 3);
        BAR();
        __builtin_amdgcn_s_setprio(1); MFMA16(1, 1, bf1s); __builtin_amdgcn_s_setprio(0);
        BAR();
        // ---- p7: (1,0)  regs-only  + W1
        if (full) stageB(1, 1, T + 3);
        BAR();
        __builtin_amdgcn_s_setprio(1); MFMA16(1, 0, bf0s); __builtin_amdgcn_s_setprio(0);
        if (full) WAIT_VM4();
        BAR();

        // z-boundary: write out this batch's tile, reset accumulator.
        if (((it + 1) & ntHMsk) == 0) {
            epi(zBase + zi);
            ++zi;
#pragma unroll
            for (int i7 = 0; i7 < 8; i7++)
#pragma unroll
                for (int j7 = 0; j7 < 4; j7++)
                    acc[i7][j7] = (floatx4){0.f, 0.f, 0.f, 0.f};
        }
    }

#undef LOAD_AF
#undef LOAD_BF
#undef MFMA16
}

// ---------------------------------------------------------------------------
// in-place fp16 softmax over rows of 512, scaled by 0.25 (head mean).
// ---------------------------------------------------------------------------
__global__ __launch_bounds__(256)
void softmax_f16(_Float16* __restrict__ S)
{
    const int row  = blockIdx.x * 4 + (threadIdx.x >> 6);
    const int lane = threadIdx.x & 63;
    _Float16* s = S + (size_t)row * 512 + lane * 8;
    half8 h = *(const half8*)s;
    float v[8];
    float mx = -1e30f;
#pragma unroll
    for (int j = 0; j < 8; j++) { v[j] = (float)h[j]; mx = fmaxf(mx, v[j]); }
#pragma unroll
    for (int off = 32; off; off >>= 1) mx = fmaxf(mx, __shfl_xor(mx, off));
    float sum = 0.f;
#pragma unroll
    for (int j = 0; j < 8; j++) { v[j] = __expf(v[j] - mx); sum += v[j]; }
#pragma unroll
    for (int off = 32; off; off >>= 1) sum += __shfl_xor(sum, off);
    const float inv = 0.25f / sum;
#pragma unroll
    for (int j = 0; j < 8; j++) h[j] = (_Float16)(v[j] * inv);
    *(half8*)s = h;
}

__global__ __launch_bounds__(256)
void cvt_f32_f16(const float* __restrict__ in, _Float16* __restrict__ out)
{
    const size_t i = ((size_t)blockIdx.x * blockDim.x + threadIdx.x) * 4;
    const float4 f = *(const float4*)(in + i);
    out[i + 0] = (_Float16)f.x;
    out[i + 1] = (_Float16)f.y;
    out[i + 2] = (_Float16)f.z;
    out[i + 3] = (_Float16)f.w;
}

// in [G][R][C] -> out [G][C][R], fp32 -> fp16
__global__ __launch_bounds__(256)
void transpose_cvt(const float* __restrict__ in, _Float16* __restrict__ out,
                   int R, int C)
{
    __shared__ float tile[32][33];
    const int g  = blockIdx.z;
    const int c0 = blockIdx.x * 32;
    const int r0 = blockIdx.y * 32;
    const float* inp  = in  + (size_t)g * R * C;
    _Float16*    outp = out + (size_t)g * R * C;
#pragma unroll
    for (int i = threadIdx.y; i < 32; i += 8)
        tile[i][threadIdx.x] = inp[(size_t)(r0 + i) * C + c0 + threadIdx.x];
    __syncthreads();
#pragma unroll
    for (int i = threadIdx.y; i < 32; i += 8)
        outp[(size_t)(c0 + i) * R + r0 + threadIdx.x] = (_Float16)tile[threadIdx.x][i];
}

// w[h][d] = sum_e Wk[h][d][e] * bq[h][e]
__global__ __launch_bounds__(256)
void wk_bq(const float* __restrict__ kq_w, const float* __restrict__ kq_b,
           float* __restrict__ w, int dinShift)
{
    const int t = blockIdx.x * 256 + threadIdx.x;
    const int h = t >> dinShift;
    const int d = t & ((1 << dinShift) - 1);
    const float* wk = kq_w + ((size_t)(h << dinShift) + d) * (2 * DH_);
    const float* bq = kq_b + (size_t)h * 2 * DH_ + DH_;
    float s = 0.f;
    for (int e = 0; e < DH_; e++) s += wk[e] * bq[e];
    w[t] = s;
}

// be1p[h][o] = sum_d e_b1[h][d] * projwT[o][d]
__global__ __launch_bounds__(256)
void fold_bias(const _Float16* __restrict__ projwT, const float* __restrict__ e_b1,
               float* __restrict__ be1p)
{
    const int t = blockIdx.x * 256 + threadIdx.x;   // t < H*DOUT
    const int h = t >> 8;
    const int o = t & 255;
    const _Float16* pw = projwT + (size_t)o * DH_;
    const float*    eb = e_b1 + (size_t)h * DH_;
    float s = 0.f;
    for (int d = 0; d < DH_; d++) s += (float)pw[d] * eb[d];
    be1p[t] = s;
}

// sb0[e] = 0.25 * sum_h e_b0[h][e]   (e < DH_)
__global__ __launch_bounds__(256)
void sum_b0(const float* __restrict__ eb, float* __restrict__ sb)
{
    const int e = blockIdx.x * 256 + threadIdx.x;
    sb[e] = 0.25f * (eb[e] + eb[DH_ + e] + eb[2 * DH_ + e] + eb[3 * DH_ + e]);
}

// V[b][h][n] = x[b*N+n, :] . w[h, :]   — one wave per row, 4 heads at once
__global__ __launch_bounds__(256)
void compute_v(const _Float16* __restrict__ x, const float* __restrict__ w,
               float* __restrict__ V, int Kin)
{
    const int row  = blockIdx.x * 4 + (threadIdx.x >> 6);
    const int lane = threadIdx.x & 63;
    const int b = row >> 9, n = row & 511;
    const _Float16* xr = x + (size_t)row * Kin;
    float s0 = 0.f, s1 = 0.f, s2 = 0.f, s3 = 0.f;
    const int iters = Kin >> 6;
    for (int j = 0; j < iters; j++) {
        const int idx = lane + j * 64;
        const float xv = (float)xr[idx];
        s0 += xv * w[idx];
        s1 += xv * w[Kin + idx];
        s2 += xv * w[2 * Kin + idx];
        s3 += xv * w[3 * Kin + idx];
    }
#pragma unroll
    for (int off = 32; off; off >>= 1) {
        s0 += __shfl_xor(s0, off); s1 += __shfl_xor(s1, off);
        s2 += __shfl_xor(s2, off); s3 += __shfl_xor(s3, off);
    }
    if (lane == 0) {
        float* vb = V + ((size_t)b * H_) * N_ + n;
        vb[0] = s0; vb[N_] = s1; vb[2 * N_] = s2; vb[3 * N_] = s3;
    }
}

// ---------------------------------------------------------------------------
extern "C" void kernel_launch(void* const* d_in, const int* in_sizes, int n_in,
                              void* d_out, int out_size, void* d_ws, size_t ws_size,
                              hipStream_t stream)
{
    (void)in_sizes; (void)n_in; (void)out_size;

    static bool attr_set = false;
    if (!attr_set) {
        hipFuncSetAttribute((const void*)gemm256<true>,
                            hipFuncAttributeMaxDynamicSharedMemorySize, 131072);
        hipFuncSetAttribute((const void*)gemm256<false>,
                            hipFuncAttributeMaxDynamicSharedMemorySize, 131072);
        attr_set = true;
    }

    const float* x      = (const float*)d_in[0];
    const float* e_w0   = (const float*)d_in[1];
    const float* e_b0   = (const float*)d_in[2];
    const float* kq_w0  = (const float*)d_in[3];
    const float* kq_b0  = (const float*)d_in[4];
    const float* e_w1   = (const float*)d_in[5];
    const float* e_b1   = (const float*)d_in[6];
    const float* kq_w1  = (const float*)d_in[7];
    const float* kq_b1  = (const float*)d_in[8];
    const float* proj_w = (const float*)d_in[9];
    const float* proj_b = (const float*)d_in[10];
    float* out = (float*)d_out;

    char* ws = (char*)d_ws;
    size_t off = 0;
    auto alloc = [&](size_t bytes) -> char* {
        char* p = ws + off;
        off += (bytes + 255) & ~(size_t)255;
        return p;
    };

    // --- persistent (~73 MB incl. xT) --------------------------------------
    _Float16* x16    = (_Float16*)alloc((size_t)BN_ * DIN_ * 2);
    _Float16* h1_16  = (_Float16*)alloc((size_t)BN_ * DH_ * 2);
    _Float16* ewT0   = (_Float16*)alloc((size_t)H_ * DH_ * DIN_ * 2);
    _Float16* projwT = (_Float16*)alloc((size_t)DOUT_ * DH_ * 2);
    _Float16* Mt0    = (_Float16*)alloc((size_t)H_ * DIN_ * DIN_ * 2);
    _Float16* Mt1    = (_Float16*)alloc((size_t)H_ * DH_ * DH_ * 2);
    _Float16* We1pT  = (_Float16*)alloc((size_t)H_ * DOUT_ * DH_ * 2);
    float*    be1p   = (float*)alloc((size_t)H_ * DOUT_ * 4);
    float*    w0     = (float*)alloc((size_t)H_ * DIN_ * 4);
    float*    w1     = (float*)alloc((size_t)H_ * DH_ * 4);
    float*    sb0    = (float*)alloc((size_t)DH_ * 4);
    float*    Vb     = (float*)alloc((size_t)B_ * H_ * N_ * 4);
    _Float16* xT     = (_Float16*)alloc((size_t)BN_ * DIN_ * 2);   // [b][d][n]

    const size_t persistAll = off;
    const long long SB = (long long)N_ * N_;
    const size_t SC_FULL  = (size_t)B_ * H_ * N_ * N_ * 2;       // 134.2 MB
    const size_t SC_CHUNK = SC_FULL / 2;                          // 67.1 MB
    const size_t A2_SZ    = (size_t)BN_ * H_ * DIN_ * 2;          // 67.1 MB
    const size_t SLACK    = 1u << 20;

    // tier A: full-batch blk0 + deferred full-batch blk1 PV  (~276 MB)
    // tier B: CH=32 chunks (ws known to be in [232,276) on this harness)
    const bool tierA = ws_size >= persistAll + SC_FULL + A2_SZ + SLACK;

    _Float16* Sc = (_Float16*)alloc(tierA ? SC_FULL : SC_CHUNK);
    _Float16* A2 = (_Float16*)alloc(A2_SZ);

    // transient cvt buffers live inside A2 (dead before A2's first GEMM use)
    _Float16* kq0_16 = A2;                                        // 2.1 MB
    _Float16* kq1_16 = kq0_16 + (size_t)H_ * DIN_ * 2 * DH_;      // 4.2 MB
    _Float16* ew1_16 = kq1_16 + (size_t)H_ * DH_ * 2 * DH_;      // 2.1 MB

    // routing: 256^2 kernel when its grid (after zLoop) fills the chip;
    // otherwise 128^2 kernel (4x the workgroups, zLoop==1 only).
    auto gemm = [&](bool outF16,
                    const _Float16* A, long long aS1, long long aS2, int lda, long long aSeg,
                    const _Float16* Bp, long long bS1, long long bS2, int ldb, long long bSeg,
                    void* C, long long cS1, long long cS2, int ldc,
                    int M, int Nn, int K, int batches, int zShift,
                    const float* bias, int biasMode, long long biasS1, long long biasS2,
                    int aSh, int bSh, int zLoop) {
        const bool can256 = (M % 256 == 0) && (Nn % 256 == 0) && (K % 128 == 0);
        const bool can128 = (M % 128 == 0) && (Nn % 128 == 0) && (K % 32 == 0)
                          && (aSh == 9) && (bSh == 9) && (zLoop == 1);
        const long long wg256 = can256
            ? (long long)(M >> 8) * (Nn >> 8) * (batches / zLoop) : 0;
        bool use256;
        if (!can128)            use256 = true;
        else if (!can256)       use256 = false;
        else                    use256 = (wg256 >= 192) || (wg256 >= 32 && wg256 * 4 < 128);
        if (use256) {
            dim3 grid(Nn / 256, M / 256, batches / zLoop), block(512);
            if (outF16)
                gemm256<true><<<grid, block, 131072, stream>>>(A, aS1, aS2, lda, aSeg, aSh,
                    Bp, bS1, bS2, ldb, bSeg, bSh, C, cS1, cS2, ldc, K, bias, biasMode, biasS1, biasS2, zShift, zLoop);
            else
                gemm256<false><<<grid, block, 131072, stream>>>(A, aS1, aS2, lda, aSeg, aSh,
                    Bp, bS1, bS2, ldb, bSeg, bSh, C, cS1, cS2, ldc, K, bias, biasMode, biasS1, biasS2, zShift, zLoop);
        } else {
            dim3 grid(Nn / 128, M / 128, batches), block(256);
            if (outF16)
                gemm_f16<true><<<grid, block, 0, stream>>>(A, aS1, aS2, lda, aSeg,
                    Bp, bS1, bS2, ldb, bSeg, C, cS1, cS2, ldc, K, bias, biasMode, biasS1, biasS2, zShift);
            else
                gemm_f16<false><<<grid, block, 0, stream>>>(A, aS1, aS2, lda, aSeg,
                    Bp, bS1, bS2, ldb, bSeg, C, cS1, cS2, ldc, K, bias, biasMode, biasS1, biasS2, zShift);
        }
    };

    // --- preprocessing -----------------------------------------------------
    cvt_f32_f16<<<BN_ * DIN_ / 1024, 256, 0, stream>>>(x, x16);
    cvt_f32_f16<<<H_ * DIN_ * 2 * DH_ / 1024, 256, 0, stream>>>(kq_w0, kq0_16);
    cvt_f32_f16<<<H_ * DH_ * 2 * DH_ / 1024, 256, 0, stream>>>(kq_w1, kq1_16);
    cvt_f32_f16<<<H_ * DH_ * DH_ / 1024, 256, 0, stream>>>(e_w1, ew1_16);
    transpose_cvt<<<dim3(DH_ / 32, DIN_ / 32, H_), dim3(32, 8), 0, stream>>>(e_w0, ewT0, DIN_, DH_);
    transpose_cvt<<<dim3(DOUT_ / 32, DH_ / 32, 1), dim3(32, 8), 0, stream>>>(proj_w, projwT, DH_, DOUT_);
    transpose_cvt<<<dim3(DIN_ / 32, N_ / 32, B_), dim3(32, 8), 0, stream>>>(x, xT, N_, DIN_);
    sum_b0<<<DH_ / 256, 256, 0, stream>>>(e_b0, sb0);

    // Mt_h = Wk_h * Wq_h^T  (so T = x * Mt^T = x * (Wq Wk^T))
    gemm(true, kq0_16, 0, (long long)DIN_ * 2 * DH_, 2 * DH_, 512,
         kq0_16 + DH_, 0, (long long)DIN_ * 2 * DH_, 2 * DH_, 512,
         Mt0, 0, (long long)DIN_ * DIN_, DIN_,
         DIN_, DIN_, DH_, H_, 2, nullptr, 0, 0, 0, 9, 9, 1);
    gemm(true, kq1_16, 0, (long long)DH_ * 2 * DH_, 2 * DH_, 512,
         kq1_16 + DH_, 0, (long long)DH_ * 2 * DH_, 2 * DH_, 512,
         Mt1, 0, (long long)DH_ * DH_, DH_,
         DH_, DH_, DH_, H_, 2, nullptr, 0, 0, 0, 9, 9, 1);
    // We1pT[h][o][d] = sum_d' projwT[o][d'] * e_w1[h][d][d']
    gemm(true, projwT, 0, 0, DH_, 512,
         ew1_16, 0, (long long)DH_ * DH_, DH_, 512,
         We1pT, 0, (long long)DOUT_ * DH_, DH_,
         DOUT_, DH_, DH_, H_, 2, nullptr, 0, 0, 0, 9, 9, 1);
    fold_bias<<<H_ * DOUT_ / 256, 256, 0, stream>>>(projwT, e_b1, be1p);
    wk_bq<<<H_ * DIN_ / 256, 256, 0, stream>>>(kq_w0, kq_b0, w0, 8);
    wk_bq<<<H_ * DH_ / 256, 256, 0, stream>>>(kq_w1, kq_b1, w1, 9);

    // --- block 0: G-path (h1 = sum_h (P_h x) W_h + 0.25 sum_h b_h) ---------
    {
        const int CH0  = tierA ? B_ : 32;
        const int NCH0 = B_ / CH0;
        const size_t GCH = (size_t)CH0 * N_ * H_ * DIN_;   // elems per A2 slot
        compute_v<<<BN_ / 4, 256, 0, stream>>>(x16, w0, Vb, DIN_);
        for (int c = 0; c < NCH0; c++) {
            const _Float16* xc  = x16 + (size_t)c * CH0 * N_ * DIN_;
            const _Float16* xTc = xT  + (size_t)c * CH0 * DIN_ * N_;
            _Float16* slot = A2 + (size_t)c * GCH;
            // T0 -> slot c (chunk 0 overwrites dead cvt scratch)
            gemm(true, xc, 0, 0, DIN_, 512,
                 Mt0, 0, 0, DIN_, 512,
                 slot, 0, 0, H_ * DIN_,
                 CH0 * N_, H_ * DIN_, DIN_, 1, 0, nullptr, 0, 0, 0, 9, 9, 1);
            // S = T x^T + V   (zLoop=2: h-pairs of same b share the B tile)
            gemm(true, slot, (long long)N_ * H_ * DIN_, DIN_, H_ * DIN_, 512,
                 xc, (long long)N_ * DIN_, 0, DIN_, 512,
                 Sc, (long long)H_ * SB, SB, N_,
                 N_, N_, DIN_, CH0 * H_, 2,
                 Vb + (size_t)c * CH0 * H_ * N_, 1, (long long)H_ * N_, N_, 9, 9, 2);
            softmax_f16<<<CH0 * H_ * N_ / 4, 256, 0, stream>>>(Sc);
            // G[b][h][q][d] = P[b,h] . x_b  -> slot c (T0 dead)
            gemm(true, Sc, (long long)H_ * SB, SB, N_, 512,
                 xTc, (long long)DIN_ * N_, 0, N_, 512,
                 slot, (long long)H_ * N_ * DIN_, (long long)N_ * DIN_, DIN_,
                 N_, DIN_, N_, CH0 * H_, 2, nullptr, 0, 0, 0, 9, 9, 1);
        }
        // deferred h1 over ALL batches: grid (2,2,64) = 256 wgs
        gemm(true, A2, (long long)H_ * N_ * DIN_, 0, DIN_, (long long)N_ * DIN_,
             ewT0, 0, 0, DIN_, (long long)DH_ * DIN_,
             h1_16, (long long)N_ * DH_, 0, DH_,
             N_, DH_, H_ * DIN_, B_, 0, sb0, 1, 0, 0, 8, 8, 1);
    }

    // --- block 1 -----------------------------------------------------------
    {
        compute_v<<<BN_ / 4, 256, 0, stream>>>(h1_16, w1, Vb, DH_);
        for (int c = 0; c < 2; c++) {
            const _Float16* hc = h1_16 + (size_t)c * 32 * N_ * DH_;
            _Float16* Scp = tierA ? Sc + (size_t)c * 32 * H_ * SB : Sc;
            // T1 -> A2, expressed as (M=256, batches=64, zLoop=2):
            // grid (8,1,32) = 256 wgs, one round, deep pipeline.
            gemm(true, hc, (long long)256 * DH_, 0, DH_, 512,
                 Mt1, 0, 0, DH_, 512,
                 A2, (long long)256 * H_ * DH_, 0, H_ * DH_,
                 256, H_ * DH_, DH_, 64, 0, nullptr, 0, 0, 0, 9, 9, 2);
            // S1  (zLoop=2)
            gemm(true, A2, (long long)N_ * H_ * DH_, DH_, H_ * DH_, 512,
                 hc, (long long)N_ * DH_, 0, DH_, 512,
                 Scp, (long long)H_ * SB, SB, N_,
                 N_, N_, DH_, 32 * H_, 2,
                 Vb + (size_t)c * 32 * H_ * N_, 1, (long long)H_ * N_, N_, 9, 9, 2);
            softmax_f16<<<32 * H_ * N_ / 4, 256, 0, stream>>>(Scp);
            if (!tierA) {
                // embW chunk -> A2 (T1 dead)
                gemm(true, We1pT, 0, 0, DH_, 512,
                     hc, (long long)N_ * DH_, 0, DH_, 512,
                     A2, (long long)H_ * DOUT_ * N_, 0, N_,
                     H_ * DOUT_, N_, DH_, 32, 0, be1p, 2, 0, 0, 9, 9, 1);
                // PV chunk (fp32 out) — routed to gemm_f16: grid (2,4,32)=256 wgs
                gemm(false, Scp, (long long)H_ * SB, 0, N_, SB,
                     A2, (long long)H_ * DOUT_ * N_, 0, N_, (long long)DOUT_ * N_,
                     out + (size_t)c * 32 * N_ * DOUT_, (long long)N_ * DOUT_, 0, DOUT_,
                     N_, DOUT_, H_ * N_, 32, 0, proj_b, 1, 0, 0, 9, 9, 1);
            }
        }
        if (tierA) {
            // embW full -> A2 (T1 dead after last S1)
            gemm(true, We1pT, 0, 0, DH_, 512,
                 h1_16, (long long)N_ * DH_, 0, DH_, 512,
                 A2, (long long)H_ * DOUT_ * N_, 0, N_,
                 H_ * DOUT_, N_, DH_, B_, 0, be1p, 2, 0, 0, 9, 9, 1);
            // deferred full-batch PV — routed to gemm_f16: grid (2,4,64)=512 wgs
            gemm(false, Sc, (long long)H_ * SB, 0, N_, SB,
                 A2, (long long)H_ * DOUT_ * N_, 0, N_, (long long)DOUT_ * N_,
                 out, (long long)N_ * DOUT_, 0, DOUT_,
                 N_, DOUT_, H_ * N_, B_, 0, proj_b, 1, 0, 0, 9, 9, 1);
        }
    }
}

// Round 7
// 927.303 us; speedup vs baseline: 1.1455x; 1.0412x over previous
//
#include <hip/hip_runtime.h>

typedef _Float16 half8 __attribute__((ext_vector_type(8)));
typedef _Float16 half4 __attribute__((ext_vector_type(4)));
typedef float floatx4 __attribute__((ext_vector_type(4)));

#define B_    64
#define N_    512
#define DIN_  256
#define DH_   512
#define DOUT_ 256
#define H_    4
#define BN_   (B_ * N_)   // 32768

// raw waitcnt immediates (gfx9: vmcnt[3:0]|[15:14], exp[6:4], lgkm[11:8])
#define WAIT_VM4_LGKM0() __builtin_amdgcn_s_waitcnt(0x0074)  // vm<=4, lgkm<=0
#define WAIT_VM0_LGKM0() __builtin_amdgcn_s_waitcnt(0x0070)  // vm<=0, lgkm<=0
#define WAIT_VM4()       __builtin_amdgcn_s_waitcnt(0x0F74)  // vm<=4 only
#define WAIT_VM0()       __builtin_amdgcn_s_waitcnt(0x0F70)  // vm<=0 only
#define MEMBAR()         __asm__ __volatile__("" ::: "memory")
#define BAR()            do { MEMBAR(); __builtin_amdgcn_s_barrier(); MEMBAR(); } while (0)

__device__ static inline void async_copy16(const _Float16* g, _Float16* l) {
    __builtin_amdgcn_global_load_lds(
        (const __attribute__((address_space(1))) void*)g,
        (__attribute__((address_space(3))) void*)l, 16, 0, 0);
}

// ---------------------------------------------------------------------------
// 128x128-tile GEMM (BK=32, 4 waves, triple-buffered): small preprocessing
// shapes and main shapes whose 256^2 grid would be starved. 512-elem K-segs.
// ---------------------------------------------------------------------------
template <bool OUT_F16>
__global__ __launch_bounds__(256)
void gemm_f16(const _Float16* __restrict__ A, long long aS1, long long aS2, int lda, long long aSeg,
              const _Float16* __restrict__ B, long long bS1, long long bS2, int ldb, long long bSeg,
              void* __restrict__ Cv, long long cS1, long long cS2, int ldc,
              int K, const float* __restrict__ bias, int biasMode,
              long long biasS1, long long biasS2, int zShift)
{
    __shared__ __align__(16) _Float16 As[3][128 * 32];
    __shared__ __align__(16) _Float16 Bs[3][128 * 32];

    const int tid  = threadIdx.x;
    const int wave = tid >> 6;
    const int lane = tid & 63;
    const int quad = lane >> 4;
    const int r16  = lane & 15;

    const int z  = blockIdx.z;
    const int z1 = z >> zShift;
    const int z2 = z & ((1 << zShift) - 1);

    const int gx = gridDim.x, gy = gridDim.y;
    const int T = gx * gy;
    int lin = blockIdx.y * gx + blockIdx.x;
    int id2 = (T & 7) ? lin : ((lin & 7) * (T >> 3) + (lin >> 3));
    const int m0 = (id2 / gx) * 128;
    const int n0 = (id2 % gx) * 128;

    const int srow = lane >> 2;
    const int scol = (((lane & 3) ^ ((lane >> 3) & 3))) * 8;

    const _Float16* gaRow = A + z1 * aS1 + z2 * aS2
                              + (long long)(m0 + wave * 32 + srow) * lda + scol;
    const _Float16* gbRow = B + z1 * bS1 + z2 * bS2
                              + (long long)(n0 + wave * 32 + srow) * ldb + scol;

    const int wm = (wave >> 1) * 64;
    const int wn = (wave & 1) * 64;
    const int gl = (quad ^ ((r16 >> 1) & 3)) * 8;

    floatx4 acc[4][4];
#pragma unroll
    for (int i = 0; i < 4; i++)
#pragma unroll
        for (int j = 0; j < 4; j++) acc[i][j] = (floatx4){0.f, 0.f, 0.f, 0.f};

    auto stage = [&](int p, int k0) {
        const _Float16* a = gaRow + (long long)(k0 >> 9) * aSeg + (k0 & 511);
        const _Float16* b = gbRow + (long long)(k0 >> 9) * bSeg + (k0 & 511);
        _Float16* la = &As[p][wave * 1024];
        _Float16* lb = &Bs[p][wave * 1024];
        async_copy16(a,                    la);
        async_copy16(a + (size_t)16 * lda, la + 512);
        async_copy16(b,                    lb);
        async_copy16(b + (size_t)16 * ldb, lb + 512);
    };

    auto compute = [&](int p) {
        half8 af[4], bf[4];
#pragma unroll
        for (int i = 0; i < 4; i++)
            af[i] = *(const half8*)&As[p][(wm + i * 16 + r16) * 32 + gl];
#pragma unroll
        for (int j = 0; j < 4; j++)
            bf[j] = *(const half8*)&Bs[p][(wn + j * 16 + r16) * 32 + gl];
#pragma unroll
        for (int i = 0; i < 4; i++)
#pragma unroll
            for (int j = 0; j < 4; j++)
                acc[i][j] = __builtin_amdgcn_mfma_f32_16x16x32_f16(
                    bf[j], af[i], acc[i][j], 0, 0, 0);
    };

    const int niter = K >> 5;
    stage(0, 0);
    stage(1, 32);
    int pNext = 2;
    int pCur  = 0;
    for (int it = 0; it < niter - 1; ++it) {
        MEMBAR(); WAIT_VM4_LGKM0();
        __builtin_amdgcn_s_barrier();
        MEMBAR();
        if (it + 2 < niter) stage(pNext, (it + 2) << 5);
        compute(pCur);
        MEMBAR();
        pNext = (pNext == 2) ? 0 : pNext + 1;
        pCur  = (pCur  == 2) ? 0 : pCur  + 1;
    }
    MEMBAR(); WAIT_VM0_LGKM0();
    __builtin_amdgcn_s_barrier(); MEMBAR();
    compute(pCur);

    const float* bz = bias + z1 * biasS1 + z2 * biasS2;
    float*    Cf = (float*)Cv    + z1 * cS1 + z2 * cS2;
    _Float16* Ch = (_Float16*)Cv + z1 * cS1 + z2 * cS2;
#pragma unroll
    for (int i = 0; i < 4; i++) {
        const int row = m0 + wm + i * 16 + r16;
#pragma unroll
        for (int j = 0; j < 4; j++) {
            const int col = n0 + wn + j * 16 + quad * 4;
            float v0 = acc[i][j][0], v1 = acc[i][j][1],
                  v2 = acc[i][j][2], v3 = acc[i][j][3];
            if (biasMode == 1) {
                v0 += bz[col]; v1 += bz[col + 1];
                v2 += bz[col + 2]; v3 += bz[col + 3];
            } else if (biasMode == 2) {
                const float bv = bz[row];
                v0 += bv; v1 += bv; v2 += bv; v3 += bv;
            }
            const size_t idx = (size_t)row * ldc + col;
            if (OUT_F16) {
                half4 hv = {(_Float16)v0, (_Float16)v1, (_Float16)v2, (_Float16)v3};
                *(half4*)&Ch[idx] = hv;
            } else {
                float4 fv = {v0, v1, v2, v3};
                *(float4*)&Cf[idx] = fv;
            }
        }
    }
}

// ---------------------------------------------------------------------------
// 256x256 tile, 8 waves (2x4), BK=64, 8-phase interleave, counted vmcnt,
// XOR-swizzled LDS via pre-swizzled global source, setprio around MFMA.
// STATIC buffer map: even K-tiles -> buf0 (read p0-p3), odd -> buf1 (p4-p7).
// B col-half-0 fragments kept in regs across the K-tile (p3/p7 reg-only).
// Generalized K segmentation: segment size = 1<<aSh elements (aSh>=7).
// z-loop: one wg handles zLoop consecutive batches (pipeline continues across
// the boundary; in-loop epilogue + acc reset).
// zOrd (this round): XCD-aware z remap for zShift==2 (z = b*4+h) batches with
// gridDim.z % 32 == 0. phys bits: [2:0]=b&7, [4:3]=h, [7:5]=b>>3. Since XCD =
// linear_wg % 8 and h sits in bits 3-4 of z, all 4 h's of a b land on the
// SAME XCD -> the shared B operand (x_b / h1_b) is fetched once per L2.
// Requires zLoop==1.
// ---------------------------------------------------------------------------
template <bool OUT_F16>
__global__ __launch_bounds__(512, 2)
void gemm256(const _Float16* __restrict__ A, long long aS1, long long aS2, int lda, long long aSeg, int aSh,
             const _Float16* __restrict__ B, long long bS1, long long bS2, int ldb, long long bSeg, int bSh,
             void* __restrict__ Cv, long long cS1, long long cS2, int ldc,
             int K, const float* __restrict__ bias, int biasMode,
             long long biasS1, long long biasS2, int zShift, int zLoop, int zOrd)
{
    extern __shared__ __align__(16) _Float16 lds[];
    _Float16* AsB = lds;                 // [2][256*64]
    _Float16* BsB = lds + 2 * 256 * 64;  // [2][256*64]

    const int tid  = threadIdx.x;
    const int wave = tid >> 6;        // 0..7
    const int lane = tid & 63;
    const int quad = lane >> 4;
    const int r16  = lane & 15;
    const int wr   = wave >> 2;       // 0..1
    const int wc   = wave & 3;        // 0..3

    int pz = blockIdx.z;
    if (zOrd) {   // bijective remap (gridDim.z % 32 == 0, zShift==2, zLoop==1)
        const int b = (pz & 7) | ((pz >> 5) << 3);
        const int h = (pz >> 3) & 3;
        pz = (b << 2) + h;
    }
    const int zBase = pz * zLoop;
    const int zMask = (1 << zShift) - 1;

    const int aTSh = aSh - 6, aTMk = (1 << aTSh) - 1;
    const int bTSh = bSh - 6, bTMk = (1 << bTSh) - 1;

    const int ntiles = K >> 6;                    // K-tiles per z (pow2, even)
    const int ntSh   = __builtin_ctz(ntiles);
    const int ntHMsk = (ntiles >> 1) - 1;
    const int TTh    = (ntiles * zLoop) >> 1;     // main-loop iterations

    const int gx = gridDim.x, gy = gridDim.y;
    const int T_ = gx * gy;
    int lin = blockIdx.y * gx + blockIdx.x;
    int id2 = (T_ & 7) ? lin : ((lin & 7) * (T_ >> 3) + (lin >> 3));
    const int m0 = (id2 / gx) * 256;
    const int n0 = (id2 % gx) * 256;

    const int sr  = tid >> 3;                       // 0..63
    const int swz = ((tid & 7) ^ (sr & 7)) * 8;     // swizzled k-offset (elems)

    // per-z operand bases (zLoop <= 2)
    const int zz0 = zBase, zz1 = zBase + (zLoop - 1);
    const _Float16* gaA0 = A + (long long)(zz0 >> zShift) * aS1 + (long long)(zz0 & zMask) * aS2
                             + (long long)(m0 + sr) * lda + swz;
    const _Float16* gaA1 = A + (long long)(zz1 >> zShift) * aS1 + (long long)(zz1 & zMask) * aS2
                             + (long long)(m0 + sr) * lda + swz;
    const _Float16* gbB0 = B + (long long)(zz0 >> zShift) * bS1 + (long long)(zz0 & zMask) * bS2
                             + (long long)(n0 + sr) * ldb + swz;
    const _Float16* gbB1 = B + (long long)(zz1 >> zShift) * bS1 + (long long)(zz1 & zMask) * bS2
                             + (long long)(n0 + sr) * ldb + swz;

    const int arow = wr * 64 + r16;
    const int brow = wc * 32 + r16;
    const int rsw  = r16 & 7;
    const int gxk0 = (quad ^ rsw) * 8;
    const int gxk1 = ((4 + quad) ^ rsw) * 8;

    floatx4 acc[8][4];
#pragma unroll
    for (int i = 0; i < 8; i++)
#pragma unroll
        for (int j = 0; j < 4; j++) acc[i][j] = (floatx4){0.f, 0.f, 0.f, 0.f};

    half8 af[4][2], bf0s[2][2], bf1s[2][2];

    auto stageA = [&](int buf, int h, int T) {
        const int tz = T >> ntSh, tk = T & (ntiles - 1);
        const _Float16* s = (tz ? gaA1 : gaA0) + (long long)(h * 128) * lda
                          + (long long)(tk >> aTSh) * aSeg + ((tk & aTMk) << 6);
        _Float16* d = AsB + buf * 16384 + h * 8192 + wave * 512;
        async_copy16(s, d);
        async_copy16(s + (long long)64 * lda, d + 4096);
    };
    auto stageB = [&](int buf, int h, int T) {
        const int tz = T >> ntSh, tk = T & (ntiles - 1);
        const _Float16* s = (tz ? gbB1 : gbB0) + (long long)(h * 128) * ldb
                          + (long long)(tk >> bTSh) * bSeg + ((tk & bTMk) << 6);
        _Float16* d = BsB + buf * 16384 + h * 8192 + wave * 512;
        async_copy16(s, d);
        async_copy16(s + (long long)64 * ldb, d + 4096);
    };

    // epilogue: VGPR->global only, no LDS, no barriers.
    auto epi = [&](int zz) {
        const int z1 = zz >> zShift, z2 = zz & zMask;
        const float* bz = bias + (long long)z1 * biasS1 + (long long)z2 * biasS2;
        float*    Cf = (float*)Cv    + (long long)z1 * cS1 + (long long)z2 * cS2;
        _Float16* Ch = (_Float16*)Cv + (long long)z1 * cS1 + (long long)z2 * cS2;
#pragma unroll
        for (int f = 0; f < 8; f++) {
            const int row = m0 + (f >> 2) * 128 + wr * 64 + (f & 3) * 16 + r16;
#pragma unroll
            for (int j = 0; j < 4; j++) {
                const int col = n0 + (j >> 1) * 128 + wc * 32 + (j & 1) * 16 + quad * 4;
                float v0 = acc[f][j][0], v1 = acc[f][j][1],
                      v2 = acc[f][j][2], v3 = acc[f][j][3];
                if (biasMode == 1) {
                    v0 += bz[col]; v1 += bz[col + 1];
                    v2 += bz[col + 2]; v3 += bz[col + 3];
                } else if (biasMode == 2) {
                    const float bv = bz[row];
                    v0 += bv; v1 += bv; v2 += bv; v3 += bv;
                }
                const size_t idx = (size_t)row * ldc + col;
                if (OUT_F16) {
                    half4 hv = {(_Float16)v0, (_Float16)v1, (_Float16)v2, (_Float16)v3};
                    *(half4*)&Ch[idx] = hv;
                } else {
                    float4 fv = {v0, v1, v2, v3};
                    *(float4*)&Cf[idx] = fv;
                }
            }
        }
    };

#define LOAD_AF(RH, BUF) do { \
    const _Float16* ab_ = AsB + (BUF) * 16384 + ((RH) * 128 + arow) * 64; \
    _Pragma("unroll") \
    for (int i5 = 0; i5 < 4; i5++) { \
        af[i5][0] = *(const half8*)(ab_ + i5 * 1024 + gxk0); \
        af[i5][1] = *(const half8*)(ab_ + i5 * 1024 + gxk1); \
    } \
} while (0)

#define LOAD_BF(DST, CH, BUF) do { \
    const _Float16* bb_ = BsB + (BUF) * 16384 + ((CH) * 128 + brow) * 64; \
    _Pragma("unroll") \
    for (int j5 = 0; j5 < 2; j5++) { \
        DST[j5][0] = *(const half8*)(bb_ + j5 * 1024 + gxk0); \
        DST[j5][1] = *(const half8*)(bb_ + j5 * 1024 + gxk1); \
    } \
} while (0)

#define MFMA16(RH, CH, BFS) do { \
    _Pragma("unroll") \
    for (int i6 = 0; i6 < 4; i6++) { \
        _Pragma("unroll") \
        for (int j6 = 0; j6 < 2; j6++) { \
            floatx4 c_ = acc[(RH) * 4 + i6][(CH) * 2 + j6]; \
            c_ = __builtin_amdgcn_mfma_f32_16x16x32_f16(BFS[j6][0], af[i6][0], c_, 0, 0, 0); \
            c_ = __builtin_amdgcn_mfma_f32_16x16x32_f16(BFS[j6][1], af[i6][1], c_, 0, 0, 0); \
            acc[(RH) * 4 + i6][(CH) * 2 + j6] = c_; \
        } \
    } \
} while (0)

    // prologue: tile0 -> buf0 (all 4 halves), tile1 -> buf1 (A0, B1)
    stageA(0, 0, 0);
    stageB(0, 1, 0);
    stageA(0, 1, 0);
    stageB(0, 0, 0);
    stageA(1, 0, 1);
    stageB(1, 1, 1);
    WAIT_VM4();
    BAR();

    int zi = 0;
    for (int it = 0; it < TTh; ++it) {
        const int T = it * 2;
        const bool full = (it < TTh - 1);

        // ---- p0: (0,0) of tile T  [buf0]
        LOAD_AF(0, 0); LOAD_BF(bf0s, 0, 0);
        stageA(1, 1, T + 1);
        BAR();
        __builtin_amdgcn_s_setprio(1); MFMA16(0, 0, bf0s); __builtin_amdgcn_s_setprio(0);
        BAR();
        // ---- p1: (0,1)
        LOAD_BF(bf1s, 1, 0);
        stageB(1, 0, T + 1);
        BAR();
        __builtin_amdgcn_s_setprio(1); MFMA16(0, 1, bf1s); __builtin_amdgcn_s_setprio(0);
        BAR();
        // ---- p2: (1,1)
        LOAD_AF(1, 0);
        if (full) stageA(0, 0, T + 2);
        BAR();
        __builtin_amdgcn_s_setprio(1); MFMA16(1, 1, bf1s); __builtin_amdgcn_s_setprio(0);
        BAR();
        // ---- p3: (1,0)  regs-only  + W0
        if (full) stageB(0, 1, T + 2);
        BAR();
        __builtin_amdgcn_s_setprio(1); MFMA16(1, 0, bf0s); __builtin_amdgcn_s_setprio(0);
        if (full) WAIT_VM4(); else WAIT_VM0();
        BAR();
        // ---- p4: (0,0) of tile T+1  [buf1]
        LOAD_AF(0, 1); LOAD_BF(bf0s, 0, 1);
        if (full) stageA(0, 1, T + 2);
        BAR();
        __builtin_amdgcn_s_setprio(1); MFMA16(0, 0, bf0s); __builtin_amdgcn_s_setprio(0);
        BAR();
        // ---- p5: (0,1)
        LOAD_BF(bf1s, 1, 1);
        if (full) stageB(0, 0, T + 2);
        BAR();
        __builtin_amdgcn_s_setprio(1); MFMA16(0, 1, bf1s); __builtin_amdgcn_s_setprio(0);
        BAR();
        // ---- p6: (1,1)
        LOAD_AF(1, 1);
        if (full) stageA(1, 0, T + 3);
        BAR();
        __builtin_amdgcn_s_setprio(1); MFMA16(1, 1, bf1s); __builtin_amdgcn_s_setprio(0);
        BAR();
        // ---- p7: (1,0)  regs-only  + W1
        if (full) stageB(1, 1, T + 3);
        BAR();
        __builtin_amdgcn_s_setprio(1); MFMA16(1, 0, bf0s); __builtin_amdgcn_s_setprio(0);
        if (full) WAIT_VM4();
        BAR();

        // z-boundary: write out this batch's tile, reset accumulator.
        if (((it + 1) & ntHMsk) == 0) {
            epi(zBase + zi);
            ++zi;
#pragma unroll
            for (int i7 = 0; i7 < 8; i7++)
#pragma unroll
                for (int j7 = 0; j7 < 4; j7++)
                    acc[i7][j7] = (floatx4){0.f, 0.f, 0.f, 0.f};
        }
    }

#undef LOAD_AF
#undef LOAD_BF
#undef MFMA16
}

// ---------------------------------------------------------------------------
// in-place fp16 softmax over rows of 512, scaled by 0.25 (head mean).
// ---------------------------------------------------------------------------
__global__ __launch_bounds__(256)
void softmax_f16(_Float16* __restrict__ S)
{
    const int row  = blockIdx.x * 4 + (threadIdx.x >> 6);
    const int lane = threadIdx.x & 63;
    _Float16* s = S + (size_t)row * 512 + lane * 8;
    half8 h = *(const half8*)s;
    float v[8];
    float mx = -1e30f;
#pragma unroll
    for (int j = 0; j < 8; j++) { v[j] = (float)h[j]; mx = fmaxf(mx, v[j]); }
#pragma unroll
    for (int off = 32; off; off >>= 1) mx = fmaxf(mx, __shfl_xor(mx, off));
    float sum = 0.f;
#pragma unroll
    for (int j = 0; j < 8; j++) { v[j] = __expf(v[j] - mx); sum += v[j]; }
#pragma unroll
    for (int off = 32; off; off >>= 1) sum += __shfl_xor(sum, off);
    const float inv = 0.25f / sum;
#pragma unroll
    for (int j = 0; j < 8; j++) h[j] = (_Float16)(v[j] * inv);
    *(half8*)s = h;
}

// 4 fp32->fp16 conversions fused into one launch (ranges in float4 units).
__global__ __launch_bounds__(256)
void cvt_multi(const float* __restrict__ s0, _Float16* __restrict__ d0, int c0,
               const float* __restrict__ s1, _Float16* __restrict__ d1, int c1,
               const float* __restrict__ s2, _Float16* __restrict__ d2, int c2,
               const float* __restrict__ s3, _Float16* __restrict__ d3, int c3)
{
    int i = blockIdx.x * 256 + threadIdx.x;
    const float* s; _Float16* d;
    if (i < c0) { s = s0; d = d0; }
    else { i -= c0;
        if (i < c1) { s = s1; d = d1; }
        else { i -= c1;
            if (i < c2) { s = s2; d = d2; }
            else { i -= c2; s = s3; d = d3; } } }
    const float4 f = ((const float4*)s)[i];
    half4 hv = {(_Float16)f.x, (_Float16)f.y, (_Float16)f.z, (_Float16)f.w};
    *(half4*)(d + (size_t)i * 4) = hv;
}

// in [G][R][C] -> out [G][C][R], fp32 -> fp16
__global__ __launch_bounds__(256)
void transpose_cvt(const float* __restrict__ in, _Float16* __restrict__ out,
                   int R, int C)
{
    __shared__ float tile[32][33];
    const int g  = blockIdx.z;
    const int c0 = blockIdx.x * 32;
    const int r0 = blockIdx.y * 32;
    const float* inp  = in  + (size_t)g * R * C;
    _Float16*    outp = out + (size_t)g * R * C;
#pragma unroll
    for (int i = threadIdx.y; i < 32; i += 8)
        tile[i][threadIdx.x] = inp[(size_t)(r0 + i) * C + c0 + threadIdx.x];
    __syncthreads();
#pragma unroll
    for (int i = threadIdx.y; i < 32; i += 8)
        outp[(size_t)(c0 + i) * R + r0 + threadIdx.x] = (_Float16)tile[threadIdx.x][i];
}

// fused small preprocessing reductions: wk_bq(w0), wk_bq(w1), fold_bias, sum_b0
// block ranges: [0,4) w0; [4,12) w1; [12,16) be1p; [16,18) sb0.
__global__ __launch_bounds__(256)
void small_ops(const float* __restrict__ kq_w0, const float* __restrict__ kq_b0,
               const float* __restrict__ kq_w1, const float* __restrict__ kq_b1,
               const _Float16* __restrict__ projwT, const float* __restrict__ e_b1,
               const float* __restrict__ e_b0,
               float* __restrict__ w0, float* __restrict__ w1,
               float* __restrict__ be1p, float* __restrict__ sb0)
{
    const int blk = blockIdx.x;
    if (blk < 4) {                       // w0[h][d], d < DIN
        const int t = blk * 256 + threadIdx.x;
        const int h = t >> 8, d = t & 255;
        const float* wk = kq_w0 + ((size_t)(h << 8) + d) * (2 * DH_);
        const float* bq = kq_b0 + (size_t)h * 2 * DH_ + DH_;
        float s = 0.f;
        for (int e = 0; e < DH_; e++) s += wk[e] * bq[e];
        w0[t] = s;
    } else if (blk < 12) {               // w1[h][d], d < DH
        const int t = (blk - 4) * 256 + threadIdx.x;
        const int h = t >> 9, d = t & 511;
        const float* wk = kq_w1 + ((size_t)(h << 9) + d) * (2 * DH_);
        const float* bq = kq_b1 + (size_t)h * 2 * DH_ + DH_;
        float s = 0.f;
        for (int e = 0; e < DH_; e++) s += wk[e] * bq[e];
        w1[t] = s;
    } else if (blk < 16) {               // be1p[h][o]
        const int t = (blk - 12) * 256 + threadIdx.x;
        const int h = t >> 8, o = t & 255;
        const _Float16* pw = projwT + (size_t)o * DH_;
        const float*    eb = e_b1 + (size_t)h * DH_;
        float s = 0.f;
        for (int d = 0; d < DH_; d++) s += (float)pw[d] * eb[d];
        be1p[t] = s;
    } else {                             // sb0[e]
        const int e = (blk - 16) * 256 + threadIdx.x;
        sb0[e] = 0.25f * (e_b0[e] + e_b0[DH_ + e] + e_b0[2 * DH_ + e] + e_b0[3 * DH_ + e]);
    }
}

// V[b][h][n] = x[b*N+n, :] . w[h, :] — one wave/row, 4 heads, vectorized half4
__global__ __launch_bounds__(256)
void compute_v(const _Float16* __restrict__ x, const float* __restrict__ w,
               float* __restrict__ V, int Kin)
{
    const int row  = blockIdx.x * 4 + (threadIdx.x >> 6);
    const int lane = threadIdx.x & 63;
    const int b = row >> 9, n = row & 511;
    const _Float16* xr = x + (size_t)row * Kin;
    float s0 = 0.f, s1 = 0.f, s2 = 0.f, s3 = 0.f;
    const int iters = Kin >> 8;          // lanes cover 256 elems/iter (4 each)
    for (int j = 0; j < iters; j++) {
        const int e = j * 256 + lane * 4;
        const half4  xv = *(const half4*)(xr + e);
        const float4 a0 = *(const float4*)(w + e);
        const float4 a1 = *(const float4*)(w + Kin + e);
        const float4 a2 = *(const float4*)(w + 2 * Kin + e);
        const float4 a3 = *(const float4*)(w + 3 * Kin + e);
        const float x0 = (float)xv[0], x1 = (float)xv[1],
                    x2 = (float)xv[2], x3 = (float)xv[3];
        s0 += x0 * a0.x + x1 * a0.y + x2 * a0.z + x3 * a0.w;
        s1 += x0 * a1.x + x1 * a1.y + x2 * a1.z + x3 * a1.w;
        s2 += x0 * a2.x + x1 * a2.y + x2 * a2.z + x3 * a2.w;
        s3 += x0 * a3.x + x1 * a3.y + x2 * a3.z + x3 * a3.w;
    }
#pragma unroll
    for (int off = 32; off; off >>= 1) {
        s0 += __shfl_xor(s0, off); s1 += __shfl_xor(s1, off);
        s2 += __shfl_xor(s2, off); s3 += __shfl_xor(s3, off);
    }
    if (lane == 0) {
        float* vb = V + ((size_t)b * H_) * N_ + n;
        vb[0] = s0; vb[N_] = s1; vb[2 * N_] = s2; vb[3 * N_] = s3;
    }
}

// ---------------------------------------------------------------------------
extern "C" void kernel_launch(void* const* d_in, const int* in_sizes, int n_in,
                              void* d_out, int out_size, void* d_ws, size_t ws_size,
                              hipStream_t stream)
{
    (void)in_sizes; (void)n_in; (void)out_size;

    static bool attr_set = false;
    if (!attr_set) {
        hipFuncSetAttribute((const void*)gemm256<true>,
                            hipFuncAttributeMaxDynamicSharedMemorySize, 131072);
        hipFuncSetAttribute((const void*)gemm256<false>,
                            hipFuncAttributeMaxDynamicSharedMemorySize, 131072);
        attr_set = true;
    }

    const float* x      = (const float*)d_in[0];
    const float* e_w0   = (const float*)d_in[1];
    const float* e_b0   = (const float*)d_in[2];
    const float* kq_w0  = (const float*)d_in[3];
    const float* kq_b0  = (const float*)d_in[4];
    const float* e_w1   = (const float*)d_in[5];
    const float* e_b1   = (const float*)d_in[6];
    const float* kq_w1  = (const float*)d_in[7];
    const float* kq_b1  = (const float*)d_in[8];
    const float* proj_w = (const float*)d_in[9];
    const float* proj_b = (const float*)d_in[10];
    float* out = (float*)d_out;

    char* ws = (char*)d_ws;
    size_t off = 0;
    auto alloc = [&](size_t bytes) -> char* {
        char* p = ws + off;
        off += (bytes + 255) & ~(size_t)255;
        return p;
    };

    // --- persistent (~73 MB incl. xT) --------------------------------------
    _Float16* x16    = (_Float16*)alloc((size_t)BN_ * DIN_ * 2);
    _Float16* h1_16  = (_Float16*)alloc((size_t)BN_ * DH_ * 2);
    _Float16* ewT0   = (_Float16*)alloc((size_t)H_ * DH_ * DIN_ * 2);
    _Float16* projwT = (_Float16*)alloc((size_t)DOUT_ * DH_ * 2);
    _Float16* Mt0    = (_Float16*)alloc((size_t)H_ * DIN_ * DIN_ * 2);
    _Float16* Mt1    = (_Float16*)alloc((size_t)H_ * DH_ * DH_ * 2);
    _Float16* We1pT  = (_Float16*)alloc((size_t)H_ * DOUT_ * DH_ * 2);
    float*    be1p   = (float*)alloc((size_t)H_ * DOUT_ * 4);
    float*    w0     = (float*)alloc((size_t)H_ * DIN_ * 4);
    float*    w1     = (float*)alloc((size_t)H_ * DH_ * 4);
    float*    sb0    = (float*)alloc((size_t)DH_ * 4);
    float*    Vb     = (float*)alloc((size_t)B_ * H_ * N_ * 4);
    _Float16* xT     = (_Float16*)alloc((size_t)BN_ * DIN_ * 2);   // [b][d][n]

    const size_t persistAll = off;
    const long long SB = (long long)N_ * N_;
    const size_t SC_FULL  = (size_t)B_ * H_ * N_ * N_ * 2;       // 134.2 MB
    const size_t SC_CHUNK = SC_FULL / 2;                          // 67.1 MB
    const size_t A2_SZ    = (size_t)BN_ * H_ * DIN_ * 2;          // 67.1 MB
    const size_t SLACK    = 1u << 20;

    // tier A: full-batch blk0 + deferred full-batch blk1 PV  (~276 MB)
    // tier B: CH=32 chunks (ws known to be in [232,276) on this harness)
    const bool tierA = ws_size >= persistAll + SC_FULL + A2_SZ + SLACK;

    _Float16* Sc = (_Float16*)alloc(tierA ? SC_FULL : SC_CHUNK);
    _Float16* A2 = (_Float16*)alloc(A2_SZ);

    // transient cvt buffers live inside A2 (dead before A2's first GEMM use)
    _Float16* kq0_16 = A2;                                        // 2.1 MB
    _Float16* kq1_16 = kq0_16 + (size_t)H_ * DIN_ * 2 * DH_;      // 4.2 MB
    _Float16* ew1_16 = kq1_16 + (size_t)H_ * DH_ * 2 * DH_;       // 2.1 MB

    // routing: 256^2 kernel when its grid (after zLoop) fills the chip;
    // otherwise 128^2 kernel (4x the workgroups; zLoop==1, zOrd==0 only).
    auto gemm = [&](bool outF16,
                    const _Float16* A, long long aS1, long long aS2, int lda, long long aSeg,
                    const _Float16* Bp, long long bS1, long long bS2, int ldb, long long bSeg,
                    void* C, long long cS1, long long cS2, int ldc,
                    int M, int Nn, int K, int batches, int zShift,
                    const float* bias, int biasMode, long long biasS1, long long biasS2,
                    int aSh, int bSh, int zLoop, int zOrd) {
        const bool can256 = (M % 256 == 0) && (Nn % 256 == 0) && (K % 128 == 0);
        const bool can128 = (M % 128 == 0) && (Nn % 128 == 0) && (K % 32 == 0)
                          && (aSh == 9) && (bSh == 9) && (zLoop == 1) && (zOrd == 0);
        const long long wg256 = can256
            ? (long long)(M >> 8) * (Nn >> 8) * (batches / zLoop) : 0;
        bool use256;
        if (!can128)            use256 = true;
        else if (!can256)       use256 = false;
        else                    use256 = (wg256 >= 192) || (wg256 >= 32 && wg256 * 4 < 128);
        if (use256) {
            dim3 grid(Nn / 256, M / 256, batches / zLoop), block(512);
            if (outF16)
                gemm256<true><<<grid, block, 131072, stream>>>(A, aS1, aS2, lda, aSeg, aSh,
                    Bp, bS1, bS2, ldb, bSeg, bSh, C, cS1, cS2, ldc, K, bias, biasMode, biasS1, biasS2, zShift, zLoop, zOrd);
            else
                gemm256<false><<<grid, block, 131072, stream>>>(A, aS1, aS2, lda, aSeg, aSh,
                    Bp, bS1, bS2, ldb, bSeg, bSh, C, cS1, cS2, ldc, K, bias, biasMode, biasS1, biasS2, zShift, zLoop, zOrd);
        } else {
            dim3 grid(Nn / 128, M / 128, batches), block(256);
            if (outF16)
                gemm_f16<true><<<grid, block, 0, stream>>>(A, aS1, aS2, lda, aSeg,
                    Bp, bS1, bS2, ldb, bSeg, C, cS1, cS2, ldc, K, bias, biasMode, biasS1, biasS2, zShift);
            else
                gemm_f16<false><<<grid, block, 0, stream>>>(A, aS1, aS2, lda, aSeg,
                    Bp, bS1, bS2, ldb, bSeg, C, cS1, cS2, ldc, K, bias, biasMode, biasS1, biasS2, zShift);
        }
    };

    // --- preprocessing -----------------------------------------------------
    {
        const int c0 = BN_ * DIN_ / 4;              // x -> x16
        const int c1 = H_ * DIN_ * 2 * DH_ / 4;     // kq_w0
        const int c2 = H_ * DH_ * 2 * DH_ / 4;      // kq_w1
        const int c3 = H_ * DH_ * DH_ / 4;          // e_w1
        cvt_multi<<<(c0 + c1 + c2 + c3) / 256, 256, 0, stream>>>(
            x, x16, c0, kq_w0, kq0_16, c1, kq_w1, kq1_16, c2, e_w1, ew1_16, c3);
    }
    transpose_cvt<<<dim3(DH_ / 32, DIN_ / 32, H_), dim3(32, 8), 0, stream>>>(e_w0, ewT0, DIN_, DH_);
    transpose_cvt<<<dim3(DOUT_ / 32, DH_ / 32, 1), dim3(32, 8), 0, stream>>>(proj_w, projwT, DH_, DOUT_);
    transpose_cvt<<<dim3(DIN_ / 32, N_ / 32, B_), dim3(32, 8), 0, stream>>>(x, xT, N_, DIN_);
    small_ops<<<18, 256, 0, stream>>>(kq_w0, kq_b0, kq_w1, kq_b1,
                                      projwT, e_b1, e_b0, w0, w1, be1p, sb0);

    // Mt_h = Wk_h * Wq_h^T  (so T = x * Mt^T = x * (Wq Wk^T))
    gemm(true, kq0_16, 0, (long long)DIN_ * 2 * DH_, 2 * DH_, 512,
         kq0_16 + DH_, 0, (long long)DIN_ * 2 * DH_, 2 * DH_, 512,
         Mt0, 0, (long long)DIN_ * DIN_, DIN_,
         DIN_, DIN_, DH_, H_, 2, nullptr, 0, 0, 0, 9, 9, 1, 0);
    gemm(true, kq1_16, 0, (long long)DH_ * 2 * DH_, 2 * DH_, 512,
         kq1_16 + DH_, 0, (long long)DH_ * 2 * DH_, 2 * DH_, 512,
         Mt1, 0, (long long)DH_ * DH_, DH_,
         DH_, DH_, DH_, H_, 2, nullptr, 0, 0, 0, 9, 9, 1, 0);
    // We1pT[h][o][d] = sum_d' projwT[o][d'] * e_w1[h][d][d']
    gemm(true, projwT, 0, 0, DH_, 512,
         ew1_16, 0, (long long)DH_ * DH_, DH_, 512,
         We1pT, 0, (long long)DOUT_ * DH_, DH_,
         DOUT_, DH_, DH_, H_, 2, nullptr, 0, 0, 0, 9, 9, 1, 0);

    // --- block 0: G-path (h1 = sum_h (P_h x) W_h + 0.25 sum_h b_h) ---------
    {
        const int CH0  = tierA ? B_ : 32;
        const int NCH0 = B_ / CH0;
        const size_t GCH = (size_t)CH0 * N_ * H_ * DIN_;   // elems per A2 slot
        compute_v<<<BN_ / 4, 256, 0, stream>>>(x16, w0, Vb, DIN_);
        for (int c = 0; c < NCH0; c++) {
            const _Float16* xc  = x16 + (size_t)c * CH0 * N_ * DIN_;
            const _Float16* xTc = xT  + (size_t)c * CH0 * DIN_ * N_;
            _Float16* slot = A2 + (size_t)c * GCH;
            // T0 -> slot c (chunk 0 overwrites dead cvt scratch)
            gemm(true, xc, 0, 0, DIN_, 512,
                 Mt0, 0, 0, DIN_, 512,
                 slot, 0, 0, H_ * DIN_,
                 CH0 * N_, H_ * DIN_, DIN_, 1, 0, nullptr, 0, 0, 0, 9, 9, 1, 0);
            // S = T x^T + V   (zOrd: h-group on same XCD -> x_b L2-shared)
            gemm(true, slot, (long long)N_ * H_ * DIN_, DIN_, H_ * DIN_, 512,
                 xc, (long long)N_ * DIN_, 0, DIN_, 512,
                 Sc, (long long)H_ * SB, SB, N_,
                 N_, N_, DIN_, CH0 * H_, 2,
                 Vb + (size_t)c * CH0 * H_ * N_, 1, (long long)H_ * N_, N_, 9, 9, 1, 1);
            softmax_f16<<<CH0 * H_ * N_ / 4, 256, 0, stream>>>(Sc);
            // G[b][h][q][d] = P[b,h] . x_b  -> slot c (T0 dead)
            gemm(true, Sc, (long long)H_ * SB, SB, N_, 512,
                 xTc, (long long)DIN_ * N_, 0, N_, 512,
                 slot, (long long)H_ * N_ * DIN_, (long long)N_ * DIN_, DIN_,
                 N_, DIN_, N_, CH0 * H_, 2, nullptr, 0, 0, 0, 9, 9, 1, 1);
        }
        // deferred h1 over ALL batches: grid (2,2,64) = 256 wgs
        gemm(true, A2, (long long)H_ * N_ * DIN_, 0, DIN_, (long long)N_ * DIN_,
             ewT0, 0, 0, DIN_, (long long)DH_ * DIN_,
             h1_16, (long long)N_ * DH_, 0, DH_,
             N_, DH_, H_ * DIN_, B_, 0, sb0, 1, 0, 0, 8, 8, 1, 0);
    }

    // --- block 1 -----------------------------------------------------------
    {
        compute_v<<<BN_ / 4, 256, 0, stream>>>(h1_16, w1, Vb, DH_);
        for (int c = 0; c < 2; c++) {
            const _Float16* hc = h1_16 + (size_t)c * 32 * N_ * DH_;
            _Float16* Scp = tierA ? Sc + (size_t)c * 32 * H_ * SB : Sc;
            // T1 -> A2, reshaped (M=256, batches=64, zLoop=2): 256 wgs, 1 round
            gemm(true, hc, (long long)256 * DH_, 0, DH_, 512,
                 Mt1, 0, 0, DH_, 512,
                 A2, (long long)256 * H_ * DH_, 0, H_ * DH_,
                 256, H_ * DH_, DH_, 64, 0, nullptr, 0, 0, 0, 9, 9, 2, 0);
            // S1  (zOrd: h-group on same XCD -> h1_b L2-shared)
            gemm(true, A2, (long long)N_ * H_ * DH_, DH_, H_ * DH_, 512,
                 hc, (long long)N_ * DH_, 0, DH_, 512,
                 Scp, (long long)H_ * SB, SB, N_,
                 N_, N_, DH_, 32 * H_, 2,
                 Vb + (size_t)c * 32 * H_ * N_, 1, (long long)H_ * N_, N_, 9, 9, 1, 1);
            softmax_f16<<<32 * H_ * N_ / 4, 256, 0, stream>>>(Scp);
            if (!tierA) {
                // embW chunk -> A2 (T1 dead)
                gemm(true, We1pT, 0, 0, DH_, 512,
                     hc, (long long)N_ * DH_, 0, DH_, 512,
                     A2, (long long)H_ * DOUT_ * N_, 0, N_,
                     H_ * DOUT_, N_, DH_, 32, 0, be1p, 2, 0, 0, 9, 9, 1, 0);
                // PV chunk (fp32 out) — routed to gemm_f16: 256 wgs
                gemm(false, Scp, (long long)H_ * SB, 0, N_, SB,
                     A2, (long long)H_ * DOUT_ * N_, 0, N_, (long long)DOUT_ * N_,
                     out + (size_t)c * 32 * N_ * DOUT_, (long long)N_ * DOUT_, 0, DOUT_,
                     N_, DOUT_, H_ * N_, 32, 0, proj_b, 1, 0, 0, 9, 9, 1, 0);
            }
        }
        if (tierA) {
            // embW full -> A2 (T1 dead after last S1)
            gemm(true, We1pT, 0, 0, DH_, 512,
                 h1_16, (long long)N_ * DH_, 0, DH_, 512,
                 A2, (long long)H_ * DOUT_ * N_, 0, N_,
                 H_ * DOUT_, N_, DH_, B_, 0, be1p, 2, 0, 0, 9, 9, 1, 0);
            // deferred full-batch PV — routed to gemm_f16: 512 wgs
            gemm(false, Sc, (long long)H_ * SB, 0, N_, SB,
                 A2, (long long)H_ * DOUT_ * N_, 0, N_, (long long)DOUT_ * N_,
                 out, (long long)N_ * DOUT_, 0, DOUT_,
                 N_, DOUT_, H_ * N_, B_, 0, proj_b, 1, 0, 0, 9, 9, 1, 0);
        }
    }
}

// Round 8
// 894.970 us; speedup vs baseline: 1.1869x; 1.0361x over previous
//
#include <hip/hip_runtime.h>

typedef _Float16 half8 __attribute__((ext_vector_type(8)));
typedef _Float16 half4 __attribute__((ext_vector_type(4)));
typedef float floatx4 __attribute__((ext_vector_type(4)));

#define B_    64
#define N_    512
#define DIN_  256
#define DH_   512
#define DOUT_ 256
#define H_    4
#define BN_   (B_ * N_)   // 32768

// raw waitcnt immediates (gfx9: vmcnt[3:0]|[15:14], exp[6:4], lgkm[11:8])
#define WAIT_VM4_LGKM0() __builtin_amdgcn_s_waitcnt(0x0074)  // vm<=4, lgkm<=0
#define WAIT_VM0_LGKM0() __builtin_amdgcn_s_waitcnt(0x0070)  // vm<=0, lgkm<=0
#define WAIT_VM4()       __builtin_amdgcn_s_waitcnt(0x0F74)  // vm<=4 only
#define WAIT_VM0()       __builtin_amdgcn_s_waitcnt(0x0F70)  // vm<=0 only
#define MEMBAR()         __asm__ __volatile__("" ::: "memory")
#define BAR()            do { MEMBAR(); __builtin_amdgcn_s_barrier(); MEMBAR(); } while (0)

__device__ static inline void async_copy16(const _Float16* g, _Float16* l) {
    __builtin_amdgcn_global_load_lds(
        (const __attribute__((address_space(1))) void*)g,
        (__attribute__((address_space(3))) void*)l, 16, 0, 0);
}

// ---------------------------------------------------------------------------
// 128x128-tile GEMM (BK=32, 4 waves, triple-buffered): small preprocessing
// shapes and main shapes whose 256^2 grid would be starved. 512-elem K-segs.
// ---------------------------------------------------------------------------
template <bool OUT_F16>
__global__ __launch_bounds__(256)
void gemm_f16(const _Float16* __restrict__ A, long long aS1, long long aS2, int lda, long long aSeg,
              const _Float16* __restrict__ B, long long bS1, long long bS2, int ldb, long long bSeg,
              void* __restrict__ Cv, long long cS1, long long cS2, int ldc,
              int K, const float* __restrict__ bias, int biasMode,
              long long biasS1, long long biasS2, int zShift)
{
    __shared__ __align__(16) _Float16 As[3][128 * 32];
    __shared__ __align__(16) _Float16 Bs[3][128 * 32];

    const int tid  = threadIdx.x;
    const int wave = tid >> 6;
    const int lane = tid & 63;
    const int quad = lane >> 4;
    const int r16  = lane & 15;

    const int z  = blockIdx.z;
    const int z1 = z >> zShift;
    const int z2 = z & ((1 << zShift) - 1);

    const int gx = gridDim.x, gy = gridDim.y;
    const int T = gx * gy;
    int lin = blockIdx.y * gx + blockIdx.x;
    int id2 = (T & 7) ? lin : ((lin & 7) * (T >> 3) + (lin >> 3));
    const int m0 = (id2 / gx) * 128;
    const int n0 = (id2 % gx) * 128;

    const int srow = lane >> 2;
    const int scol = (((lane & 3) ^ ((lane >> 3) & 3))) * 8;

    const _Float16* gaRow = A + z1 * aS1 + z2 * aS2
                              + (long long)(m0 + wave * 32 + srow) * lda + scol;
    const _Float16* gbRow = B + z1 * bS1 + z2 * bS2
                              + (long long)(n0 + wave * 32 + srow) * ldb + scol;

    const int wm = (wave >> 1) * 64;
    const int wn = (wave & 1) * 64;
    const int gl = (quad ^ ((r16 >> 1) & 3)) * 8;

    floatx4 acc[4][4];
#pragma unroll
    for (int i = 0; i < 4; i++)
#pragma unroll
        for (int j = 0; j < 4; j++) acc[i][j] = (floatx4){0.f, 0.f, 0.f, 0.f};

    auto stage = [&](int p, int k0) {
        const _Float16* a = gaRow + (long long)(k0 >> 9) * aSeg + (k0 & 511);
        const _Float16* b = gbRow + (long long)(k0 >> 9) * bSeg + (k0 & 511);
        _Float16* la = &As[p][wave * 1024];
        _Float16* lb = &Bs[p][wave * 1024];
        async_copy16(a,                    la);
        async_copy16(a + (size_t)16 * lda, la + 512);
        async_copy16(b,                    lb);
        async_copy16(b + (size_t)16 * ldb, lb + 512);
    };

    auto compute = [&](int p) {
        half8 af[4], bf[4];
#pragma unroll
        for (int i = 0; i < 4; i++)
            af[i] = *(const half8*)&As[p][(wm + i * 16 + r16) * 32 + gl];
#pragma unroll
        for (int j = 0; j < 4; j++)
            bf[j] = *(const half8*)&Bs[p][(wn + j * 16 + r16) * 32 + gl];
#pragma unroll
        for (int i = 0; i < 4; i++)
#pragma unroll
            for (int j = 0; j < 4; j++)
                acc[i][j] = __builtin_amdgcn_mfma_f32_16x16x32_f16(
                    bf[j], af[i], acc[i][j], 0, 0, 0);
    };

    const int niter = K >> 5;
    stage(0, 0);
    stage(1, 32);
    int pNext = 2;
    int pCur  = 0;
    for (int it = 0; it < niter - 1; ++it) {
        MEMBAR(); WAIT_VM4_LGKM0();
        __builtin_amdgcn_s_barrier();
        MEMBAR();
        if (it + 2 < niter) stage(pNext, (it + 2) << 5);
        compute(pCur);
        MEMBAR();
        pNext = (pNext == 2) ? 0 : pNext + 1;
        pCur  = (pCur  == 2) ? 0 : pCur  + 1;
    }
    MEMBAR(); WAIT_VM0_LGKM0();
    __builtin_amdgcn_s_barrier(); MEMBAR();
    compute(pCur);

    const float* bz = bias + z1 * biasS1 + z2 * biasS2;
    float*    Cf = (float*)Cv    + z1 * cS1 + z2 * cS2;
    _Float16* Ch = (_Float16*)Cv + z1 * cS1 + z2 * cS2;
#pragma unroll
    for (int i = 0; i < 4; i++) {
        const int row = m0 + wm + i * 16 + r16;
#pragma unroll
        for (int j = 0; j < 4; j++) {
            const int col = n0 + wn + j * 16 + quad * 4;
            float v0 = acc[i][j][0], v1 = acc[i][j][1],
                  v2 = acc[i][j][2], v3 = acc[i][j][3];
            if (biasMode == 1) {
                v0 += bz[col]; v1 += bz[col + 1];
                v2 += bz[col + 2]; v3 += bz[col + 3];
            } else if (biasMode == 2) {
                const float bv = bz[row];
                v0 += bv; v1 += bv; v2 += bv; v3 += bv;
            }
            const size_t idx = (size_t)row * ldc + col;
            if (OUT_F16) {
                half4 hv = {(_Float16)v0, (_Float16)v1, (_Float16)v2, (_Float16)v3};
                *(half4*)&Ch[idx] = hv;
            } else {
                float4 fv = {v0, v1, v2, v3};
                *(float4*)&Cf[idx] = fv;
            }
        }
    }
}

// ---------------------------------------------------------------------------
// 256x256 tile, 8 waves (2x4), BK=64, 8-phase interleave, counted vmcnt,
// XOR-swizzled LDS via pre-swizzled global source, setprio around MFMA.
// STATIC buffer map: even K-tiles -> buf0 (read p0-p3), odd -> buf1 (p4-p7).
// B col-half-0 fragments kept in regs across the K-tile (p3/p7 reg-only).
// Generalized K segmentation: segment size = 1<<aSh elements (aSh>=7).
// z-loop: one wg handles zLoop batches (pipeline continues across boundary;
// in-loop epilogue + acc reset).
// zOrd modes:
//   0: zz0 = pz*zLoop, zz1 = zz0 + (zLoop-1)          (consecutive)
//   1: XCD h-grouping for zShift==2, grid.z==128, zLoop==1:
//      b=(pz&7)|((pz>>5)<<3), h=(pz>>3)&3 -> all h of a b on same XCD.
//   2: XCD h-grouping + b-PAIR continuation, zShift==2, batches==128,
//      zLoop==2, grid.z==64: b=pz&15, h=pz>>4; zz0=b*4+h, zz1=zz0+64
//      (i.e. (b,h) then (b+16,h)). flat%8 = 4*(b&1)+xy is h-independent ->
//      L2 h-sharing preserved; paired batch shares NOTHING -> no eviction.
// ---------------------------------------------------------------------------
template <bool OUT_F16>
__global__ __launch_bounds__(512, 2)
void gemm256(const _Float16* __restrict__ A, long long aS1, long long aS2, int lda, long long aSeg, int aSh,
             const _Float16* __restrict__ B, long long bS1, long long bS2, int ldb, long long bSeg, int bSh,
             void* __restrict__ Cv, long long cS1, long long cS2, int ldc,
             int K, const float* __restrict__ bias, int biasMode,
             long long biasS1, long long biasS2, int zShift, int zLoop, int zOrd)
{
    extern __shared__ __align__(16) _Float16 lds[];
    _Float16* AsB = lds;                 // [2][256*64]
    _Float16* BsB = lds + 2 * 256 * 64;  // [2][256*64]

    const int tid  = threadIdx.x;
    const int wave = tid >> 6;        // 0..7
    const int lane = tid & 63;
    const int quad = lane >> 4;
    const int r16  = lane & 15;
    const int wr   = wave >> 2;       // 0..1
    const int wc   = wave & 3;        // 0..3

    const int pz = blockIdx.z;
    int zz0, zz1;
    if (zOrd == 1) {
        const int b = (pz & 7) | ((pz >> 5) << 3);
        const int h = (pz >> 3) & 3;
        zz0 = (b << 2) + h; zz1 = zz0;
    } else if (zOrd == 2) {
        const int b = pz & 15;
        const int h = pz >> 4;
        zz0 = (b << 2) + h; zz1 = zz0 + 64;
    } else {
        zz0 = pz * zLoop; zz1 = zz0 + (zLoop - 1);
    }
    const int zMask = (1 << zShift) - 1;

    const int aTSh = aSh - 6, aTMk = (1 << aTSh) - 1;
    const int bTSh = bSh - 6, bTMk = (1 << bTSh) - 1;

    const int ntiles = K >> 6;                    // K-tiles per z (pow2, even)
    const int ntSh   = __builtin_ctz(ntiles);
    const int ntHMsk = (ntiles >> 1) - 1;
    const int TTh    = (ntiles * zLoop) >> 1;     // main-loop iterations

    const int gx = gridDim.x, gy = gridDim.y;
    const int T_ = gx * gy;
    int lin = blockIdx.y * gx + blockIdx.x;
    int id2 = (T_ & 7) ? lin : ((lin & 7) * (T_ >> 3) + (lin >> 3));
    const int m0 = (id2 / gx) * 256;
    const int n0 = (id2 % gx) * 256;

    const int sr  = tid >> 3;                       // 0..63
    const int swz = ((tid & 7) ^ (sr & 7)) * 8;     // swizzled k-offset (elems)

    const _Float16* gaA0 = A + (long long)(zz0 >> zShift) * aS1 + (long long)(zz0 & zMask) * aS2
                             + (long long)(m0 + sr) * lda + swz;
    const _Float16* gaA1 = A + (long long)(zz1 >> zShift) * aS1 + (long long)(zz1 & zMask) * aS2
                             + (long long)(m0 + sr) * lda + swz;
    const _Float16* gbB0 = B + (long long)(zz0 >> zShift) * bS1 + (long long)(zz0 & zMask) * bS2
                             + (long long)(n0 + sr) * ldb + swz;
    const _Float16* gbB1 = B + (long long)(zz1 >> zShift) * bS1 + (long long)(zz1 & zMask) * bS2
                             + (long long)(n0 + sr) * ldb + swz;

    const int arow = wr * 64 + r16;
    const int brow = wc * 32 + r16;
    const int rsw  = r16 & 7;
    const int gxk0 = (quad ^ rsw) * 8;
    const int gxk1 = ((4 + quad) ^ rsw) * 8;

    floatx4 acc[8][4];
#pragma unroll
    for (int i = 0; i < 8; i++)
#pragma unroll
        for (int j = 0; j < 4; j++) acc[i][j] = (floatx4){0.f, 0.f, 0.f, 0.f};

    half8 af[4][2], bf0s[2][2], bf1s[2][2];

    auto stageA = [&](int buf, int h, int T) {
        const int tz = T >> ntSh, tk = T & (ntiles - 1);
        const _Float16* s = (tz ? gaA1 : gaA0) + (long long)(h * 128) * lda
                          + (long long)(tk >> aTSh) * aSeg + ((tk & aTMk) << 6);
        _Float16* d = AsB + buf * 16384 + h * 8192 + wave * 512;
        async_copy16(s, d);
        async_copy16(s + (long long)64 * lda, d + 4096);
    };
    auto stageB = [&](int buf, int h, int T) {
        const int tz = T >> ntSh, tk = T & (ntiles - 1);
        const _Float16* s = (tz ? gbB1 : gbB0) + (long long)(h * 128) * ldb
                          + (long long)(tk >> bTSh) * bSeg + ((tk & bTMk) << 6);
        _Float16* d = BsB + buf * 16384 + h * 8192 + wave * 512;
        async_copy16(s, d);
        async_copy16(s + (long long)64 * ldb, d + 4096);
    };

    // epilogue: VGPR->global only, no LDS, no barriers.
    auto epi = [&](int zz) {
        const int z1 = zz >> zShift, z2 = zz & zMask;
        const float* bz = bias + (long long)z1 * biasS1 + (long long)z2 * biasS2;
        float*    Cf = (float*)Cv    + (long long)z1 * cS1 + (long long)z2 * cS2;
        _Float16* Ch = (_Float16*)Cv + (long long)z1 * cS1 + (long long)z2 * cS2;
#pragma unroll
        for (int f = 0; f < 8; f++) {
            const int row = m0 + (f >> 2) * 128 + wr * 64 + (f & 3) * 16 + r16;
#pragma unroll
            for (int j = 0; j < 4; j++) {
                const int col = n0 + (j >> 1) * 128 + wc * 32 + (j & 1) * 16 + quad * 4;
                float v0 = acc[f][j][0], v1 = acc[f][j][1],
                      v2 = acc[f][j][2], v3 = acc[f][j][3];
                if (biasMode == 1) {
                    v0 += bz[col]; v1 += bz[col + 1];
                    v2 += bz[col + 2]; v3 += bz[col + 3];
                } else if (biasMode == 2) {
                    const float bv = bz[row];
                    v0 += bv; v1 += bv; v2 += bv; v3 += bv;
                }
                const size_t idx = (size_t)row * ldc + col;
                if (OUT_F16) {
                    half4 hv = {(_Float16)v0, (_Float16)v1, (_Float16)v2, (_Float16)v3};
                    *(half4*)&Ch[idx] = hv;
                } else {
                    float4 fv = {v0, v1, v2, v3};
                    *(float4*)&Cf[idx] = fv;
                }
            }
        }
    };

#define LOAD_AF(RH, BUF) do { \
    const _Float16* ab_ = AsB + (BUF) * 16384 + ((RH) * 128 + arow) * 64; \
    _Pragma("unroll") \
    for (int i5 = 0; i5 < 4; i5++) { \
        af[i5][0] = *(const half8*)(ab_ + i5 * 1024 + gxk0); \
        af[i5][1] = *(const half8*)(ab_ + i5 * 1024 + gxk1); \
    } \
} while (0)

#define LOAD_BF(DST, CH, BUF) do { \
    const _Float16* bb_ = BsB + (BUF) * 16384 + ((CH) * 128 + brow) * 64; \
    _Pragma("unroll") \
    for (int j5 = 0; j5 < 2; j5++) { \
        DST[j5][0] = *(const half8*)(bb_ + j5 * 1024 + gxk0); \
        DST[j5][1] = *(const half8*)(bb_ + j5 * 1024 + gxk1); \
    } \
} while (0)

#define MFMA16(RH, CH, BFS) do { \
    _Pragma("unroll") \
    for (int i6 = 0; i6 < 4; i6++) { \
        _Pragma("unroll") \
        for (int j6 = 0; j6 < 2; j6++) { \
            floatx4 c_ = acc[(RH) * 4 + i6][(CH) * 2 + j6]; \
            c_ = __builtin_amdgcn_mfma_f32_16x16x32_f16(BFS[j6][0], af[i6][0], c_, 0, 0, 0); \
            c_ = __builtin_amdgcn_mfma_f32_16x16x32_f16(BFS[j6][1], af[i6][1], c_, 0, 0, 0); \
            acc[(RH) * 4 + i6][(CH) * 2 + j6] = c_; \
        } \
    } \
} while (0)

    // prologue: tile0 -> buf0 (all 4 halves), tile1 -> buf1 (A0, B1)
    stageA(0, 0, 0);
    stageB(0, 1, 0);
    stageA(0, 1, 0);
    stageB(0, 0, 0);
    stageA(1, 0, 1);
    stageB(1, 1, 1);
    WAIT_VM4();
    BAR();

    int zi = 0;
    for (int it = 0; it < TTh; ++it) {
        const int T = it * 2;
        const bool full = (it < TTh - 1);

        // ---- p0: (0,0) of tile T  [buf0]
        LOAD_AF(0, 0); LOAD_BF(bf0s, 0, 0);
        stageA(1, 1, T + 1);
        BAR();
        __builtin_amdgcn_s_setprio(1); MFMA16(0, 0, bf0s); __builtin_amdgcn_s_setprio(0);
        BAR();
        // ---- p1: (0,1)
        LOAD_BF(bf1s, 1, 0);
        stageB(1, 0, T + 1);
        BAR();
        __builtin_amdgcn_s_setprio(1); MFMA16(0, 1, bf1s); __builtin_amdgcn_s_setprio(0);
        BAR();
        // ---- p2: (1,1)
        LOAD_AF(1, 0);
        if (full) stageA(0, 0, T + 2);
        BAR();
        __builtin_amdgcn_s_setprio(1); MFMA16(1, 1, bf1s); __builtin_amdgcn_s_setprio(0);
        BAR();
        // ---- p3: (1,0)  regs-only  + W0
        if (full) stageB(0, 1, T + 2);
        BAR();
        __builtin_amdgcn_s_setprio(1); MFMA16(1, 0, bf0s); __builtin_amdgcn_s_setprio(0);
        if (full) WAIT_VM4(); else WAIT_VM0();
        BAR();
        // ---- p4: (0,0) of tile T+1  [buf1]
        LOAD_AF(0, 1); LOAD_BF(bf0s, 0, 1);
        if (full) stageA(0, 1, T + 2);
        BAR();
        __builtin_amdgcn_s_setprio(1); MFMA16(0, 0, bf0s); __builtin_amdgcn_s_setprio(0);
        BAR();
        // ---- p5: (0,1)
        LOAD_BF(bf1s, 1, 1);
        if (full) stageB(0, 0, T + 2);
        BAR();
        __builtin_amdgcn_s_setprio(1); MFMA16(0, 1, bf1s); __builtin_amdgcn_s_setprio(0);
        BAR();
        // ---- p6: (1,1)
        LOAD_AF(1, 1);
        if (full) stageA(1, 0, T + 3);
        BAR();
        __builtin_amdgcn_s_setprio(1); MFMA16(1, 1, bf1s); __builtin_amdgcn_s_setprio(0);
        BAR();
        // ---- p7: (1,0)  regs-only  + W1
        if (full) stageB(1, 1, T + 3);
        BAR();
        __builtin_amdgcn_s_setprio(1); MFMA16(1, 0, bf0s); __builtin_amdgcn_s_setprio(0);
        if (full) WAIT_VM4();
        BAR();

        // z-boundary: write out this batch's tile, reset accumulator.
        if (((it + 1) & ntHMsk) == 0) {
            epi(zi ? zz1 : zz0);
            ++zi;
#pragma unroll
            for (int i7 = 0; i7 < 8; i7++)
#pragma unroll
                for (int j7 = 0; j7 < 4; j7++)
                    acc[i7][j7] = (floatx4){0.f, 0.f, 0.f, 0.f};
        }
    }

#undef LOAD_AF
#undef LOAD_BF
#undef MFMA16
}

// ---------------------------------------------------------------------------
// in-place fp16 softmax over rows of 512, scaled by 0.25 (head mean).
// ---------------------------------------------------------------------------
__global__ __launch_bounds__(256)
void softmax_f16(_Float16* __restrict__ S)
{
    const int row  = blockIdx.x * 4 + (threadIdx.x >> 6);
    const int lane = threadIdx.x & 63;
    _Float16* s = S + (size_t)row * 512 + lane * 8;
    half8 h = *(const half8*)s;
    float v[8];
    float mx = -1e30f;
#pragma unroll
    for (int j = 0; j < 8; j++) { v[j] = (float)h[j]; mx = fmaxf(mx, v[j]); }
#pragma unroll
    for (int off = 32; off; off >>= 1) mx = fmaxf(mx, __shfl_xor(mx, off));
    float sum = 0.f;
#pragma unroll
    for (int j = 0; j < 8; j++) { v[j] = __expf(v[j] - mx); sum += v[j]; }
#pragma unroll
    for (int off = 32; off; off >>= 1) sum += __shfl_xor(sum, off);
    const float inv = 0.25f / sum;
#pragma unroll
    for (int j = 0; j < 8; j++) h[j] = (_Float16)(v[j] * inv);
    *(half8*)s = h;
}

// 4 fp32->fp16 conversions fused into one launch (ranges in float4 units).
__global__ __launch_bounds__(256)
void cvt_multi(const float* __restrict__ s0, _Float16* __restrict__ d0, int c0,
               const float* __restrict__ s1, _Float16* __restrict__ d1, int c1,
               const float* __restrict__ s2, _Float16* __restrict__ d2, int c2,
               const float* __restrict__ s3, _Float16* __restrict__ d3, int c3)
{
    int i = blockIdx.x * 256 + threadIdx.x;
    const float* s; _Float16* d;
    if (i < c0) { s = s0; d = d0; }
    else { i -= c0;
        if (i < c1) { s = s1; d = d1; }
        else { i -= c1;
            if (i < c2) { s = s2; d = d2; }
            else { i -= c2; s = s3; d = d3; } } }
    const float4 f = ((const float4*)s)[i];
    half4 hv = {(_Float16)f.x, (_Float16)f.y, (_Float16)f.z, (_Float16)f.w};
    *(half4*)(d + (size_t)i * 4) = hv;
}

// in [G][R][C] -> out [G][C][R], fp32 -> fp16
__global__ __launch_bounds__(256)
void transpose_cvt(const float* __restrict__ in, _Float16* __restrict__ out,
                   int R, int C)
{
    __shared__ float tile[32][33];
    const int g  = blockIdx.z;
    const int c0 = blockIdx.x * 32;
    const int r0 = blockIdx.y * 32;
    const float* inp  = in  + (size_t)g * R * C;
    _Float16*    outp = out + (size_t)g * R * C;
#pragma unroll
    for (int i = threadIdx.y; i < 32; i += 8)
        tile[i][threadIdx.x] = inp[(size_t)(r0 + i) * C + c0 + threadIdx.x];
    __syncthreads();
#pragma unroll
    for (int i = threadIdx.y; i < 32; i += 8)
        outp[(size_t)(c0 + i) * R + r0 + threadIdx.x] = (_Float16)tile[threadIdx.x][i];
}

// fused small preprocessing reductions: wk_bq(w0), wk_bq(w1), fold_bias, sum_b0
// block ranges: [0,4) w0; [4,12) w1; [12,16) be1p; [16,18) sb0.
__global__ __launch_bounds__(256)
void small_ops(const float* __restrict__ kq_w0, const float* __restrict__ kq_b0,
               const float* __restrict__ kq_w1, const float* __restrict__ kq_b1,
               const _Float16* __restrict__ projwT, const float* __restrict__ e_b1,
               const float* __restrict__ e_b0,
               float* __restrict__ w0, float* __restrict__ w1,
               float* __restrict__ be1p, float* __restrict__ sb0)
{
    const int blk = blockIdx.x;
    if (blk < 4) {                       // w0[h][d], d < DIN
        const int t = blk * 256 + threadIdx.x;
        const int h = t >> 8, d = t & 255;
        const float* wk = kq_w0 + ((size_t)(h << 8) + d) * (2 * DH_);
        const float* bq = kq_b0 + (size_t)h * 2 * DH_ + DH_;
        float s = 0.f;
        for (int e = 0; e < DH_; e++) s += wk[e] * bq[e];
        w0[t] = s;
    } else if (blk < 12) {               // w1[h][d], d < DH
        const int t = (blk - 4) * 256 + threadIdx.x;
        const int h = t >> 9, d = t & 511;
        const float* wk = kq_w1 + ((size_t)(h << 9) + d) * (2 * DH_);
        const float* bq = kq_b1 + (size_t)h * 2 * DH_ + DH_;
        float s = 0.f;
        for (int e = 0; e < DH_; e++) s += wk[e] * bq[e];
        w1[t] = s;
    } else if (blk < 16) {               // be1p[h][o]
        const int t = (blk - 12) * 256 + threadIdx.x;
        const int h = t >> 8, o = t & 255;
        const _Float16* pw = projwT + (size_t)o * DH_;
        const float*    eb = e_b1 + (size_t)h * DH_;
        float s = 0.f;
        for (int d = 0; d < DH_; d++) s += (float)pw[d] * eb[d];
        be1p[t] = s;
    } else {                             // sb0[e]
        const int e = (blk - 16) * 256 + threadIdx.x;
        sb0[e] = 0.25f * (e_b0[e] + e_b0[DH_ + e] + e_b0[2 * DH_ + e] + e_b0[3 * DH_ + e]);
    }
}

// V[b][h][n] = x[b*N+n, :] . w[h, :] — one wave/row, 4 heads, vectorized half4
__global__ __launch_bounds__(256)
void compute_v(const _Float16* __restrict__ x, const float* __restrict__ w,
               float* __restrict__ V, int Kin)
{
    const int row  = blockIdx.x * 4 + (threadIdx.x >> 6);
    const int lane = threadIdx.x & 63;
    const int b = row >> 9, n = row & 511;
    const _Float16* xr = x + (size_t)row * Kin;
    float s0 = 0.f, s1 = 0.f, s2 = 0.f, s3 = 0.f;
    const int iters = Kin >> 8;          // lanes cover 256 elems/iter (4 each)
    for (int j = 0; j < iters; j++) {
        const int e = j * 256 + lane * 4;
        const half4  xv = *(const half4*)(xr + e);
        const float4 a0 = *(const float4*)(w + e);
        const float4 a1 = *(const float4*)(w + Kin + e);
        const float4 a2 = *(const float4*)(w + 2 * Kin + e);
        const float4 a3 = *(const float4*)(w + 3 * Kin + e);
        const float x0 = (float)xv[0], x1 = (float)xv[1],
                    x2 = (float)xv[2], x3 = (float)xv[3];
        s0 += x0 * a0.x + x1 * a0.y + x2 * a0.z + x3 * a0.w;
        s1 += x0 * a1.x + x1 * a1.y + x2 * a1.z + x3 * a1.w;
        s2 += x0 * a2.x + x1 * a2.y + x2 * a2.z + x3 * a2.w;
        s3 += x0 * a3.x + x1 * a3.y + x2 * a3.z + x3 * a3.w;
    }
#pragma unroll
    for (int off = 32; off; off >>= 1) {
        s0 += __shfl_xor(s0, off); s1 += __shfl_xor(s1, off);
        s2 += __shfl_xor(s2, off); s3 += __shfl_xor(s3, off);
    }
    if (lane == 0) {
        float* vb = V + ((size_t)b * H_) * N_ + n;
        vb[0] = s0; vb[N_] = s1; vb[2 * N_] = s2; vb[3 * N_] = s3;
    }
}

// ---------------------------------------------------------------------------
extern "C" void kernel_launch(void* const* d_in, const int* in_sizes, int n_in,
                              void* d_out, int out_size, void* d_ws, size_t ws_size,
                              hipStream_t stream)
{
    (void)in_sizes; (void)n_in; (void)out_size;

    static bool attr_set = false;
    if (!attr_set) {
        hipFuncSetAttribute((const void*)gemm256<true>,
                            hipFuncAttributeMaxDynamicSharedMemorySize, 131072);
        hipFuncSetAttribute((const void*)gemm256<false>,
                            hipFuncAttributeMaxDynamicSharedMemorySize, 131072);
        attr_set = true;
    }

    const float* x      = (const float*)d_in[0];
    const float* e_w0   = (const float*)d_in[1];
    const float* e_b0   = (const float*)d_in[2];
    const float* kq_w0  = (const float*)d_in[3];
    const float* kq_b0  = (const float*)d_in[4];
    const float* e_w1   = (const float*)d_in[5];
    const float* e_b1   = (const float*)d_in[6];
    const float* kq_w1  = (const float*)d_in[7];
    const float* kq_b1  = (const float*)d_in[8];
    const float* proj_w = (const float*)d_in[9];
    const float* proj_b = (const float*)d_in[10];
    float* out = (float*)d_out;

    char* ws = (char*)d_ws;
    size_t off = 0;
    auto alloc = [&](size_t bytes) -> char* {
        char* p = ws + off;
        off += (bytes + 255) & ~(size_t)255;
        return p;
    };

    // --- persistent (~73 MB incl. xT) --------------------------------------
    _Float16* x16    = (_Float16*)alloc((size_t)BN_ * DIN_ * 2);
    _Float16* h1_16  = (_Float16*)alloc((size_t)BN_ * DH_ * 2);
    _Float16* ewT0   = (_Float16*)alloc((size_t)H_ * DH_ * DIN_ * 2);
    _Float16* projwT = (_Float16*)alloc((size_t)DOUT_ * DH_ * 2);
    _Float16* Mt0    = (_Float16*)alloc((size_t)H_ * DIN_ * DIN_ * 2);
    _Float16* Mt1    = (_Float16*)alloc((size_t)H_ * DH_ * DH_ * 2);
    _Float16* We1pT  = (_Float16*)alloc((size_t)H_ * DOUT_ * DH_ * 2);
    float*    be1p   = (float*)alloc((size_t)H_ * DOUT_ * 4);
    float*    w0     = (float*)alloc((size_t)H_ * DIN_ * 4);
    float*    w1     = (float*)alloc((size_t)H_ * DH_ * 4);
    float*    sb0    = (float*)alloc((size_t)DH_ * 4);
    float*    Vb     = (float*)alloc((size_t)B_ * H_ * N_ * 4);
    _Float16* xT     = (_Float16*)alloc((size_t)BN_ * DIN_ * 2);   // [b][d][n]

    const size_t persistAll = off;
    const long long SB = (long long)N_ * N_;
    const size_t SC_FULL  = (size_t)B_ * H_ * N_ * N_ * 2;       // 134.2 MB
    const size_t SC_CHUNK = SC_FULL / 2;                          // 67.1 MB
    const size_t A2_SZ    = (size_t)BN_ * H_ * DIN_ * 2;          // 67.1 MB
    const size_t SLACK    = 1u << 20;

    // tier A: full-batch blk0 + deferred full-batch blk1 PV  (~276 MB)
    // tier B: CH=32 chunks (ws known to be in [266,276) on this harness)
    const bool tierA = ws_size >= persistAll + SC_FULL + A2_SZ + SLACK;

    _Float16* Sc = (_Float16*)alloc(tierA ? SC_FULL : SC_CHUNK);
    _Float16* A2 = (_Float16*)alloc(A2_SZ);

    // transient cvt buffers live inside A2 (dead before A2's first GEMM use)
    _Float16* kq0_16 = A2;                                        // 2.1 MB
    _Float16* kq1_16 = kq0_16 + (size_t)H_ * DIN_ * 2 * DH_;      // 4.2 MB
    _Float16* ew1_16 = kq1_16 + (size_t)H_ * DH_ * 2 * DH_;       // 2.1 MB

    // routing: 256^2 kernel when its grid (after zLoop) fills the chip;
    // otherwise 128^2 kernel (zLoop==1, zOrd==0 only).
    auto gemm = [&](bool outF16,
                    const _Float16* A, long long aS1, long long aS2, int lda, long long aSeg,
                    const _Float16* Bp, long long bS1, long long bS2, int ldb, long long bSeg,
                    void* C, long long cS1, long long cS2, int ldc,
                    int M, int Nn, int K, int batches, int zShift,
                    const float* bias, int biasMode, long long biasS1, long long biasS2,
                    int aSh, int bSh, int zLoop, int zOrd) {
        const bool can256 = (M % 256 == 0) && (Nn % 256 == 0) && (K % 128 == 0);
        const bool can128 = (M % 128 == 0) && (Nn % 128 == 0) && (K % 32 == 0)
                          && (aSh == 9) && (bSh == 9) && (zLoop == 1) && (zOrd == 0);
        const long long wg256 = can256
            ? (long long)(M >> 8) * (Nn >> 8) * (batches / zLoop) : 0;
        bool use256;
        if (!can128)            use256 = true;
        else if (!can256)       use256 = false;
        else                    use256 = (wg256 >= 192) || (wg256 >= 32 && wg256 * 4 < 128);
        if (use256) {
            dim3 grid(Nn / 256, M / 256, batches / zLoop), block(512);
            if (outF16)
                gemm256<true><<<grid, block, 131072, stream>>>(A, aS1, aS2, lda, aSeg, aSh,
                    Bp, bS1, bS2, ldb, bSeg, bSh, C, cS1, cS2, ldc, K, bias, biasMode, biasS1, biasS2, zShift, zLoop, zOrd);
            else
                gemm256<false><<<grid, block, 131072, stream>>>(A, aS1, aS2, lda, aSeg, aSh,
                    Bp, bS1, bS2, ldb, bSeg, bSh, C, cS1, cS2, ldc, K, bias, biasMode, biasS1, biasS2, zShift, zLoop, zOrd);
        } else {
            dim3 grid(Nn / 128, M / 128, batches), block(256);
            if (outF16)
                gemm_f16<true><<<grid, block, 0, stream>>>(A, aS1, aS2, lda, aSeg,
                    Bp, bS1, bS2, ldb, bSeg, C, cS1, cS2, ldc, K, bias, biasMode, biasS1, biasS2, zShift);
            else
                gemm_f16<false><<<grid, block, 0, stream>>>(A, aS1, aS2, lda, aSeg,
                    Bp, bS1, bS2, ldb, bSeg, C, cS1, cS2, ldc, K, bias, biasMode, biasS1, biasS2, zShift);
        }
    };

    // --- preprocessing -----------------------------------------------------
    {
        const int c0 = BN_ * DIN_ / 4;              // x -> x16
        const int c1 = H_ * DIN_ * 2 * DH_ / 4;     // kq_w0
        const int c2 = H_ * DH_ * 2 * DH_ / 4;      // kq_w1
        const int c3 = H_ * DH_ * DH_ / 4;          // e_w1
        cvt_multi<<<(c0 + c1 + c2 + c3) / 256, 256, 0, stream>>>(
            x, x16, c0, kq_w0, kq0_16, c1, kq_w1, kq1_16, c2, e_w1, ew1_16, c3);
    }
    transpose_cvt<<<dim3(DH_ / 32, DIN_ / 32, H_), dim3(32, 8), 0, stream>>>(e_w0, ewT0, DIN_, DH_);
    transpose_cvt<<<dim3(DOUT_ / 32, DH_ / 32, 1), dim3(32, 8), 0, stream>>>(proj_w, projwT, DH_, DOUT_);
    transpose_cvt<<<dim3(DIN_ / 32, N_ / 32, B_), dim3(32, 8), 0, stream>>>(x, xT, N_, DIN_);
    small_ops<<<18, 256, 0, stream>>>(kq_w0, kq_b0, kq_w1, kq_b1,
                                      projwT, e_b1, e_b0, w0, w1, be1p, sb0);

    // Mt_h = Wk_h * Wq_h^T  (so T = x * Mt^T = x * (Wq Wk^T))
    gemm(true, kq0_16, 0, (long long)DIN_ * 2 * DH_, 2 * DH_, 512,
         kq0_16 + DH_, 0, (long long)DIN_ * 2 * DH_, 2 * DH_, 512,
         Mt0, 0, (long long)DIN_ * DIN_, DIN_,
         DIN_, DIN_, DH_, H_, 2, nullptr, 0, 0, 0, 9, 9, 1, 0);
    gemm(true, kq1_16, 0, (long long)DH_ * 2 * DH_, 2 * DH_, 512,
         kq1_16 + DH_, 0, (long long)DH_ * 2 * DH_, 2 * DH_, 512,
         Mt1, 0, (long long)DH_ * DH_, DH_,
         DH_, DH_, DH_, H_, 2, nullptr, 0, 0, 0, 9, 9, 1, 0);
    // We1pT[h][o][d] = sum_d' projwT[o][d'] * e_w1[h][d][d']
    gemm(true, projwT, 0, 0, DH_, 512,
         ew1_16, 0, (long long)DH_ * DH_, DH_, 512,
         We1pT, 0, (long long)DOUT_ * DH_, DH_,
         DOUT_, DH_, DH_, H_, 2, nullptr, 0, 0, 0, 9, 9, 1, 0);

    // --- block 0: G-path (h1 = sum_h (P_h x) W_h + 0.25 sum_h b_h) ---------
    {
        const int CH0  = tierA ? B_ : 32;
        const int NCH0 = B_ / CH0;
        const int sOrd  = tierA ? 1 : 2;   // zOrd=2 requires batches==128
        const int sLoop = tierA ? 1 : 2;
        const size_t GCH = (size_t)CH0 * N_ * H_ * DIN_;   // elems per A2 slot
        compute_v<<<BN_ / 4, 256, 0, stream>>>(x16, w0, Vb, DIN_);

        // T0 full-batch (batched over b, zLoop=2): one 256-wg deep dispatch.
        // Writes all of A2; chunk c's slot region holds T0 rows of chunk c.
        gemm(true, x16, (long long)N_ * DIN_, 0, DIN_, 512,
             Mt0, 0, 0, DIN_, 512,
             A2, (long long)N_ * H_ * DIN_, 0, H_ * DIN_,
             N_, H_ * DIN_, DIN_, B_, 0, nullptr, 0, 0, 0, 9, 9, 2, 0);

        for (int c = 0; c < NCH0; c++) {
            const _Float16* xc  = x16 + (size_t)c * CH0 * N_ * DIN_;
            const _Float16* xTc = xT  + (size_t)c * CH0 * DIN_ * N_;
            _Float16* slot = A2 + (size_t)c * GCH;
            // S = T x^T + V   (zOrd=2: b-paired z-continuation + h L2-group)
            gemm(true, slot, (long long)N_ * H_ * DIN_, DIN_, H_ * DIN_, 512,
                 xc, (long long)N_ * DIN_, 0, DIN_, 512,
                 Sc, (long long)H_ * SB, SB, N_,
                 N_, N_, DIN_, CH0 * H_, 2,
                 Vb + (size_t)c * CH0 * H_ * N_, 1, (long long)H_ * N_, N_, 9, 9, sLoop, sOrd);
            softmax_f16<<<CH0 * H_ * N_ / 4, 256, 0, stream>>>(Sc);
            // G[b][h][q][d] = P[b,h] . x_b  -> slot c (T0 chunk c dead)
            gemm(true, Sc, (long long)H_ * SB, SB, N_, 512,
                 xTc, (long long)DIN_ * N_, 0, N_, 512,
                 slot, (long long)H_ * N_ * DIN_, (long long)N_ * DIN_, DIN_,
                 N_, DIN_, N_, CH0 * H_, 2, nullptr, 0, 0, 0, 9, 9, 1, 1);
        }
        // deferred h1 over ALL batches: grid (2,2,64) = 256 wgs
        gemm(true, A2, (long long)H_ * N_ * DIN_, 0, DIN_, (long long)N_ * DIN_,
             ewT0, 0, 0, DIN_, (long long)DH_ * DIN_,
             h1_16, (long long)N_ * DH_, 0, DH_,
             N_, DH_, H_ * DIN_, B_, 0, sb0, 1, 0, 0, 8, 8, 1, 0);
    }

    // --- block 1 -----------------------------------------------------------
    {
        compute_v<<<BN_ / 4, 256, 0, stream>>>(h1_16, w1, Vb, DH_);
        for (int c = 0; c < 2; c++) {
            const _Float16* hc = h1_16 + (size_t)c * 32 * N_ * DH_;
            _Float16* Scp = tierA ? Sc + (size_t)c * 32 * H_ * SB : Sc;
            // T1 -> A2, reshaped (M=256, batches=64, zLoop=2): 256 wgs, 1 round
            gemm(true, hc, (long long)256 * DH_, 0, DH_, 512,
                 Mt1, 0, 0, DH_, 512,
                 A2, (long long)256 * H_ * DH_, 0, H_ * DH_,
                 256, H_ * DH_, DH_, 64, 0, nullptr, 0, 0, 0, 9, 9, 2, 0);
            // S1  (zOrd=2: b-paired continuation + h L2-group)
            gemm(true, A2, (long long)N_ * H_ * DH_, DH_, H_ * DH_, 512,
                 hc, (long long)N_ * DH_, 0, DH_, 512,
                 Scp, (long long)H_ * SB, SB, N_,
                 N_, N_, DH_, 32 * H_, 2,
                 Vb + (size_t)c * 32 * H_ * N_, 1, (long long)H_ * N_, N_, 9, 9, 2, 2);
            softmax_f16<<<32 * H_ * N_ / 4, 256, 0, stream>>>(Scp);
            if (!tierA) {
                // embW chunk -> A2 (T1 dead)
                gemm(true, We1pT, 0, 0, DH_, 512,
                     hc, (long long)N_ * DH_, 0, DH_, 512,
                     A2, (long long)H_ * DOUT_ * N_, 0, N_,
                     H_ * DOUT_, N_, DH_, 32, 0, be1p, 2, 0, 0, 9, 9, 1, 0);
                // PV chunk (fp32 out) — routed to gemm_f16: 256 wgs
                gemm(false, Scp, (long long)H_ * SB, 0, N_, SB,
                     A2, (long long)H_ * DOUT_ * N_, 0, N_, (long long)DOUT_ * N_,
                     out + (size_t)c * 32 * N_ * DOUT_, (long long)N_ * DOUT_, 0, DOUT_,
                     N_, DOUT_, H_ * N_, 32, 0, proj_b, 1, 0, 0, 9, 9, 1, 0);
            }
        }
        if (tierA) {
            // embW full -> A2 (T1 dead after last S1)
            gemm(true, We1pT, 0, 0, DH_, 512,
                 h1_16, (long long)N_ * DH_, 0, DH_, 512,
                 A2, (long long)H_ * DOUT_ * N_, 0, N_,
                 H_ * DOUT_, N_, DH_, B_, 0, be1p, 2, 0, 0, 9, 9, 1, 0);
            // deferred full-batch PV — routed to gemm_f16: 512 wgs
            gemm(false, Sc, (long long)H_ * SB, 0, N_, SB,
                 A2, (long long)H_ * DOUT_ * N_, 0, N_, (long long)DOUT_ * N_,
                 out, (long long)N_ * DOUT_, 0, DOUT_,
                 N_, DOUT_, H_ * N_, B_, 0, proj_b, 1, 0, 0, 9, 9, 1, 0);
        }
    }
}

// Round 9
// 841.485 us; speedup vs baseline: 1.2623x; 1.0636x over previous
//
#include <hip/hip_runtime.h>

typedef _Float16 half8 __attribute__((ext_vector_type(8)));
typedef _Float16 half4 __attribute__((ext_vector_type(4)));
typedef float floatx4 __attribute__((ext_vector_type(4)));

#define B_    64
#define N_    512
#define DIN_  256
#define DH_   512
#define DOUT_ 256
#define H_    4
#define BN_   (B_ * N_)   // 32768

// raw waitcnt immediates (gfx9: vmcnt[3:0]|[15:14], exp[6:4], lgkm[11:8])
#define WAIT_VM4_LGKM0() __builtin_amdgcn_s_waitcnt(0x0074)  // vm<=4, lgkm<=0
#define WAIT_VM0_LGKM0() __builtin_amdgcn_s_waitcnt(0x0070)  // vm<=0, lgkm<=0
#define WAIT_VM4()       __builtin_amdgcn_s_waitcnt(0x0F74)  // vm<=4 only
#define WAIT_VM0()       __builtin_amdgcn_s_waitcnt(0x0F70)  // vm<=0 only
#define MEMBAR()         __asm__ __volatile__("" ::: "memory")
#define BAR()            do { MEMBAR(); __builtin_amdgcn_s_barrier(); MEMBAR(); } while (0)

__device__ static inline void async_copy16(const _Float16* g, _Float16* l) {
    __builtin_amdgcn_global_load_lds(
        (const __attribute__((address_space(1))) void*)g,
        (__attribute__((address_space(3))) void*)l, 16, 0, 0);
}

// ---------------------------------------------------------------------------
// 128x128-tile GEMM (BK=32, 4 waves, triple-buffered): small preprocessing
// shapes and main shapes whose 256^2 grid would be starved. 512-elem K-segs.
// splitK: when 1, blockIdx.z encodes (batch<<1)|half; each wg computes a
// K/2 window and writes raw fp32 partials at Cv + half*cSplit (no bias) —
// doubles the grid so 2 blocks/CU co-reside and hide the barrier drain.
// ---------------------------------------------------------------------------
template <bool OUT_F16>
__global__ __launch_bounds__(256)
void gemm_f16(const _Float16* __restrict__ A, long long aS1, long long aS2, int lda, long long aSeg,
              const _Float16* __restrict__ B, long long bS1, long long bS2, int ldb, long long bSeg,
              void* __restrict__ Cv, long long cS1, long long cS2, int ldc,
              int K, const float* __restrict__ bias, int biasMode,
              long long biasS1, long long biasS2, int zShift,
              int splitK, long long cSplit)
{
    __shared__ __align__(16) _Float16 As[3][128 * 32];
    __shared__ __align__(16) _Float16 Bs[3][128 * 32];

    const int tid  = threadIdx.x;
    const int wave = tid >> 6;
    const int lane = tid & 63;
    const int quad = lane >> 4;
    const int r16  = lane & 15;

    int zz = blockIdx.z;
    int half = 0;
    if (splitK) { half = zz & 1; zz >>= 1; }
    const int z1 = zz >> zShift;
    const int z2 = zz & ((1 << zShift) - 1);
    const int Keff  = splitK ? (K >> 1) : K;
    const int kBase = splitK ? half * (K >> 1) : 0;

    const int gx = gridDim.x, gy = gridDim.y;
    const int T = gx * gy;
    int lin = blockIdx.y * gx + blockIdx.x;
    int id2 = (T & 7) ? lin : ((lin & 7) * (T >> 3) + (lin >> 3));
    const int m0 = (id2 / gx) * 128;
    const int n0 = (id2 % gx) * 128;

    const int srow = lane >> 2;
    const int scol = (((lane & 3) ^ ((lane >> 3) & 3))) * 8;

    const _Float16* gaRow = A + z1 * aS1 + z2 * aS2
                              + (long long)(m0 + wave * 32 + srow) * lda + scol;
    const _Float16* gbRow = B + z1 * bS1 + z2 * bS2
                              + (long long)(n0 + wave * 32 + srow) * ldb + scol;

    const int wm = (wave >> 1) * 64;
    const int wn = (wave & 1) * 64;
    const int gl = (quad ^ ((r16 >> 1) & 3)) * 8;

    floatx4 acc[4][4];
#pragma unroll
    for (int i = 0; i < 4; i++)
#pragma unroll
        for (int j = 0; j < 4; j++) acc[i][j] = (floatx4){0.f, 0.f, 0.f, 0.f};

    auto stage = [&](int p, int k0r) {
        const int k0 = k0r + kBase;
        const _Float16* a = gaRow + (long long)(k0 >> 9) * aSeg + (k0 & 511);
        const _Float16* b = gbRow + (long long)(k0 >> 9) * bSeg + (k0 & 511);
        _Float16* la = &As[p][wave * 1024];
        _Float16* lb = &Bs[p][wave * 1024];
        async_copy16(a,                    la);
        async_copy16(a + (size_t)16 * lda, la + 512);
        async_copy16(b,                    lb);
        async_copy16(b + (size_t)16 * ldb, lb + 512);
    };

    auto compute = [&](int p) {
        half8 af[4], bf[4];
#pragma unroll
        for (int i = 0; i < 4; i++)
            af[i] = *(const half8*)&As[p][(wm + i * 16 + r16) * 32 + gl];
#pragma unroll
        for (int j = 0; j < 4; j++)
            bf[j] = *(const half8*)&Bs[p][(wn + j * 16 + r16) * 32 + gl];
#pragma unroll
        for (int i = 0; i < 4; i++)
#pragma unroll
            for (int j = 0; j < 4; j++)
                acc[i][j] = __builtin_amdgcn_mfma_f32_16x16x32_f16(
                    bf[j], af[i], acc[i][j], 0, 0, 0);
    };

    const int niter = Keff >> 5;
    stage(0, 0);
    stage(1, 32);
    int pNext = 2;
    int pCur  = 0;
    for (int it = 0; it < niter - 1; ++it) {
        MEMBAR(); WAIT_VM4_LGKM0();
        __builtin_amdgcn_s_barrier();
        MEMBAR();
        if (it + 2 < niter) stage(pNext, (it + 2) << 5);
        compute(pCur);
        MEMBAR();
        pNext = (pNext == 2) ? 0 : pNext + 1;
        pCur  = (pCur  == 2) ? 0 : pCur  + 1;
    }
    MEMBAR(); WAIT_VM0_LGKM0();
    __builtin_amdgcn_s_barrier(); MEMBAR();
    compute(pCur);

    const float* bz = bias + z1 * biasS1 + z2 * biasS2;
    float*    Cf = (float*)Cv    + z1 * cS1 + z2 * cS2 + (long long)half * cSplit;
    _Float16* Ch = (_Float16*)Cv + z1 * cS1 + z2 * cS2 + (long long)half * cSplit;
#pragma unroll
    for (int i = 0; i < 4; i++) {
        const int row = m0 + wm + i * 16 + r16;
#pragma unroll
        for (int j = 0; j < 4; j++) {
            const int col = n0 + wn + j * 16 + quad * 4;
            float v0 = acc[i][j][0], v1 = acc[i][j][1],
                  v2 = acc[i][j][2], v3 = acc[i][j][3];
            if (biasMode == 1) {
                v0 += bz[col]; v1 += bz[col + 1];
                v2 += bz[col + 2]; v3 += bz[col + 3];
            } else if (biasMode == 2) {
                const float bv = bz[row];
                v0 += bv; v1 += bv; v2 += bv; v3 += bv;
            }
            const size_t idx = (size_t)row * ldc + col;
            if (OUT_F16) {
                half4 hv = {(_Float16)v0, (_Float16)v1, (_Float16)v2, (_Float16)v3};
                *(half4*)&Ch[idx] = hv;
            } else {
                float4 fv = {v0, v1, v2, v3};
                *(float4*)&Cf[idx] = fv;
            }
        }
    }
}

// out = p[0] + p[1] + bias[col]  (fp32, float4 lanes; DOUT_-periodic bias)
__global__ __launch_bounds__(256)
void combine_pv(const float* __restrict__ p, long long partStride,
                const float* __restrict__ bias, float* __restrict__ out)
{
    const size_t i = ((size_t)blockIdx.x * 256 + threadIdx.x) * 4;
    const float4 a = *(const float4*)(p + i);
    const float4 b = *(const float4*)(p + partStride + i);
    const float4 bb = *(const float4*)(bias + (i & (DOUT_ - 1)));
    float4 r = {a.x + b.x + bb.x, a.y + b.y + bb.y,
                a.z + b.z + bb.z, a.w + b.w + bb.w};
    *(float4*)(out + i) = r;
}

// ---------------------------------------------------------------------------
// 256x256 tile, 8 waves (2x4), BK=64, 8-phase interleave, counted vmcnt,
// XOR-swizzled LDS via pre-swizzled global source, setprio around MFMA.
// STATIC buffer map: even K-tiles -> buf0 (read p0-p3), odd -> buf1 (p4-p7).
// B col-half-0 fragments kept in regs across the K-tile (p3/p7 reg-only).
// Generalized K segmentation: segment size = 1<<aSh elements (aSh>=7).
// z-loop: one wg handles zLoop batches (pipeline continues across boundary;
// in-loop epilogue + acc reset).
// zOrd modes:
//   0: zz0 = pz*zLoop, zz1 = zz0 + (zLoop-1)          (consecutive)
//   1: XCD h-grouping for zShift==2, grid.z==128, zLoop==1
//   2: XCD h-grouping + b-PAIR continuation (batches==128, zLoop==2)
// ---------------------------------------------------------------------------
template <bool OUT_F16>
__global__ __launch_bounds__(512, 2)
void gemm256(const _Float16* __restrict__ A, long long aS1, long long aS2, int lda, long long aSeg, int aSh,
             const _Float16* __restrict__ B, long long bS1, long long bS2, int ldb, long long bSeg, int bSh,
             void* __restrict__ Cv, long long cS1, long long cS2, int ldc,
             int K, const float* __restrict__ bias, int biasMode,
             long long biasS1, long long biasS2, int zShift, int zLoop, int zOrd)
{
    extern __shared__ __align__(16) _Float16 lds[];
    _Float16* AsB = lds;                 // [2][256*64]
    _Float16* BsB = lds + 2 * 256 * 64;  // [2][256*64]

    const int tid  = threadIdx.x;
    const int wave = tid >> 6;        // 0..7
    const int lane = tid & 63;
    const int quad = lane >> 4;
    const int r16  = lane & 15;
    const int wr   = wave >> 2;       // 0..1
    const int wc   = wave & 3;        // 0..3

    const int pz = blockIdx.z;
    int zz0, zz1;
    if (zOrd == 1) {
        const int b = (pz & 7) | ((pz >> 5) << 3);
        const int h = (pz >> 3) & 3;
        zz0 = (b << 2) + h; zz1 = zz0;
    } else if (zOrd == 2) {
        const int b = pz & 15;
        const int h = pz >> 4;
        zz0 = (b << 2) + h; zz1 = zz0 + 64;
    } else {
        zz0 = pz * zLoop; zz1 = zz0 + (zLoop - 1);
    }
    const int zMask = (1 << zShift) - 1;

    const int aTSh = aSh - 6, aTMk = (1 << aTSh) - 1;
    const int bTSh = bSh - 6, bTMk = (1 << bTSh) - 1;

    const int ntiles = K >> 6;                    // K-tiles per z (pow2, even)
    const int ntSh   = __builtin_ctz(ntiles);
    const int ntHMsk = (ntiles >> 1) - 1;
    const int TTh    = (ntiles * zLoop) >> 1;     // main-loop iterations

    const int gx = gridDim.x, gy = gridDim.y;
    const int T_ = gx * gy;
    int lin = blockIdx.y * gx + blockIdx.x;
    int id2 = (T_ & 7) ? lin : ((lin & 7) * (T_ >> 3) + (lin >> 3));
    const int m0 = (id2 / gx) * 256;
    const int n0 = (id2 % gx) * 256;

    const int sr  = tid >> 3;                       // 0..63
    const int swz = ((tid & 7) ^ (sr & 7)) * 8;     // swizzled k-offset (elems)

    const _Float16* gaA0 = A + (long long)(zz0 >> zShift) * aS1 + (long long)(zz0 & zMask) * aS2
                             + (long long)(m0 + sr) * lda + swz;
    const _Float16* gaA1 = A + (long long)(zz1 >> zShift) * aS1 + (long long)(zz1 & zMask) * aS2
                             + (long long)(m0 + sr) * lda + swz;
    const _Float16* gbB0 = B + (long long)(zz0 >> zShift) * bS1 + (long long)(zz0 & zMask) * bS2
                             + (long long)(n0 + sr) * ldb + swz;
    const _Float16* gbB1 = B + (long long)(zz1 >> zShift) * bS1 + (long long)(zz1 & zMask) * bS2
                             + (long long)(n0 + sr) * ldb + swz;

    const int arow = wr * 64 + r16;
    const int brow = wc * 32 + r16;
    const int rsw  = r16 & 7;
    const int gxk0 = (quad ^ rsw) * 8;
    const int gxk1 = ((4 + quad) ^ rsw) * 8;

    floatx4 acc[8][4];
#pragma unroll
    for (int i = 0; i < 8; i++)
#pragma unroll
        for (int j = 0; j < 4; j++) acc[i][j] = (floatx4){0.f, 0.f, 0.f, 0.f};

    half8 af[4][2], bf0s[2][2], bf1s[2][2];

    auto stageA = [&](int buf, int h, int T) {
        const int tz = T >> ntSh, tk = T & (ntiles - 1);
        const _Float16* s = (tz ? gaA1 : gaA0) + (long long)(h * 128) * lda
                          + (long long)(tk >> aTSh) * aSeg + ((tk & aTMk) << 6);
        _Float16* d = AsB + buf * 16384 + h * 8192 + wave * 512;
        async_copy16(s, d);
        async_copy16(s + (long long)64 * lda, d + 4096);
    };
    auto stageB = [&](int buf, int h, int T) {
        const int tz = T >> ntSh, tk = T & (ntiles - 1);
        const _Float16* s = (tz ? gbB1 : gbB0) + (long long)(h * 128) * ldb
                          + (long long)(tk >> bTSh) * bSeg + ((tk & bTMk) << 6);
        _Float16* d = BsB + buf * 16384 + h * 8192 + wave * 512;
        async_copy16(s, d);
        async_copy16(s + (long long)64 * ldb, d + 4096);
    };

    // epilogue: VGPR->global only, no LDS, no barriers.
    auto epi = [&](int zz) {
        const int z1 = zz >> zShift, z2 = zz & zMask;
        const float* bz = bias + (long long)z1 * biasS1 + (long long)z2 * biasS2;
        float*    Cf = (float*)Cv    + (long long)z1 * cS1 + (long long)z2 * cS2;
        _Float16* Ch = (_Float16*)Cv + (long long)z1 * cS1 + (long long)z2 * cS2;
#pragma unroll
        for (int f = 0; f < 8; f++) {
            const int row = m0 + (f >> 2) * 128 + wr * 64 + (f & 3) * 16 + r16;
#pragma unroll
            for (int j = 0; j < 4; j++) {
                const int col = n0 + (j >> 1) * 128 + wc * 32 + (j & 1) * 16 + quad * 4;
                float v0 = acc[f][j][0], v1 = acc[f][j][1],
                      v2 = acc[f][j][2], v3 = acc[f][j][3];
                if (biasMode == 1) {
                    v0 += bz[col]; v1 += bz[col + 1];
                    v2 += bz[col + 2]; v3 += bz[col + 3];
                } else if (biasMode == 2) {
                    const float bv = bz[row];
                    v0 += bv; v1 += bv; v2 += bv; v3 += bv;
                }
                const size_t idx = (size_t)row * ldc + col;
                if (OUT_F16) {
                    half4 hv = {(_Float16)v0, (_Float16)v1, (_Float16)v2, (_Float16)v3};
                    *(half4*)&Ch[idx] = hv;
                } else {
                    float4 fv = {v0, v1, v2, v3};
                    *(float4*)&Cf[idx] = fv;
                }
            }
        }
    };

#define LOAD_AF(RH, BUF) do { \
    const _Float16* ab_ = AsB + (BUF) * 16384 + ((RH) * 128 + arow) * 64; \
    _Pragma("unroll") \
    for (int i5 = 0; i5 < 4; i5++) { \
        af[i5][0] = *(const half8*)(ab_ + i5 * 1024 + gxk0); \
        af[i5][1] = *(const half8*)(ab_ + i5 * 1024 + gxk1); \
    } \
} while (0)

#define LOAD_BF(DST, CH, BUF) do { \
    const _Float16* bb_ = BsB + (BUF) * 16384 + ((CH) * 128 + brow) * 64; \
    _Pragma("unroll") \
    for (int j5 = 0; j5 < 2; j5++) { \
        DST[j5][0] = *(const half8*)(bb_ + j5 * 1024 + gxk0); \
        DST[j5][1] = *(const half8*)(bb_ + j5 * 1024 + gxk1); \
    } \
} while (0)

#define MFMA16(RH, CH, BFS) do { \
    _Pragma("unroll") \
    for (int i6 = 0; i6 < 4; i6++) { \
        _Pragma("unroll") \
        for (int j6 = 0; j6 < 2; j6++) { \
            floatx4 c_ = acc[(RH) * 4 + i6][(CH) * 2 + j6]; \
            c_ = __builtin_amdgcn_mfma_f32_16x16x32_f16(BFS[j6][0], af[i6][0], c_, 0, 0, 0); \
            c_ = __builtin_amdgcn_mfma_f32_16x16x32_f16(BFS[j6][1], af[i6][1], c_, 0, 0, 0); \
            acc[(RH) * 4 + i6][(CH) * 2 + j6] = c_; \
        } \
    } \
} while (0)

    // prologue: tile0 -> buf0 (all 4 halves), tile1 -> buf1 (A0, B1)
    stageA(0, 0, 0);
    stageB(0, 1, 0);
    stageA(0, 1, 0);
    stageB(0, 0, 0);
    stageA(1, 0, 1);
    stageB(1, 1, 1);
    WAIT_VM4();
    BAR();

    int zi = 0;
    for (int it = 0; it < TTh; ++it) {
        const int T = it * 2;
        const bool full = (it < TTh - 1);

        // ---- p0: (0,0) of tile T  [buf0]
        LOAD_AF(0, 0); LOAD_BF(bf0s, 0, 0);
        stageA(1, 1, T + 1);
        BAR();
        __builtin_amdgcn_s_setprio(1); MFMA16(0, 0, bf0s); __builtin_amdgcn_s_setprio(0);
        BAR();
        // ---- p1: (0,1)
        LOAD_BF(bf1s, 1, 0);
        stageB(1, 0, T + 1);
        BAR();
        __builtin_amdgcn_s_setprio(1); MFMA16(0, 1, bf1s); __builtin_amdgcn_s_setprio(0);
        BAR();
        // ---- p2: (1,1)
        LOAD_AF(1, 0);
        if (full) stageA(0, 0, T + 2);
        BAR();
        __builtin_amdgcn_s_setprio(1); MFMA16(1, 1, bf1s); __builtin_amdgcn_s_setprio(0);
        BAR();
        // ---- p3: (1,0)  regs-only  + W0
        if (full) stageB(0, 1, T + 2);
        BAR();
        __builtin_amdgcn_s_setprio(1); MFMA16(1, 0, bf0s); __builtin_amdgcn_s_setprio(0);
        if (full) WAIT_VM4(); else WAIT_VM0();
        BAR();
        // ---- p4: (0,0) of tile T+1  [buf1]
        LOAD_AF(0, 1); LOAD_BF(bf0s, 0, 1);
        if (full) stageA(0, 1, T + 2);
        BAR();
        __builtin_amdgcn_s_setprio(1); MFMA16(0, 0, bf0s); __builtin_amdgcn_s_setprio(0);
        BAR();
        // ---- p5: (0,1)
        LOAD_BF(bf1s, 1, 1);
        if (full) stageB(0, 0, T + 2);
        BAR();
        __builtin_amdgcn_s_setprio(1); MFMA16(0, 1, bf1s); __builtin_amdgcn_s_setprio(0);
        BAR();
        // ---- p6: (1,1)
        LOAD_AF(1, 1);
        if (full) stageA(1, 0, T + 3);
        BAR();
        __builtin_amdgcn_s_setprio(1); MFMA16(1, 1, bf1s); __builtin_amdgcn_s_setprio(0);
        BAR();
        // ---- p7: (1,0)  regs-only  + W1
        if (full) stageB(1, 1, T + 3);
        BAR();
        __builtin_amdgcn_s_setprio(1); MFMA16(1, 0, bf0s); __builtin_amdgcn_s_setprio(0);
        if (full) WAIT_VM4();
        BAR();

        // z-boundary: write out this batch's tile, reset accumulator.
        if (((it + 1) & ntHMsk) == 0) {
            epi(zi ? zz1 : zz0);
            ++zi;
#pragma unroll
            for (int i7 = 0; i7 < 8; i7++)
#pragma unroll
                for (int j7 = 0; j7 < 4; j7++)
                    acc[i7][j7] = (floatx4){0.f, 0.f, 0.f, 0.f};
        }
    }

#undef LOAD_AF
#undef LOAD_BF
#undef MFMA16
}

// ---------------------------------------------------------------------------
// in-place fp16 softmax over rows of 512, scaled by 0.25 (head mean).
// ---------------------------------------------------------------------------
__global__ __launch_bounds__(256)
void softmax_f16(_Float16* __restrict__ S)
{
    const int row  = blockIdx.x * 4 + (threadIdx.x >> 6);
    const int lane = threadIdx.x & 63;
    _Float16* s = S + (size_t)row * 512 + lane * 8;
    half8 h = *(const half8*)s;
    float v[8];
    float mx = -1e30f;
#pragma unroll
    for (int j = 0; j < 8; j++) { v[j] = (float)h[j]; mx = fmaxf(mx, v[j]); }
#pragma unroll
    for (int off = 32; off; off >>= 1) mx = fmaxf(mx, __shfl_xor(mx, off));
    float sum = 0.f;
#pragma unroll
    for (int j = 0; j < 8; j++) { v[j] = __expf(v[j] - mx); sum += v[j]; }
#pragma unroll
    for (int off = 32; off; off >>= 1) sum += __shfl_xor(sum, off);
    const float inv = 0.25f / sum;
#pragma unroll
    for (int j = 0; j < 8; j++) h[j] = (_Float16)(v[j] * inv);
    *(half8*)s = h;
}

// 4 fp32->fp16 conversions fused into one launch (ranges in float4 units).
__global__ __launch_bounds__(256)
void cvt_multi(const float* __restrict__ s0, _Float16* __restrict__ d0, int c0,
               const float* __restrict__ s1, _Float16* __restrict__ d1, int c1,
               const float* __restrict__ s2, _Float16* __restrict__ d2, int c2,
               const float* __restrict__ s3, _Float16* __restrict__ d3, int c3)
{
    int i = blockIdx.x * 256 + threadIdx.x;
    const float* s; _Float16* d;
    if (i < c0) { s = s0; d = d0; }
    else { i -= c0;
        if (i < c1) { s = s1; d = d1; }
        else { i -= c1;
            if (i < c2) { s = s2; d = d2; }
            else { i -= c2; s = s3; d = d3; } } }
    const float4 f = ((const float4*)s)[i];
    half4 hv = {(_Float16)f.x, (_Float16)f.y, (_Float16)f.z, (_Float16)f.w};
    *(half4*)(d + (size_t)i * 4) = hv;
}

// in [G][R][C] -> out [G][C][R], fp32 -> fp16
__global__ __launch_bounds__(256)
void transpose_cvt(const float* __restrict__ in, _Float16* __restrict__ out,
                   int R, int C)
{
    __shared__ float tile[32][33];
    const int g  = blockIdx.z;
    const int c0 = blockIdx.x * 32;
    const int r0 = blockIdx.y * 32;
    const float* inp  = in  + (size_t)g * R * C;
    _Float16*    outp = out + (size_t)g * R * C;
#pragma unroll
    for (int i = threadIdx.y; i < 32; i += 8)
        tile[i][threadIdx.x] = inp[(size_t)(r0 + i) * C + c0 + threadIdx.x];
    __syncthreads();
#pragma unroll
    for (int i = threadIdx.y; i < 32; i += 8)
        outp[(size_t)(c0 + i) * R + r0 + threadIdx.x] = (_Float16)tile[threadIdx.x][i];
}

// fused small preprocessing reductions: wk_bq(w0), wk_bq(w1), fold_bias, sum_b0
// block ranges: [0,4) w0; [4,12) w1; [12,16) be1p; [16,18) sb0.
__global__ __launch_bounds__(256)
void small_ops(const float* __restrict__ kq_w0, const float* __restrict__ kq_b0,
               const float* __restrict__ kq_w1, const float* __restrict__ kq_b1,
               const _Float16* __restrict__ projwT, const float* __restrict__ e_b1,
               const float* __restrict__ e_b0,
               float* __restrict__ w0, float* __restrict__ w1,
               float* __restrict__ be1p, float* __restrict__ sb0)
{
    const int blk = blockIdx.x;
    if (blk < 4) {                       // w0[h][d], d < DIN
        const int t = blk * 256 + threadIdx.x;
        const int h = t >> 8, d = t & 255;
        const float* wk = kq_w0 + ((size_t)(h << 8) + d) * (2 * DH_);
        const float* bq = kq_b0 + (size_t)h * 2 * DH_ + DH_;
        float s = 0.f;
        for (int e = 0; e < DH_; e++) s += wk[e] * bq[e];
        w0[t] = s;
    } else if (blk < 12) {               // w1[h][d], d < DH
        const int t = (blk - 4) * 256 + threadIdx.x;
        const int h = t >> 9, d = t & 511;
        const float* wk = kq_w1 + ((size_t)(h << 9) + d) * (2 * DH_);
        const float* bq = kq_b1 + (size_t)h * 2 * DH_ + DH_;
        float s = 0.f;
        for (int e = 0; e < DH_; e++) s += wk[e] * bq[e];
        w1[t] = s;
    } else if (blk < 16) {               // be1p[h][o]
        const int t = (blk - 12) * 256 + threadIdx.x;
        const int h = t >> 8, o = t & 255;
        const _Float16* pw = projwT + (size_t)o * DH_;
        const float*    eb = e_b1 + (size_t)h * DH_;
        float s = 0.f;
        for (int d = 0; d < DH_; d++) s += (float)pw[d] * eb[d];
        be1p[t] = s;
    } else {                             // sb0[e]
        const int e = (blk - 16) * 256 + threadIdx.x;
        sb0[e] = 0.25f * (e_b0[e] + e_b0[DH_ + e] + e_b0[2 * DH_ + e] + e_b0[3 * DH_ + e]);
    }
}

// ---------------------------------------------------------------------------
extern "C" void kernel_launch(void* const* d_in, const int* in_sizes, int n_in,
                              void* d_out, int out_size, void* d_ws, size_t ws_size,
                              hipStream_t stream)
{
    (void)in_sizes; (void)n_in; (void)out_size;

    static bool attr_set = false;
    if (!attr_set) {
        hipFuncSetAttribute((const void*)gemm256<true>,
                            hipFuncAttributeMaxDynamicSharedMemorySize, 131072);
        hipFuncSetAttribute((const void*)gemm256<false>,
                            hipFuncAttributeMaxDynamicSharedMemorySize, 131072);
        attr_set = true;
    }

    const float* x      = (const float*)d_in[0];
    const float* e_w0   = (const float*)d_in[1];
    const float* e_b0   = (const float*)d_in[2];
    const float* kq_w0  = (const float*)d_in[3];
    const float* kq_b0  = (const float*)d_in[4];
    const float* e_w1   = (const float*)d_in[5];
    const float* e_b1   = (const float*)d_in[6];
    const float* kq_w1  = (const float*)d_in[7];
    const float* kq_b1  = (const float*)d_in[8];
    const float* proj_w = (const float*)d_in[9];
    const float* proj_b = (const float*)d_in[10];
    float* out = (float*)d_out;

    char* ws = (char*)d_ws;
    size_t off = 0;
    auto alloc = [&](size_t bytes) -> char* {
        char* p = ws + off;
        off += (bytes + 255) & ~(size_t)255;
        return p;
    };

    // --- persistent (~72 MB incl. xT) --------------------------------------
    _Float16* x16    = (_Float16*)alloc((size_t)BN_ * DIN_ * 2);
    _Float16* h1_16  = (_Float16*)alloc((size_t)BN_ * DH_ * 2);
    _Float16* ewT0   = (_Float16*)alloc((size_t)H_ * DH_ * DIN_ * 2);
    _Float16* projwT = (_Float16*)alloc((size_t)DOUT_ * DH_ * 2);
    _Float16* Mt0    = (_Float16*)alloc((size_t)H_ * DIN_ * DIN_ * 2);
    _Float16* Mt1    = (_Float16*)alloc((size_t)H_ * DH_ * DH_ * 2);
    _Float16* We1pT  = (_Float16*)alloc((size_t)H_ * DOUT_ * DH_ * 2);
    float*    be1p   = (float*)alloc((size_t)H_ * DOUT_ * 4);
    float*    w0     = (float*)alloc((size_t)H_ * DIN_ * 4);
    float*    w1     = (float*)alloc((size_t)H_ * DH_ * 4);
    float*    sb0    = (float*)alloc((size_t)DH_ * 4);
    _Float16* xT     = (_Float16*)alloc((size_t)BN_ * DIN_ * 2);   // [b][d][n]

    const size_t persistAll = off;
    const long long SB = (long long)N_ * N_;
    const size_t SC_FULL  = (size_t)B_ * H_ * N_ * N_ * 2;       // 134.2 MB
    const size_t SC_CHUNK = SC_FULL / 2;                          // 67.1 MB
    const size_t A2_SZ    = (size_t)BN_ * H_ * DIN_ * 2;          // 67.1 MB
    const size_t SLACK    = 1u << 20;

    // tier A: full-batch blk0 + deferred full-batch blk1 PV  (~275 MB)
    // tier B: CH=32 chunks (ws known to be in [232,275) on this harness)
    const bool tierA = ws_size >= persistAll + SC_FULL + A2_SZ + SLACK;

    _Float16* Sc = (_Float16*)alloc(tierA ? SC_FULL : SC_CHUNK);
    _Float16* A2 = (_Float16*)alloc(A2_SZ);

    // transient cvt buffers live inside A2 (dead before A2's first GEMM use)
    _Float16* kq0_16 = A2;                                        // 2.1 MB
    _Float16* kq1_16 = kq0_16 + (size_t)H_ * DIN_ * 2 * DH_;      // 4.2 MB
    _Float16* ew1_16 = kq1_16 + (size_t)H_ * DH_ * 2 * DH_;       // 2.1 MB

    // routing: 256^2 kernel when its grid (after zLoop) fills the chip;
    // otherwise 128^2 kernel (zLoop==1, zOrd==0 only).
    auto gemm = [&](bool outF16,
                    const _Float16* A, long long aS1, long long aS2, int lda, long long aSeg,
                    const _Float16* Bp, long long bS1, long long bS2, int ldb, long long bSeg,
                    void* C, long long cS1, long long cS2, int ldc,
                    int M, int Nn, int K, int batches, int zShift,
                    const float* bias, int biasMode, long long biasS1, long long biasS2,
                    int aSh, int bSh, int zLoop, int zOrd) {
        const bool can256 = (M % 256 == 0) && (Nn % 256 == 0) && (K % 128 == 0);
        const bool can128 = (M % 128 == 0) && (Nn % 128 == 0) && (K % 32 == 0)
                          && (aSh == 9) && (bSh == 9) && (zLoop == 1) && (zOrd == 0);
        const long long wg256 = can256
            ? (long long)(M >> 8) * (Nn >> 8) * (batches / zLoop) : 0;
        bool use256;
        if (!can128)            use256 = true;
        else if (!can256)       use256 = false;
        else                    use256 = (wg256 >= 192) || (wg256 >= 32 && wg256 * 4 < 128);
        if (use256) {
            dim3 grid(Nn / 256, M / 256, batches / zLoop), block(512);
            if (outF16)
                gemm256<true><<<grid, block, 131072, stream>>>(A, aS1, aS2, lda, aSeg, aSh,
                    Bp, bS1, bS2, ldb, bSeg, bSh, C, cS1, cS2, ldc, K, bias, biasMode, biasS1, biasS2, zShift, zLoop, zOrd);
            else
                gemm256<false><<<grid, block, 131072, stream>>>(A, aS1, aS2, lda, aSeg, aSh,
                    Bp, bS1, bS2, ldb, bSeg, bSh, C, cS1, cS2, ldc, K, bias, biasMode, biasS1, biasS2, zShift, zLoop, zOrd);
        } else {
            dim3 grid(Nn / 128, M / 128, batches), block(256);
            if (outF16)
                gemm_f16<true><<<grid, block, 0, stream>>>(A, aS1, aS2, lda, aSeg,
                    Bp, bS1, bS2, ldb, bSeg, C, cS1, cS2, ldc, K, bias, biasMode, biasS1, biasS2, zShift, 0, 0);
            else
                gemm_f16<false><<<grid, block, 0, stream>>>(A, aS1, aS2, lda, aSeg,
                    Bp, bS1, bS2, ldb, bSeg, C, cS1, cS2, ldc, K, bias, biasMode, biasS1, biasS2, zShift, 0, 0);
        }
    };

    // --- preprocessing -----------------------------------------------------
    {
        const int c0 = BN_ * DIN_ / 4;              // x -> x16
        const int c1 = H_ * DIN_ * 2 * DH_ / 4;     // kq_w0
        const int c2 = H_ * DH_ * 2 * DH_ / 4;      // kq_w1
        const int c3 = H_ * DH_ * DH_ / 4;          // e_w1
        cvt_multi<<<(c0 + c1 + c2 + c3) / 256, 256, 0, stream>>>(
            x, x16, c0, kq_w0, kq0_16, c1, kq_w1, kq1_16, c2, e_w1, ew1_16, c3);
    }
    transpose_cvt<<<dim3(DH_ / 32, DIN_ / 32, H_), dim3(32, 8), 0, stream>>>(e_w0, ewT0, DIN_, DH_);
    transpose_cvt<<<dim3(DOUT_ / 32, DH_ / 32, 1), dim3(32, 8), 0, stream>>>(proj_w, projwT, DH_, DOUT_);
    transpose_cvt<<<dim3(DIN_ / 32, N_ / 32, B_), dim3(32, 8), 0, stream>>>(x, xT, N_, DIN_);
    small_ops<<<18, 256, 0, stream>>>(kq_w0, kq_b0, kq_w1, kq_b1,
                                      projwT, e_b1, e_b0, w0, w1, be1p, sb0);

    // Mt_h = Wk_h * Wq_h^T  (so T = x * Mt^T = x * (Wq Wk^T))
    gemm(true, kq0_16, 0, (long long)DIN_ * 2 * DH_, 2 * DH_, 512,
         kq0_16 + DH_, 0, (long long)DIN_ * 2 * DH_, 2 * DH_, 512,
         Mt0, 0, (long long)DIN_ * DIN_, DIN_,
         DIN_, DIN_, DH_, H_, 2, nullptr, 0, 0, 0, 9, 9, 1, 0);
    gemm(true, kq1_16, 0, (long long)DH_ * 2 * DH_, 2 * DH_, 512,
         kq1_16 + DH_, 0, (long long)DH_ * 2 * DH_, 2 * DH_, 512,
         Mt1, 0, (long long)DH_ * DH_, DH_,
         DH_, DH_, DH_, H_, 2, nullptr, 0, 0, 0, 9, 9, 1, 0);
    // We1pT[h][o][d] = sum_d' projwT[o][d'] * e_w1[h][d][d']
    gemm(true, projwT, 0, 0, DH_, 512,
         ew1_16, 0, (long long)DH_ * DH_, DH_, 512,
         We1pT, 0, (long long)DOUT_ * DH_, DH_,
         DOUT_, DH_, DH_, H_, 2, nullptr, 0, 0, 0, 9, 9, 1, 0);

    // --- block 0: G-path (h1 = sum_h (P_h x) W_h + 0.25 sum_h b_h) ---------
    // V folded into T': S = (T + 1*w^T) x^T, so T0 gets column-bias w0.
    {
        const int CH0  = tierA ? B_ : 32;
        const int NCH0 = B_ / CH0;
        const int sOrd  = tierA ? 1 : 2;   // zOrd=2 requires batches==128
        const int sLoop = tierA ? 1 : 2;
        const size_t GCH = (size_t)CH0 * N_ * H_ * DIN_;   // elems per A2 slot

        // T0' full-batch (batched over b, zLoop=2), col-bias w0[h*DIN+d].
        gemm(true, x16, (long long)N_ * DIN_, 0, DIN_, 512,
             Mt0, 0, 0, DIN_, 512,
             A2, (long long)N_ * H_ * DIN_, 0, H_ * DIN_,
             N_, H_ * DIN_, DIN_, B_, 0, w0, 1, 0, 0, 9, 9, 2, 0);

        for (int c = 0; c < NCH0; c++) {
            const _Float16* xc  = x16 + (size_t)c * CH0 * N_ * DIN_;
            const _Float16* xTc = xT  + (size_t)c * CH0 * DIN_ * N_;
            _Float16* slot = A2 + (size_t)c * GCH;
            // S = T' x^T  (no bias; zOrd: h L2-group / b-pair continuation)
            gemm(true, slot, (long long)N_ * H_ * DIN_, DIN_, H_ * DIN_, 512,
                 xc, (long long)N_ * DIN_, 0, DIN_, 512,
                 Sc, (long long)H_ * SB, SB, N_,
                 N_, N_, DIN_, CH0 * H_, 2,
                 nullptr, 0, 0, 0, 9, 9, sLoop, sOrd);
            softmax_f16<<<CH0 * H_ * N_ / 4, 256, 0, stream>>>(Sc);
            // G[b][h][q][d] = P[b,h] . x_b  -> slot c (T0 chunk c dead)
            gemm(true, Sc, (long long)H_ * SB, SB, N_, 512,
                 xTc, (long long)DIN_ * N_, 0, N_, 512,
                 slot, (long long)H_ * N_ * DIN_, (long long)N_ * DIN_, DIN_,
                 N_, DIN_, N_, CH0 * H_, 2, nullptr, 0, 0, 0, 9, 9, 1, 1);
        }
        // deferred h1 over ALL batches: grid (2,2,64) = 256 wgs
        gemm(true, A2, (long long)H_ * N_ * DIN_, 0, DIN_, (long long)N_ * DIN_,
             ewT0, 0, 0, DIN_, (long long)DH_ * DIN_,
             h1_16, (long long)N_ * DH_, 0, DH_,
             N_, DH_, H_ * DIN_, B_, 0, sb0, 1, 0, 0, 8, 8, 1, 0);
    }

    // --- block 1 -----------------------------------------------------------
    {
        for (int c = 0; c < 2; c++) {
            const _Float16* hc = h1_16 + (size_t)c * 32 * N_ * DH_;
            _Float16* Scp = tierA ? Sc + (size_t)c * 32 * H_ * SB : Sc;
            // T1' -> A2, reshaped (M=256, batches=64, zLoop=2); col-bias w1.
            gemm(true, hc, (long long)256 * DH_, 0, DH_, 512,
                 Mt1, 0, 0, DH_, 512,
                 A2, (long long)256 * H_ * DH_, 0, H_ * DH_,
                 256, H_ * DH_, DH_, 64, 0, w1, 1, 0, 0, 9, 9, 2, 0);
            // S1 = T1' h1^T  (no bias; zOrd=2)
            gemm(true, A2, (long long)N_ * H_ * DH_, DH_, H_ * DH_, 512,
                 hc, (long long)N_ * DH_, 0, DH_, 512,
                 Scp, (long long)H_ * SB, SB, N_,
                 N_, N_, DH_, 32 * H_, 2,
                 nullptr, 0, 0, 0, 9, 9, 2, 2);
            softmax_f16<<<32 * H_ * N_ / 4, 256, 0, stream>>>(Scp);
            if (!tierA) {
                // embW chunk -> A2 lower half (T1 dead)
                gemm(true, We1pT, 0, 0, DH_, 512,
                     hc, (long long)N_ * DH_, 0, DH_, 512,
                     A2, (long long)H_ * DOUT_ * N_, 0, N_,
                     H_ * DOUT_, N_, DH_, 32, 0, be1p, 2, 0, 0, 9, 9, 1, 0);
                // PV chunk, split-K=2 -> fp32 partials in A2 upper half
                // (dead T1 space), grid (2,4,64)=512 wgs -> 2 blocks/CU.
                float* pPart = (float*)(A2 + (size_t)32 * H_ * DOUT_ * N_);
                const long long partStride = (long long)32 * N_ * DOUT_;
                {
                    dim3 grid(DOUT_ / 128, N_ / 128, 64), block(256);
                    gemm_f16<false><<<grid, block, 0, stream>>>(
                        Scp, (long long)H_ * SB, 0, N_, SB,
                        A2, (long long)H_ * DOUT_ * N_, 0, N_, (long long)DOUT_ * N_,
                        pPart, (long long)N_ * DOUT_, 0, DOUT_,
                        H_ * N_, nullptr, 0, 0, 0, 0, 1, partStride);
                }
                combine_pv<<<(unsigned)(partStride / 4 / 256), 256, 0, stream>>>(
                    pPart, partStride, proj_b, out + (size_t)c * 32 * N_ * DOUT_);
            }
        }
        if (tierA) {
            // embW full -> A2 (T1 dead after last S1)
            gemm(true, We1pT, 0, 0, DH_, 512,
                 h1_16, (long long)N_ * DH_, 0, DH_, 512,
                 A2, (long long)H_ * DOUT_ * N_, 0, N_,
                 H_ * DOUT_, N_, DH_, B_, 0, be1p, 2, 0, 0, 9, 9, 1, 0);
            // deferred full-batch PV — 512 wgs (2 blocks/CU), no split needed
            gemm(false, Sc, (long long)H_ * SB, 0, N_, SB,
                 A2, (long long)H_ * DOUT_ * N_, 0, N_, (long long)DOUT_ * N_,
                 out, (long long)N_ * DOUT_, 0, DOUT_,
                 N_, DOUT_, H_ * N_, B_, 0, proj_b, 1, 0, 0, 9, 9, 1, 0);
        }
    }
}